// Round 6
// baseline (1109.915 us; speedup 1.0000x reference)
//
#include <hip/hip_runtime.h>

#define D 256
#define NE 8192
#define NZ 16384
#define BM 128
#define BK 32
#define NB (NE / BM)
#define NTRI (NB * (NB + 1) / 2)
#define NSPLIT_A 8
#define SPLIT_NA (NE / NSPLIT_A)   // 1024
#define GAPTH 6.0e-5f
#define LDH 40                     // fp16 LDS row stride (32 data + 8 pad; keeps 16B align)
#define LDM 17                     // merge-phase LDS stride (floats) - conflict-free reads

typedef _Float16 f16x8 __attribute__((ext_vector_type(8)));
typedef _Float16 f16x4 __attribute__((ext_vector_type(4)));
typedef float f32x4 __attribute__((ext_vector_type(4)));

#define MFMA16(a, b, c) __builtin_amdgcn_mfma_f32_16x16x32_f16(a, b, c, 0, 0, 0)

// ---------------- workspace layout (bytes) ----------------
#define WS_SUMS   0                            // double[4]
#define WS_CNT2   64                           // int: item count
#define WS_ZSQ    256                          // float[NZ]
#define WS_ESQ    (WS_ZSQ + NZ * 4)            // float[NE]
#define WS_IDX    (WS_ESQ + NE * 4)            // int[NZ]
#define WS_PS1    (WS_IDX + NZ * 4)            // float[NZ*8]
#define WS_PS2    (WS_PS1 + NZ * NSPLIT_A * 4)
#define WS_PIX    (WS_PS2 + NZ * NSPLIT_A * 4)
#define WS_RMX    (WS_PIX + NZ * NSPLIT_A * 4) // uint[NE]
#define WS_RMN    (WS_RMX + NE * 4)            // uint[NE]
#define WS_PACK   (WS_RMN + NE * 4)            // u64[NZ]
#define WS_ITEMS  (WS_PACK + NZ * 8)           // int[NZ*8]
#define WS_ZH     (WS_ITEMS + NZ * NSPLIT_A * 4) // f16[NZ*D]
#define WS_EH     (WS_ZH + NZ * D * 2)           // f16[NE*D]

__device__ __forceinline__ float waveReduceSumF(float v) {
    v += __shfl_down(v, 32); v += __shfl_down(v, 16); v += __shfl_down(v, 8);
    v += __shfl_down(v, 4);  v += __shfl_down(v, 2);  v += __shfl_down(v, 1);
    return v;
}
__device__ __forceinline__ double waveReduceSumD(double v) {
    v += __shfl_down(v, 32); v += __shfl_down(v, 16); v += __shfl_down(v, 8);
    v += __shfl_down(v, 4);  v += __shfl_down(v, 2);  v += __shfl_down(v, 1);
    return v;
}

__global__ void k_init(double* sums, int* cnt2) {
    sums[0] = 0.0; sums[1] = 0.0; sums[2] = 0.0; sums[3] = 0.0;
    *cnt2 = 0;
}

__global__ __launch_bounds__(256) void k_initmm(unsigned* __restrict__ rmx,
                                                unsigned* __restrict__ rmn,
                                                unsigned long long* __restrict__ pack) {
    const int n = blockIdx.x * 256 + threadIdx.x;
    if (n < NE) { rmx[n] = 0u; rmn[n] = 0x7F800000u; }
    pack[n] = ~0ull;   // grid covers NZ
}

// np.sum(x*x, axis=1) bit-exact (numpy pairwise summation, n=256)
__global__ __launch_bounds__(256) void k_rowsq(const float* __restrict__ src,
                                               float* __restrict__ rsq,
                                               double* __restrict__ sums) {
    const int row = blockIdx.x * 256 + threadIdx.x;
    const float* p = src + (size_t)row * D;
    float h[2];
#pragma unroll
    for (int half = 0; half < 2; ++half) {
        const float* q = p + half * 128;
        float4 a0 = *(const float4*)&q[0];
        float4 a1 = *(const float4*)&q[4];
        float r0 = __fmul_rn(a0.x, a0.x);
        float r1 = __fmul_rn(a0.y, a0.y);
        float r2 = __fmul_rn(a0.z, a0.z);
        float r3 = __fmul_rn(a0.w, a0.w);
        float r4 = __fmul_rn(a1.x, a1.x);
        float r5 = __fmul_rn(a1.y, a1.y);
        float r6 = __fmul_rn(a1.z, a1.z);
        float r7 = __fmul_rn(a1.w, a1.w);
#pragma unroll
        for (int i = 8; i < 128; i += 8) {
            const float4 b0 = *(const float4*)&q[i];
            const float4 b1 = *(const float4*)&q[i + 4];
            r0 = __fadd_rn(r0, __fmul_rn(b0.x, b0.x));
            r1 = __fadd_rn(r1, __fmul_rn(b0.y, b0.y));
            r2 = __fadd_rn(r2, __fmul_rn(b0.z, b0.z));
            r3 = __fadd_rn(r3, __fmul_rn(b0.w, b0.w));
            r4 = __fadd_rn(r4, __fmul_rn(b1.x, b1.x));
            r5 = __fadd_rn(r5, __fmul_rn(b1.y, b1.y));
            r6 = __fadd_rn(r6, __fmul_rn(b1.z, b1.z));
            r7 = __fadd_rn(r7, __fmul_rn(b1.w, b1.w));
        }
        const float t01 = __fadd_rn(r0, r1);
        const float t23 = __fadd_rn(r2, r3);
        const float t45 = __fadd_rn(r4, r5);
        const float t67 = __fadd_rn(r6, r7);
        h[half] = __fadd_rn(__fadd_rn(t01, t23), __fadd_rn(t45, t67));
    }
    const float tot = __fadd_rn(h[0], h[1]);
    rsq[row] = tot;
    if (sums != nullptr) {
        double s = waveReduceSumD((double)tot);
        if ((threadIdx.x & 63) == 0) atomicAdd(&sums[0], s);
    }
}

// z -> fp16(z)
__global__ __launch_bounds__(256) void k_cvt_z(const float* __restrict__ z,
                                               _Float16* __restrict__ zh) {
    const size_t g = (size_t)blockIdx.x * 256 + threadIdx.x;
    const float4 x = *(const float4*)&z[g * 4];
    f16x4 hv;
    hv[0] = (_Float16)x.x; hv[1] = (_Float16)x.y;
    hv[2] = (_Float16)x.z; hv[3] = (_Float16)x.w;
    *(f16x4*)&zh[g * 4] = hv;
}

// e -> fp16(e * 2^13)  (scaled into fp16 normal range)
__global__ __launch_bounds__(256) void k_cvt_e(const float* __restrict__ e,
                                               _Float16* __restrict__ eh) {
    const size_t g = (size_t)blockIdx.x * 256 + threadIdx.x;
    const float4 x = *(const float4*)&e[g * 4];
    f16x4 hv;
    hv[0] = (_Float16)(x.x * 8192.0f); hv[1] = (_Float16)(x.y * 8192.0f);
    hv[2] = (_Float16)(x.z * 8192.0f); hv[3] = (_Float16)(x.w * 8192.0f);
    *(f16x4*)&eh[g * 4] = hv;
}

// ---- MFMA argmin pass: single zh*eh MFMA, top-2 per row per split ----
__global__ __launch_bounds__(256) void k_argmin_mfma(
        const _Float16* __restrict__ zh, const _Float16* __restrict__ eh,
        const float* __restrict__ zsq, const float* __restrict__ esq,
        float* __restrict__ ps1, float* __restrict__ ps2, int* __restrict__ pix) {
    __shared__ __align__(16) char smem[26112];
    _Float16* Ah = (_Float16*)smem;            // [128][LDH] = 10240 B
    _Float16* Bh = (_Float16*)(smem + 10240);  // [64][LDH]  =  5120 B

    const int t = threadIdx.x;
    const int lane = t & 63;
    const int w = t >> 6;
    const int quad = lane >> 4;
    const int l15 = lane & 15;
    const int row0 = blockIdx.x * BM;
    const int sp = blockIdx.y;
    const int cb = sp * SPLIT_NA;
    const int wrow = row0 + w * 32;

    float zq[8];
#pragma unroll
    for (int mi = 0; mi < 2; ++mi)
#pragma unroll
        for (int r = 0; r < 4; ++r)
            zq[mi * 4 + r] = zsq[wrow + mi * 16 + quad * 4 + r];

    float b1[8], b2[8];
    int i1[8];
#pragma unroll
    for (int s = 0; s < 8; ++s) { b1[s] = 3.4e38f; b2[s] = 3.4e38f; i1[s] = 0; }

    const int br = t >> 2;
    const int bseg = t & 3;

    for (int ch = 0; ch < 16; ++ch) {
        const int c0 = cb + ch * 64;

        f32x4 acc[2][4];
#pragma unroll
        for (int mi = 0; mi < 2; ++mi)
#pragma unroll
            for (int nj = 0; nj < 4; ++nj) acc[mi][nj] = (f32x4){0.f, 0.f, 0.f, 0.f};

        for (int kb = 0; kb < D; kb += BK) {
            __syncthreads();
#pragma unroll
            for (int uu = 0; uu < 2; ++uu) {
                const int u = t + uu * 256;
                const int r = u >> 2, seg = u & 3;
                *(uint4*)&Ah[r * LDH + seg * 8] =
                    *(const uint4*)&zh[(size_t)(row0 + r) * D + kb + seg * 8];
            }
            *(uint4*)&Bh[br * LDH + bseg * 8] =
                *(const uint4*)&eh[(size_t)(c0 + br) * D + kb + bseg * 8];
            __syncthreads();

            f16x8 ah[2], bh[4];
#pragma unroll
            for (int mi = 0; mi < 2; ++mi)
                ah[mi] = *(const f16x8*)&Ah[(w * 32 + mi * 16 + l15) * LDH + quad * 8];
#pragma unroll
            for (int nj = 0; nj < 4; ++nj)
                bh[nj] = *(const f16x8*)&Bh[(nj * 16 + l15) * LDH + quad * 8];
#pragma unroll
            for (int mi = 0; mi < 2; ++mi)
#pragma unroll
                for (int nj = 0; nj < 4; ++nj)
                    acc[mi][nj] = MFMA16(ah[mi], bh[nj], acc[mi][nj]);
        }

        // score x~ = (fl(zsq+esq)-zsq) - 2*dot ; dot = acc * 2^-13
#pragma unroll
        for (int nj = 0; nj < 4; ++nj) {
            const int gcol = c0 + nj * 16 + l15;
            const float eqv = esq[gcol];
#pragma unroll
            for (int mi = 0; mi < 2; ++mi)
#pragma unroll
                for (int r = 0; r < 4; ++r) {
                    const int s = mi * 4 + r;
                    const float t1 = __fadd_rn(zq[s], eqv);
                    const float v = __fsub_rn(t1, zq[s]);      // exact (Sterbenz)
                    const float sc = fmaf(acc[mi][nj][r], -0x1p-12f, v);
                    if (sc < b1[s]) { b2[s] = b1[s]; b1[s] = sc; i1[s] = gcol; }
                    else if (sc < b2[s]) b2[s] = sc;
                }
        }
    }

    // per-row top-2 merge across the 16 lane-columns (stride LDM=17: conflict-free)
    __syncthreads();
    float* MB1 = (float*)smem;             // [128][17]
    float* MB2 = (float*)(smem + 8704);
    int*   MI  = (int*)(smem + 17408);
#pragma unroll
    for (int s = 0; s < 8; ++s) {
        const int rl = w * 32 + (s >> 2) * 16 + quad * 4 + (s & 3);
        MB1[rl * LDM + l15] = b1[s];
        MB2[rl * LDM + l15] = b2[s];
        MI[rl * LDM + l15] = i1[s];
    }
    __syncthreads();
    if (t < BM) {
        float v1 = MB1[t * LDM], v2 = MB2[t * LDM];
        int ii1 = MI[t * LDM];
#pragma unroll
        for (int c = 1; c < 16; ++c) {
            const float s1 = MB1[t * LDM + c];
            const float s2 = MB2[t * LDM + c];
            const int ii = MI[t * LDM + c];
            if (s1 < v1 || (s1 == v1 && ii < ii1)) {
                v2 = fminf(fminf(v2, v1), s2);
                v1 = s1; ii1 = ii;
            } else {
                v2 = fminf(v2, s1);
            }
        }
        ps1[(size_t)(row0 + t) * NSPLIT_A + sp] = v1;
        ps2[(size_t)(row0 + t) * NSPLIT_A + sp] = v2;
        pix[(size_t)(row0 + t) * NSPLIT_A + sp] = ii1;
    }
}

// merge splits; provisional idx; emit (row,split) repair items for near-ties
__global__ __launch_bounds__(256) void k_merge(const float* __restrict__ ps1,
                                               const float* __restrict__ ps2,
                                               const int* __restrict__ pi,
                                               int* __restrict__ idxbuf,
                                               float* __restrict__ outidx,
                                               int* __restrict__ cnt2,
                                               int* __restrict__ items) {
    const int n = blockIdx.x * 256 + threadIdx.x;
    float v1 = ps1[n * NSPLIT_A];
    float v2 = ps2[n * NSPLIT_A];
    int ii1 = pi[n * NSPLIT_A];
#pragma unroll
    for (int s = 1; s < NSPLIT_A; ++s) {
        const float s1 = ps1[n * NSPLIT_A + s];
        const float s2 = ps2[n * NSPLIT_A + s];
        const int ii = pi[n * NSPLIT_A + s];
        if (s1 < v1 || (s1 == v1 && ii < ii1)) {
            v2 = fminf(fminf(v2, v1), s2);
            v1 = s1; ii1 = ii;
        } else {
            v2 = fminf(v2, s1);
        }
    }
    idxbuf[n] = ii1;
    outidx[n] = (float)ii1;
    if (v2 - v1 < GAPTH) {
        int mask = 0, nq = 0;
        const float lim = v1 + GAPTH;
#pragma unroll
        for (int s = 0; s < NSPLIT_A; ++s)
            if (ps1[n * NSPLIT_A + s] <= lim) { mask |= 1 << s; ++nq; }
        int base = atomicAdd(cnt2, nq);
#pragma unroll
        for (int s = 0; s < NSPLIT_A; ++s)
            if ((mask >> s) & 1) items[base++] = (n << 3) | s;
    }
}

// np-bit-exact repair: one block per (row,split) item; 1024 cols, serial-k fp32 chain
__global__ __launch_bounds__(256) void k_fix_item(const float* __restrict__ z,
                                                  const float* __restrict__ emb,
                                                  const float* __restrict__ zsq,
                                                  const float* __restrict__ esq,
                                                  const int* __restrict__ cnt2,
                                                  const int* __restrict__ items,
                                                  unsigned long long* __restrict__ pack) {
    __shared__ float zrow[D];
    __shared__ float rs[256];
    __shared__ int ri[256];
    const int t = threadIdx.x;
    const int nit = *cnt2;
    for (int it = blockIdx.x; it < nit; it += gridDim.x) {
        const int itm = items[it];
        const int row = itm >> 3;
        const int cb = (itm & 7) * SPLIT_NA;
        __syncthreads();
        if (t < 64) *(float4*)&zrow[t * 4] = *(const float4*)&z[(size_t)row * D + t * 4];
        __syncthreads();
        const float zq = zsq[row];
        float dot[4] = {0.f, 0.f, 0.f, 0.f};
        const float* e0 = &emb[(size_t)(cb + t) * D];
        const float* e1 = &emb[(size_t)(cb + 256 + t) * D];
        const float* e2 = &emb[(size_t)(cb + 512 + t) * D];
        const float* e3 = &emb[(size_t)(cb + 768 + t) * D];
#pragma unroll 8
        for (int k = 0; k < D; k += 4) {
            const float4 a0 = *(const float4*)&e0[k];
            const float4 a1 = *(const float4*)&e1[k];
            const float4 a2 = *(const float4*)&e2[k];
            const float4 a3 = *(const float4*)&e3[k];
            const float z0 = zrow[k], z1 = zrow[k + 1], z2 = zrow[k + 2], z3 = zrow[k + 3];
            dot[0] = fmaf(z0, a0.x, dot[0]); dot[0] = fmaf(z1, a0.y, dot[0]);
            dot[0] = fmaf(z2, a0.z, dot[0]); dot[0] = fmaf(z3, a0.w, dot[0]);
            dot[1] = fmaf(z0, a1.x, dot[1]); dot[1] = fmaf(z1, a1.y, dot[1]);
            dot[1] = fmaf(z2, a1.z, dot[1]); dot[1] = fmaf(z3, a1.w, dot[1]);
            dot[2] = fmaf(z0, a2.x, dot[2]); dot[2] = fmaf(z1, a2.y, dot[2]);
            dot[2] = fmaf(z2, a2.z, dot[2]); dot[2] = fmaf(z3, a2.w, dot[2]);
            dot[3] = fmaf(z0, a3.x, dot[3]); dot[3] = fmaf(z1, a3.y, dot[3]);
            dot[3] = fmaf(z2, a3.z, dot[3]); dot[3] = fmaf(z3, a3.w, dot[3]);
        }
        float best = 3.4e38f; int bidx = 0;
#pragma unroll
        for (int cc = 0; cc < 4; ++cc) {
            const int j = cb + cc * 256 + t;   // ascending per thread
            const float t1 = __fadd_rn(zq, esq[j]);
            const float s = fmaf(-2.f, dot[cc], t1);
            if (s < best) { best = s; bidx = j; }
        }
        rs[t] = best; ri[t] = bidx;
        __syncthreads();
        for (int off = 128; off > 0; off >>= 1) {
            if (t < off) {
                const float s2 = rs[t + off]; const int i2 = ri[t + off];
                if (s2 < rs[t] || (s2 == rs[t] && i2 < ri[t])) { rs[t] = s2; ri[t] = i2; }
            }
            __syncthreads();
        }
        if (t == 0) {
            const unsigned long long pk =
                ((unsigned long long)__float_as_uint(rs[0]) << 32) | (unsigned)ri[0];
            atomicMin(&pack[row], pk);
        }
    }
}

__global__ __launch_bounds__(256) void k_fixdecode(const unsigned long long* __restrict__ pack,
                                                   int* __restrict__ idxbuf,
                                                   float* __restrict__ outidx) {
    const int n = blockIdx.x * 256 + threadIdx.x;
    const unsigned long long p = pack[n];
    if (p != ~0ull) {
        const int idx = (int)(p & 0xffffffffu);
        idxbuf[n] = idx;
        outidx[n] = (float)idx;
    }
}

__global__ __launch_bounds__(256) void k_gather(const float* __restrict__ z,
                                                const float* __restrict__ emb,
                                                const int* __restrict__ idxbuf,
                                                float* __restrict__ out,
                                                double* __restrict__ sums) {
    const int row = blockIdx.x * 4 + (threadIdx.x >> 6);
    const int lane = threadIdx.x & 63;
    const int idx = idxbuf[row];
    const float4 e4 = *(const float4*)&emb[(size_t)idx * D + lane * 4];
    const float4 z4 = *(const float4*)&z[(size_t)row * D + lane * 4];
    *(float4*)&out[(size_t)row * D + lane * 4] = e4;
    const float dx = e4.x - z4.x, dy = e4.y - z4.y;
    const float dzv = e4.z - z4.z, dw = e4.w - z4.w;
    float s = dx * dx + dy * dy + dzv * dzv + dw * dw;
    s = waveReduceSumF(s);
    if (lane == 0) atomicAdd(&sums[1], (double)s);
}

// ---- pairwise cdist row min/max via fp16 MFMA, triangular tiles ----
__global__ __launch_bounds__(256) void k_pairwise_mfma(const _Float16* __restrict__ eh,
                                                       const float* __restrict__ esq,
                                                       unsigned* __restrict__ rmxg,
                                                       unsigned* __restrict__ rmng) {
    __shared__ __align__(16) char smem[20480];
    _Float16* Ah = (_Float16*)smem;            // [128][LDH]
    _Float16* Bh = (_Float16*)(smem + 10240);  // [128][LDH]

    int p = blockIdx.x;
    int bi = 0;
    while (p >= NB - bi) { p -= NB - bi; ++bi; }
    const int bj = bi + p;
    const int row0 = bi * BM;
    const int c0 = bj * BM;

    const int t = threadIdx.x;
    const int lane = t & 63;
    const int w = t >> 6;
    const int quad = lane >> 4;
    const int l15 = lane & 15;

    float esqR[8], esqC[8];
#pragma unroll
    for (int mi = 0; mi < 2; ++mi)
#pragma unroll
        for (int r = 0; r < 4; ++r)
            esqR[mi * 4 + r] = esq[row0 + w * 32 + mi * 16 + quad * 4 + r];
#pragma unroll
    for (int nj = 0; nj < 8; ++nj) esqC[nj] = esq[c0 + nj * 16 + l15];

    f32x4 acc[2][8];
#pragma unroll
    for (int mi = 0; mi < 2; ++mi)
#pragma unroll
        for (int nj = 0; nj < 8; ++nj) acc[mi][nj] = (f32x4){0.f, 0.f, 0.f, 0.f};

    for (int kb = 0; kb < D; kb += BK) {
        __syncthreads();
#pragma unroll
        for (int uu = 0; uu < 2; ++uu) {
            const int u = t + uu * 256;
            const int r = u >> 2, seg = u & 3;
            *(uint4*)&Ah[r * LDH + seg * 8] =
                *(const uint4*)&eh[(size_t)(row0 + r) * D + kb + seg * 8];
            *(uint4*)&Bh[r * LDH + seg * 8] =
                *(const uint4*)&eh[(size_t)(c0 + r) * D + kb + seg * 8];
        }
        __syncthreads();

        f16x8 ah[2], bh[8];
#pragma unroll
        for (int mi = 0; mi < 2; ++mi)
            ah[mi] = *(const f16x8*)&Ah[(w * 32 + mi * 16 + l15) * LDH + quad * 8];
#pragma unroll
        for (int nj = 0; nj < 8; ++nj)
            bh[nj] = *(const f16x8*)&Bh[(nj * 16 + l15) * LDH + quad * 8];
#pragma unroll
        for (int mi = 0; mi < 2; ++mi)
#pragma unroll
            for (int nj = 0; nj < 8; ++nj)
                acc[mi][nj] = MFMA16(ah[mi], bh[nj], acc[mi][nj]);
    }

    float rmn[8], rmx[8], cmn[8], cmx[8];
#pragma unroll
    for (int s = 0; s < 8; ++s) { rmn[s] = 3.4e38f; rmx[s] = 0.f; cmn[s] = 3.4e38f; cmx[s] = 0.f; }
#pragma unroll
    for (int mi = 0; mi < 2; ++mi)
#pragma unroll
        for (int nj = 0; nj < 8; ++nj)
#pragma unroll
            for (int r = 0; r < 4; ++r) {
                const int s = mi * 4 + r;
                const float t1 = __fadd_rn(esqR[s], esqC[nj]);
                const float d2 = fmaf(-0x1p-25f, acc[mi][nj][r], t1);
                const float d2c = fmaxf(d2, 0.f);
                rmn[s] = fminf(rmn[s], d2c);
                rmx[s] = fmaxf(rmx[s], d2c);
                cmn[nj] = fminf(cmn[nj], d2c);
                cmx[nj] = fmaxf(cmx[nj], d2c);
            }

    __syncthreads();
    float* Mx = (float*)smem;            // [128][LDM]
    float* Mn = (float*)(smem + 8704);
#pragma unroll
    for (int s = 0; s < 8; ++s) {
        const int rl = w * 32 + (s >> 2) * 16 + quad * 4 + (s & 3);
        Mx[rl * LDM + l15] = rmx[s];
        Mn[rl * LDM + l15] = rmn[s];
    }
    __syncthreads();
    if (t < BM) {
        float mx = Mx[t * LDM], mn = Mn[t * LDM];
#pragma unroll
        for (int c = 1; c < 16; ++c) {
            mx = fmaxf(mx, Mx[t * LDM + c]);
            mn = fminf(mn, Mn[t * LDM + c]);
        }
        atomicMax(&rmxg[row0 + t], __float_as_uint(mx));
        atomicMin(&rmng[row0 + t], __float_as_uint(mn));
    }
    __syncthreads();
#pragma unroll
    for (int nj = 0; nj < 8; ++nj) {
        const int cl = nj * 16 + l15;
        Mx[cl * LDM + w * 4 + quad] = cmx[nj];
        Mn[cl * LDM + w * 4 + quad] = cmn[nj];
    }
    __syncthreads();
    if (t < BM) {
        float mx = Mx[t * LDM], mn = Mn[t * LDM];
#pragma unroll
        for (int c = 1; c < 16; ++c) {
            mx = fmaxf(mx, Mx[t * LDM + c]);
            mn = fminf(mn, Mn[t * LDM + c]);
        }
        atomicMax(&rmxg[c0 + t], __float_as_uint(mx));
        atomicMin(&rmng[c0 + t], __float_as_uint(mn));
    }
}

__global__ __launch_bounds__(256) void k_mm_sum(const unsigned* __restrict__ rmxg,
                                                const unsigned* __restrict__ rmng,
                                                double* __restrict__ sums) {
    const int n = blockIdx.x * 256 + threadIdx.x;
    const float mx = sqrtf(__uint_as_float(rmxg[n]));
    const float mn = sqrtf(__uint_as_float(rmng[n]));
    float v = mx - mn;
    v = waveReduceSumF(v);
    __shared__ float part[4];
    if ((threadIdx.x & 63) == 0) part[threadIdx.x >> 6] = v;
    __syncthreads();
    if (threadIdx.x == 0)
        atomicAdd(&sums[2], (double)(part[0] + part[1] + part[2] + part[3]));
}

__global__ void k_final(const double* __restrict__ sums, float* __restrict__ out) {
    const double loss = 1.25 * (sums[1] / (double)((size_t)NZ * D));
    const double qq = 0.1 * (sums[2] / (double)NE) + 0.1 * sums[0];
    out[(size_t)NZ * D + NZ] = (float)loss;
    out[(size_t)NZ * D + NZ + 1] = (float)qq;
}

extern "C" void kernel_launch(void* const* d_in, const int* in_sizes, int n_in,
                              void* d_out, int out_size, void* d_ws, size_t ws_size,
                              hipStream_t stream) {
    const float* z = (const float*)d_in[0];
    const float* emb = (const float*)d_in[1];
    float* out = (float*)d_out;
    char* ws = (char*)d_ws;

    double* sums = (double*)(ws + WS_SUMS);
    int* cnt2 = (int*)(ws + WS_CNT2);
    float* zsq = (float*)(ws + WS_ZSQ);
    float* esq = (float*)(ws + WS_ESQ);
    int* idxb = (int*)(ws + WS_IDX);
    float* ps1 = (float*)(ws + WS_PS1);
    float* ps2 = (float*)(ws + WS_PS2);
    int* pix = (int*)(ws + WS_PIX);
    unsigned* rmx = (unsigned*)(ws + WS_RMX);
    unsigned* rmn = (unsigned*)(ws + WS_RMN);
    unsigned long long* pack = (unsigned long long*)(ws + WS_PACK);
    int* items = (int*)(ws + WS_ITEMS);
    _Float16* zh = (_Float16*)(ws + WS_ZH);
    _Float16* eh = (_Float16*)(ws + WS_EH);

    hipLaunchKernelGGL(k_init, dim3(1), dim3(1), 0, stream, sums, cnt2);
    hipLaunchKernelGGL(k_initmm, dim3(NZ / 256), dim3(256), 0, stream, rmx, rmn, pack);
    hipLaunchKernelGGL(k_rowsq, dim3(NZ / 256), dim3(256), 0, stream, z, zsq, (double*)nullptr);
    hipLaunchKernelGGL(k_rowsq, dim3(NE / 256), dim3(256), 0, stream, emb, esq, sums);
    hipLaunchKernelGGL(k_cvt_z, dim3(NZ * D / 4 / 256), dim3(256), 0, stream, z, zh);
    hipLaunchKernelGGL(k_cvt_e, dim3(NE * D / 4 / 256), dim3(256), 0, stream, emb, eh);
    hipLaunchKernelGGL(k_argmin_mfma, dim3(NZ / BM, NSPLIT_A), dim3(256), 0, stream,
                       zh, eh, zsq, esq, ps1, ps2, pix);
    hipLaunchKernelGGL(k_pairwise_mfma, dim3(NTRI), dim3(256), 0, stream,
                       eh, esq, rmx, rmn);
    hipLaunchKernelGGL(k_merge, dim3(NZ / 256), dim3(256), 0, stream,
                       ps1, ps2, pix, idxb, out + (size_t)NZ * D, cnt2, items);
    hipLaunchKernelGGL(k_fix_item, dim3(2048), dim3(256), 0, stream,
                       z, emb, zsq, esq, cnt2, items, pack);
    hipLaunchKernelGGL(k_fixdecode, dim3(NZ / 256), dim3(256), 0, stream,
                       pack, idxb, out + (size_t)NZ * D);
    hipLaunchKernelGGL(k_gather, dim3(NZ / 4), dim3(256), 0, stream,
                       z, emb, idxb, out, sums);
    hipLaunchKernelGGL(k_mm_sum, dim3(NE / 256), dim3(256), 0, stream,
                       rmx, rmn, sums);
    hipLaunchKernelGGL(k_final, dim3(1), dim3(1), 0, stream, sums, out);
}

// Round 7
// 829.580 us; speedup vs baseline: 1.3379x; 1.3379x over previous
//
#include <hip/hip_runtime.h>

#define D 256
#define NE 8192
#define NZ 16384
#define BM 128
#define BK 32
#define LDA (BM + 4)               // fp32 k-major LDS stride (k_fix_split)
#define NB (NE / BM)
#define NTRI (NB * (NB + 1) / 2)
#define NSPLIT_A 8
#define SPLIT_NA (NE / NSPLIT_A)   // 1024
#define GAPTH 6.0e-5f
#define LDH 40                     // fp16 LDS row stride
#define LDM 17                     // merge-phase LDS stride

// fp32-path LDS swizzle (verified R4/R5)
#define SROT(kk) (8 * ((((kk) >> 2)) & 3))
#define SWZR(kk, r) ((((r) + SROT(kk)) & 127))

typedef _Float16 f16x8 __attribute__((ext_vector_type(8)));
typedef _Float16 f16x4 __attribute__((ext_vector_type(4)));
typedef float f32x4 __attribute__((ext_vector_type(4)));

#define MFMA16(a, b, c) __builtin_amdgcn_mfma_f32_16x16x32_f16(a, b, c, 0, 0, 0)

// ---------------- workspace layout (bytes) ----------------
#define WS_SUMS   0                            // double[4]
#define WS_CNT8   64                           // int[8]: per-split repair counts
#define WS_ZSQ    256                          // float[NZ]
#define WS_ESQ    (WS_ZSQ + NZ * 4)            // float[NE]
#define WS_IDX    (WS_ESQ + NE * 4)            // int[NZ]
#define WS_PS1    (WS_IDX + NZ * 4)            // float[NZ*8]
#define WS_PS2    (WS_PS1 + NZ * NSPLIT_A * 4)
#define WS_PIX    (WS_PS2 + NZ * NSPLIT_A * 4)
#define WS_RMX    (WS_PIX + NZ * NSPLIT_A * 4) // uint[NE]
#define WS_RMN    (WS_RMX + NE * 4)            // uint[NE]
#define WS_PACK   (WS_RMN + NE * 4)            // u64[NZ]
#define WS_LISTS  (WS_PACK + NZ * 8)           // int[8][NZ]
#define WS_ZH     (WS_LISTS + NZ * NSPLIT_A * 4) // f16[NZ*D]
#define WS_EH     (WS_ZH + NZ * D * 2)           // f16[NE*D]

__device__ __forceinline__ float waveReduceSumF(float v) {
    v += __shfl_down(v, 32); v += __shfl_down(v, 16); v += __shfl_down(v, 8);
    v += __shfl_down(v, 4);  v += __shfl_down(v, 2);  v += __shfl_down(v, 1);
    return v;
}
__device__ __forceinline__ double waveReduceSumD(double v) {
    v += __shfl_down(v, 32); v += __shfl_down(v, 16); v += __shfl_down(v, 8);
    v += __shfl_down(v, 4);  v += __shfl_down(v, 2);  v += __shfl_down(v, 1);
    return v;
}

__global__ void k_init(double* sums, int* cnt8) {
    sums[0] = 0.0; sums[1] = 0.0; sums[2] = 0.0; sums[3] = 0.0;
#pragma unroll
    for (int s = 0; s < 8; ++s) cnt8[s] = 0;
}

__global__ __launch_bounds__(256) void k_initmm(unsigned* __restrict__ rmx,
                                                unsigned* __restrict__ rmn,
                                                unsigned long long* __restrict__ pack) {
    const int n = blockIdx.x * 256 + threadIdx.x;
    if (n < NE) { rmx[n] = 0u; rmn[n] = 0x7F800000u; }
    pack[n] = ~0ull;   // grid covers NZ
}

// np.sum(x*x, axis=1) bit-exact (numpy pairwise summation, n=256)
__global__ __launch_bounds__(256) void k_rowsq(const float* __restrict__ src,
                                               float* __restrict__ rsq,
                                               double* __restrict__ sums) {
    const int row = blockIdx.x * 256 + threadIdx.x;
    const float* p = src + (size_t)row * D;
    float h[2];
#pragma unroll
    for (int half = 0; half < 2; ++half) {
        const float* q = p + half * 128;
        float4 a0 = *(const float4*)&q[0];
        float4 a1 = *(const float4*)&q[4];
        float r0 = __fmul_rn(a0.x, a0.x);
        float r1 = __fmul_rn(a0.y, a0.y);
        float r2 = __fmul_rn(a0.z, a0.z);
        float r3 = __fmul_rn(a0.w, a0.w);
        float r4 = __fmul_rn(a1.x, a1.x);
        float r5 = __fmul_rn(a1.y, a1.y);
        float r6 = __fmul_rn(a1.z, a1.z);
        float r7 = __fmul_rn(a1.w, a1.w);
#pragma unroll
        for (int i = 8; i < 128; i += 8) {
            const float4 b0 = *(const float4*)&q[i];
            const float4 b1 = *(const float4*)&q[i + 4];
            r0 = __fadd_rn(r0, __fmul_rn(b0.x, b0.x));
            r1 = __fadd_rn(r1, __fmul_rn(b0.y, b0.y));
            r2 = __fadd_rn(r2, __fmul_rn(b0.z, b0.z));
            r3 = __fadd_rn(r3, __fmul_rn(b0.w, b0.w));
            r4 = __fadd_rn(r4, __fmul_rn(b1.x, b1.x));
            r5 = __fadd_rn(r5, __fmul_rn(b1.y, b1.y));
            r6 = __fadd_rn(r6, __fmul_rn(b1.z, b1.z));
            r7 = __fadd_rn(r7, __fmul_rn(b1.w, b1.w));
        }
        const float t01 = __fadd_rn(r0, r1);
        const float t23 = __fadd_rn(r2, r3);
        const float t45 = __fadd_rn(r4, r5);
        const float t67 = __fadd_rn(r6, r7);
        h[half] = __fadd_rn(__fadd_rn(t01, t23), __fadd_rn(t45, t67));
    }
    const float tot = __fadd_rn(h[0], h[1]);
    rsq[row] = tot;
    if (sums != nullptr) {
        double s = waveReduceSumD((double)tot);
        if ((threadIdx.x & 63) == 0) atomicAdd(&sums[0], s);
    }
}

// z -> fp16(z)
__global__ __launch_bounds__(256) void k_cvt_z(const float* __restrict__ z,
                                               _Float16* __restrict__ zh) {
    const size_t g = (size_t)blockIdx.x * 256 + threadIdx.x;
    const float4 x = *(const float4*)&z[g * 4];
    f16x4 hv;
    hv[0] = (_Float16)x.x; hv[1] = (_Float16)x.y;
    hv[2] = (_Float16)x.z; hv[3] = (_Float16)x.w;
    *(f16x4*)&zh[g * 4] = hv;
}

// e -> fp16(e * 2^13)
__global__ __launch_bounds__(256) void k_cvt_e(const float* __restrict__ e,
                                               _Float16* __restrict__ eh) {
    const size_t g = (size_t)blockIdx.x * 256 + threadIdx.x;
    const float4 x = *(const float4*)&e[g * 4];
    f16x4 hv;
    hv[0] = (_Float16)(x.x * 8192.0f); hv[1] = (_Float16)(x.y * 8192.0f);
    hv[2] = (_Float16)(x.z * 8192.0f); hv[3] = (_Float16)(x.w * 8192.0f);
    *(f16x4*)&eh[g * 4] = hv;
}

// ---- MFMA argmin pass: single zh*eh MFMA, top-2 per row per split ----
__global__ __launch_bounds__(256) void k_argmin_mfma(
        const _Float16* __restrict__ zh, const _Float16* __restrict__ eh,
        const float* __restrict__ zsq, const float* __restrict__ esq,
        float* __restrict__ ps1, float* __restrict__ ps2, int* __restrict__ pix) {
    __shared__ __align__(16) char smem[26112];
    _Float16* Ah = (_Float16*)smem;            // [128][LDH]
    _Float16* Bh = (_Float16*)(smem + 10240);  // [64][LDH]

    const int t = threadIdx.x;
    const int lane = t & 63;
    const int w = t >> 6;
    const int quad = lane >> 4;
    const int l15 = lane & 15;
    const int row0 = blockIdx.x * BM;
    const int sp = blockIdx.y;
    const int cb = sp * SPLIT_NA;
    const int wrow = row0 + w * 32;

    float zq[8];
#pragma unroll
    for (int mi = 0; mi < 2; ++mi)
#pragma unroll
        for (int r = 0; r < 4; ++r)
            zq[mi * 4 + r] = zsq[wrow + mi * 16 + quad * 4 + r];

    float b1[8], b2[8];
    int i1[8];
#pragma unroll
    for (int s = 0; s < 8; ++s) { b1[s] = 3.4e38f; b2[s] = 3.4e38f; i1[s] = 0; }

    const int br = t >> 2;
    const int bseg = t & 3;

    for (int ch = 0; ch < 16; ++ch) {
        const int c0 = cb + ch * 64;

        f32x4 acc[2][4];
#pragma unroll
        for (int mi = 0; mi < 2; ++mi)
#pragma unroll
            for (int nj = 0; nj < 4; ++nj) acc[mi][nj] = (f32x4){0.f, 0.f, 0.f, 0.f};

        for (int kb = 0; kb < D; kb += BK) {
            __syncthreads();
#pragma unroll
            for (int uu = 0; uu < 2; ++uu) {
                const int u = t + uu * 256;
                const int r = u >> 2, seg = u & 3;
                *(uint4*)&Ah[r * LDH + seg * 8] =
                    *(const uint4*)&zh[(size_t)(row0 + r) * D + kb + seg * 8];
            }
            *(uint4*)&Bh[br * LDH + bseg * 8] =
                *(const uint4*)&eh[(size_t)(c0 + br) * D + kb + bseg * 8];
            __syncthreads();

            f16x8 ah[2], bh[4];
#pragma unroll
            for (int mi = 0; mi < 2; ++mi)
                ah[mi] = *(const f16x8*)&Ah[(w * 32 + mi * 16 + l15) * LDH + quad * 8];
#pragma unroll
            for (int nj = 0; nj < 4; ++nj)
                bh[nj] = *(const f16x8*)&Bh[(nj * 16 + l15) * LDH + quad * 8];
#pragma unroll
            for (int mi = 0; mi < 2; ++mi)
#pragma unroll
                for (int nj = 0; nj < 4; ++nj)
                    acc[mi][nj] = MFMA16(ah[mi], bh[nj], acc[mi][nj]);
        }

#pragma unroll
        for (int nj = 0; nj < 4; ++nj) {
            const int gcol = c0 + nj * 16 + l15;
            const float eqv = esq[gcol];
#pragma unroll
            for (int mi = 0; mi < 2; ++mi)
#pragma unroll
                for (int r = 0; r < 4; ++r) {
                    const int s = mi * 4 + r;
                    const float t1 = __fadd_rn(zq[s], eqv);
                    const float v = __fsub_rn(t1, zq[s]);      // exact (Sterbenz)
                    const float sc = fmaf(acc[mi][nj][r], -0x1p-12f, v);
                    if (sc < b1[s]) { b2[s] = b1[s]; b1[s] = sc; i1[s] = gcol; }
                    else if (sc < b2[s]) b2[s] = sc;
                }
        }
    }

    __syncthreads();
    float* MB1 = (float*)smem;             // [128][17]
    float* MB2 = (float*)(smem + 8704);
    int*   MI  = (int*)(smem + 17408);
#pragma unroll
    for (int s = 0; s < 8; ++s) {
        const int rl = w * 32 + (s >> 2) * 16 + quad * 4 + (s & 3);
        MB1[rl * LDM + l15] = b1[s];
        MB2[rl * LDM + l15] = b2[s];
        MI[rl * LDM + l15] = i1[s];
    }
    __syncthreads();
    if (t < BM) {
        float v1 = MB1[t * LDM], v2 = MB2[t * LDM];
        int ii1 = MI[t * LDM];
#pragma unroll
        for (int c = 1; c < 16; ++c) {
            const float s1 = MB1[t * LDM + c];
            const float s2 = MB2[t * LDM + c];
            const int ii = MI[t * LDM + c];
            if (s1 < v1 || (s1 == v1 && ii < ii1)) {
                v2 = fminf(fminf(v2, v1), s2);
                v1 = s1; ii1 = ii;
            } else {
                v2 = fminf(v2, s1);
            }
        }
        ps1[(size_t)(row0 + t) * NSPLIT_A + sp] = v1;
        ps2[(size_t)(row0 + t) * NSPLIT_A + sp] = v2;
        pix[(size_t)(row0 + t) * NSPLIT_A + sp] = ii1;
    }
}

// merge splits; provisional idx; append near-tie rows to candidate-split lists
__global__ __launch_bounds__(256) void k_merge(const float* __restrict__ ps1,
                                               const float* __restrict__ ps2,
                                               const int* __restrict__ pi,
                                               int* __restrict__ idxbuf,
                                               float* __restrict__ outidx,
                                               int* __restrict__ cnt8,
                                               int* __restrict__ lists) {
    const int n = blockIdx.x * 256 + threadIdx.x;
    float v1 = ps1[n * NSPLIT_A];
    float v2 = ps2[n * NSPLIT_A];
    int ii1 = pi[n * NSPLIT_A];
#pragma unroll
    for (int s = 1; s < NSPLIT_A; ++s) {
        const float s1 = ps1[n * NSPLIT_A + s];
        const float s2 = ps2[n * NSPLIT_A + s];
        const int ii = pi[n * NSPLIT_A + s];
        if (s1 < v1 || (s1 == v1 && ii < ii1)) {
            v2 = fminf(fminf(v2, v1), s2);
            v1 = s1; ii1 = ii;
        } else {
            v2 = fminf(v2, s1);
        }
    }
    idxbuf[n] = ii1;
    outidx[n] = (float)ii1;
    if (v2 - v1 < GAPTH) {
        const float lim = v1 + GAPTH;
#pragma unroll
        for (int s = 0; s < NSPLIT_A; ++s)
            if (ps1[n * NSPLIT_A + s] <= lim) {
                const int p = atomicAdd(&cnt8[s], 1);
                lists[s * NZ + p] = n;
            }
    }
}

// np-bit-exact fp32 repair: gathered flagged rows x this split's 1024 cols
__global__ __launch_bounds__(256) void k_fix_split(const float* __restrict__ z,
                                                   const float* __restrict__ emb,
                                                   const float* __restrict__ zsq,
                                                   const float* __restrict__ esq,
                                                   const int* __restrict__ cnt8,
                                                   const int* __restrict__ lists,
                                                   unsigned long long* __restrict__ pack) {
    __shared__ float As[BK * LDA];
    __shared__ float Bs[BK * LDA];
    __shared__ float Sq[BM];
    __shared__ int frow[BM];

    const int s = blockIdx.y;
    const int ns = cnt8[s];
    const int cbase = s * SPLIT_NA;
    const int t = threadIdx.x;
    const int tr = t >> 4;
    const int tc = t & 15;
    const int sr = t >> 3;
    const int skq = t & 7;
    const int wrot = 8 * (skq & 3);

    for (int rb = blockIdx.x; rb * BM < ns; rb += gridDim.x) {
        __syncthreads();
        if (t < BM) {
            const int fi = rb * BM + t;
            frow[t] = (fi < ns) ? lists[s * NZ + fi] : lists[s * NZ];
        }
        __syncthreads();

        float zqr[8];
#pragma unroll
        for (int i = 0; i < 8; ++i) zqr[i] = zsq[frow[tr * 8 + i]];

        float best[8];
        int bidx[8];
#pragma unroll
        for (int i = 0; i < 8; ++i) { best[i] = 3.4e38f; bidx[i] = 0; }

        for (int ch = 0; ch < 8; ++ch) {
            const int c0 = cbase + ch * BM;
            if (t < BM) Sq[t] = esq[c0 + t];

            float acc[8][8];
#pragma unroll
            for (int i = 0; i < 8; ++i)
#pragma unroll
                for (int j = 0; j < 8; ++j) acc[i][j] = 0.f;

            for (int kb = 0; kb < D; kb += BK) {
                __syncthreads();
#pragma unroll
                for (int q = 0; q < 4; ++q) {
                    const int r = sr + 32 * q;
                    const int rr = (r + wrot) & 127;
                    const float4 av = *(const float4*)&z[(size_t)frow[r] * D + kb + 4 * skq];
                    const float4 bv = *(const float4*)&emb[(size_t)(c0 + r) * D + kb + 4 * skq];
                    As[(4 * skq + 0) * LDA + rr] = av.x;
                    As[(4 * skq + 1) * LDA + rr] = av.y;
                    As[(4 * skq + 2) * LDA + rr] = av.z;
                    As[(4 * skq + 3) * LDA + rr] = av.w;
                    Bs[(4 * skq + 0) * LDA + rr] = bv.x;
                    Bs[(4 * skq + 1) * LDA + rr] = bv.y;
                    Bs[(4 * skq + 2) * LDA + rr] = bv.z;
                    Bs[(4 * skq + 3) * LDA + rr] = bv.w;
                }
                __syncthreads();
#pragma unroll
                for (int k = 0; k < BK; ++k) {
                    const float4 a0 = *(const float4*)&As[k * LDA + SWZR(k, tr * 8)];
                    const float4 a1 = *(const float4*)&As[k * LDA + SWZR(k, tr * 8 + 4)];
                    const float4 b0 = *(const float4*)&Bs[k * LDA + SWZR(k, tc * 4)];
                    const float4 b1 = *(const float4*)&Bs[k * LDA + SWZR(k, 64 + tc * 4)];
                    const float a[8] = {a0.x, a0.y, a0.z, a0.w, a1.x, a1.y, a1.z, a1.w};
                    const float b[8] = {b0.x, b0.y, b0.z, b0.w, b1.x, b1.y, b1.z, b1.w};
#pragma unroll
                    for (int i = 0; i < 8; ++i)
#pragma unroll
                        for (int j = 0; j < 8; ++j)
                            acc[i][j] = fmaf(a[i], b[j], acc[i][j]);
                }
            }
#pragma unroll
            for (int jj = 0; jj < 8; ++jj) {
                const int cloc = (jj < 4) ? (tc * 4 + jj) : (64 + tc * 4 + (jj - 4));
                const float sq = Sq[cloc];
                const int gcol = c0 + cloc;
#pragma unroll
                for (int i = 0; i < 8; ++i) {
                    const float t1 = __fadd_rn(zqr[i], sq);
                    const float sc = fmaf(-2.f, acc[i][jj], t1);
                    if (sc < best[i]) { best[i] = sc; bidx[i] = gcol; }
                }
            }
            __syncthreads();
        }

        // per-row merge (LDS reuse), then cross-split merge via packed atomicMin
        float* Rs = As;
        int* Ri = (int*)Bs;
#pragma unroll
        for (int i = 0; i < 8; ++i) {
            Rs[(tr * 8 + i) * LDM + tc] = best[i];
            Ri[(tr * 8 + i) * LDM + tc] = bidx[i];
        }
        __syncthreads();
        if (t < BM) {
            float bs = Rs[t * LDM];
            int bi = Ri[t * LDM];
#pragma unroll
            for (int c = 1; c < 16; ++c) {
                const float sc = Rs[t * LDM + c];
                const int ii = Ri[t * LDM + c];
                if (sc < bs || (sc == bs && ii < bi)) { bs = sc; bi = ii; }
            }
            const int fi = rb * BM + t;
            if (fi < ns) {
                const unsigned long long pk =
                    ((unsigned long long)__float_as_uint(bs) << 32) | (unsigned)bi;
                atomicMin(&pack[frow[t]], pk);
            }
        }
    }
}

__global__ __launch_bounds__(256) void k_fixdecode(const unsigned long long* __restrict__ pack,
                                                   int* __restrict__ idxbuf,
                                                   float* __restrict__ outidx) {
    const int n = blockIdx.x * 256 + threadIdx.x;
    const unsigned long long p = pack[n];
    if (p != ~0ull) {
        const int idx = (int)(p & 0xffffffffu);
        idxbuf[n] = idx;
        outidx[n] = (float)idx;
    }
}

__global__ __launch_bounds__(256) void k_gather(const float* __restrict__ z,
                                                const float* __restrict__ emb,
                                                const int* __restrict__ idxbuf,
                                                float* __restrict__ out,
                                                double* __restrict__ sums) {
    const int row = blockIdx.x * 4 + (threadIdx.x >> 6);
    const int lane = threadIdx.x & 63;
    const int idx = idxbuf[row];
    const float4 e4 = *(const float4*)&emb[(size_t)idx * D + lane * 4];
    const float4 z4 = *(const float4*)&z[(size_t)row * D + lane * 4];
    *(float4*)&out[(size_t)row * D + lane * 4] = e4;
    const float dx = e4.x - z4.x, dy = e4.y - z4.y;
    const float dzv = e4.z - z4.z, dw = e4.w - z4.w;
    float s = dx * dx + dy * dy + dzv * dzv + dw * dw;
    s = waveReduceSumF(s);
    if (lane == 0) atomicAdd(&sums[1], (double)s);
}

// ---- pairwise cdist row min/max via fp16 MFMA, triangular tiles ----
__global__ __launch_bounds__(256) void k_pairwise_mfma(const _Float16* __restrict__ eh,
                                                       const float* __restrict__ esq,
                                                       unsigned* __restrict__ rmxg,
                                                       unsigned* __restrict__ rmng) {
    __shared__ __align__(16) char smem[20480];
    _Float16* Ah = (_Float16*)smem;            // [128][LDH]
    _Float16* Bh = (_Float16*)(smem + 10240);  // [128][LDH]

    int p = blockIdx.x;
    int bi = 0;
    while (p >= NB - bi) { p -= NB - bi; ++bi; }
    const int bj = bi + p;
    const int row0 = bi * BM;
    const int c0 = bj * BM;

    const int t = threadIdx.x;
    const int lane = t & 63;
    const int w = t >> 6;
    const int quad = lane >> 4;
    const int l15 = lane & 15;

    float esqR[8], esqC[8];
#pragma unroll
    for (int mi = 0; mi < 2; ++mi)
#pragma unroll
        for (int r = 0; r < 4; ++r)
            esqR[mi * 4 + r] = esq[row0 + w * 32 + mi * 16 + quad * 4 + r];
#pragma unroll
    for (int nj = 0; nj < 8; ++nj) esqC[nj] = esq[c0 + nj * 16 + l15];

    f32x4 acc[2][8];
#pragma unroll
    for (int mi = 0; mi < 2; ++mi)
#pragma unroll
        for (int nj = 0; nj < 8; ++nj) acc[mi][nj] = (f32x4){0.f, 0.f, 0.f, 0.f};

    for (int kb = 0; kb < D; kb += BK) {
        __syncthreads();
#pragma unroll
        for (int uu = 0; uu < 2; ++uu) {
            const int u = t + uu * 256;
            const int r = u >> 2, seg = u & 3;
            *(uint4*)&Ah[r * LDH + seg * 8] =
                *(const uint4*)&eh[(size_t)(row0 + r) * D + kb + seg * 8];
            *(uint4*)&Bh[r * LDH + seg * 8] =
                *(const uint4*)&eh[(size_t)(c0 + r) * D + kb + seg * 8];
        }
        __syncthreads();

        f16x8 ah[2], bh[8];
#pragma unroll
        for (int mi = 0; mi < 2; ++mi)
            ah[mi] = *(const f16x8*)&Ah[(w * 32 + mi * 16 + l15) * LDH + quad * 8];
#pragma unroll
        for (int nj = 0; nj < 8; ++nj)
            bh[nj] = *(const f16x8*)&Bh[(nj * 16 + l15) * LDH + quad * 8];
#pragma unroll
        for (int mi = 0; mi < 2; ++mi)
#pragma unroll
            for (int nj = 0; nj < 8; ++nj)
                acc[mi][nj] = MFMA16(ah[mi], bh[nj], acc[mi][nj]);
    }

    float rmn[8], rmx[8], cmn[8], cmx[8];
#pragma unroll
    for (int s = 0; s < 8; ++s) { rmn[s] = 3.4e38f; rmx[s] = 0.f; cmn[s] = 3.4e38f; cmx[s] = 0.f; }
#pragma unroll
    for (int mi = 0; mi < 2; ++mi)
#pragma unroll
        for (int nj = 0; nj < 8; ++nj)
#pragma unroll
            for (int r = 0; r < 4; ++r) {
                const int s = mi * 4 + r;
                const float t1 = __fadd_rn(esqR[s], esqC[nj]);
                const float d2 = fmaf(-0x1p-25f, acc[mi][nj][r], t1);
                const float d2c = fmaxf(d2, 0.f);
                rmn[s] = fminf(rmn[s], d2c);
                rmx[s] = fmaxf(rmx[s], d2c);
                cmn[nj] = fminf(cmn[nj], d2c);
                cmx[nj] = fmaxf(cmx[nj], d2c);
            }

    __syncthreads();
    float* Mx = (float*)smem;            // [128][LDM]
    float* Mn = (float*)(smem + 8704);
#pragma unroll
    for (int s = 0; s < 8; ++s) {
        const int rl = w * 32 + (s >> 2) * 16 + quad * 4 + (s & 3);
        Mx[rl * LDM + l15] = rmx[s];
        Mn[rl * LDM + l15] = rmn[s];
    }
    __syncthreads();
    if (t < BM) {
        float mx = Mx[t * LDM], mn = Mn[t * LDM];
#pragma unroll
        for (int c = 1; c < 16; ++c) {
            mx = fmaxf(mx, Mx[t * LDM + c]);
            mn = fminf(mn, Mn[t * LDM + c]);
        }
        atomicMax(&rmxg[row0 + t], __float_as_uint(mx));
        atomicMin(&rmng[row0 + t], __float_as_uint(mn));
    }
    __syncthreads();
#pragma unroll
    for (int nj = 0; nj < 8; ++nj) {
        const int cl = nj * 16 + l15;
        Mx[cl * LDM + w * 4 + quad] = cmx[nj];
        Mn[cl * LDM + w * 4 + quad] = cmn[nj];
    }
    __syncthreads();
    if (t < BM) {
        float mx = Mx[t * LDM], mn = Mn[t * LDM];
#pragma unroll
        for (int c = 1; c < 16; ++c) {
            mx = fmaxf(mx, Mx[t * LDM + c]);
            mn = fminf(mn, Mn[t * LDM + c]);
        }
        atomicMax(&rmxg[c0 + t], __float_as_uint(mx));
        atomicMin(&rmng[c0 + t], __float_as_uint(mn));
    }
}

__global__ __launch_bounds__(256) void k_mm_sum(const unsigned* __restrict__ rmxg,
                                                const unsigned* __restrict__ rmng,
                                                double* __restrict__ sums) {
    const int n = blockIdx.x * 256 + threadIdx.x;
    const float mx = sqrtf(__uint_as_float(rmxg[n]));
    const float mn = sqrtf(__uint_as_float(rmng[n]));
    float v = mx - mn;
    v = waveReduceSumF(v);
    __shared__ float part[4];
    if ((threadIdx.x & 63) == 0) part[threadIdx.x >> 6] = v;
    __syncthreads();
    if (threadIdx.x == 0)
        atomicAdd(&sums[2], (double)(part[0] + part[1] + part[2] + part[3]));
}

__global__ void k_final(const double* __restrict__ sums, float* __restrict__ out) {
    const double loss = 1.25 * (sums[1] / (double)((size_t)NZ * D));
    const double qq = 0.1 * (sums[2] / (double)NE) + 0.1 * sums[0];
    out[(size_t)NZ * D + NZ] = (float)loss;
    out[(size_t)NZ * D + NZ + 1] = (float)qq;
}

extern "C" void kernel_launch(void* const* d_in, const int* in_sizes, int n_in,
                              void* d_out, int out_size, void* d_ws, size_t ws_size,
                              hipStream_t stream) {
    const float* z = (const float*)d_in[0];
    const float* emb = (const float*)d_in[1];
    float* out = (float*)d_out;
    char* ws = (char*)d_ws;

    double* sums = (double*)(ws + WS_SUMS);
    int* cnt8 = (int*)(ws + WS_CNT8);
    float* zsq = (float*)(ws + WS_ZSQ);
    float* esq = (float*)(ws + WS_ESQ);
    int* idxb = (int*)(ws + WS_IDX);
    float* ps1 = (float*)(ws + WS_PS1);
    float* ps2 = (float*)(ws + WS_PS2);
    int* pix = (int*)(ws + WS_PIX);
    unsigned* rmx = (unsigned*)(ws + WS_RMX);
    unsigned* rmn = (unsigned*)(ws + WS_RMN);
    unsigned long long* pack = (unsigned long long*)(ws + WS_PACK);
    int* lists = (int*)(ws + WS_LISTS);
    _Float16* zh = (_Float16*)(ws + WS_ZH);
    _Float16* eh = (_Float16*)(ws + WS_EH);

    hipLaunchKernelGGL(k_init, dim3(1), dim3(1), 0, stream, sums, cnt8);
    hipLaunchKernelGGL(k_initmm, dim3(NZ / 256), dim3(256), 0, stream, rmx, rmn, pack);
    hipLaunchKernelGGL(k_rowsq, dim3(NZ / 256), dim3(256), 0, stream, z, zsq, (double*)nullptr);
    hipLaunchKernelGGL(k_rowsq, dim3(NE / 256), dim3(256), 0, stream, emb, esq, sums);
    hipLaunchKernelGGL(k_cvt_z, dim3(NZ * D / 4 / 256), dim3(256), 0, stream, z, zh);
    hipLaunchKernelGGL(k_cvt_e, dim3(NE * D / 4 / 256), dim3(256), 0, stream, emb, eh);
    hipLaunchKernelGGL(k_argmin_mfma, dim3(NZ / BM, NSPLIT_A), dim3(256), 0, stream,
                       zh, eh, zsq, esq, ps1, ps2, pix);
    hipLaunchKernelGGL(k_pairwise_mfma, dim3(NTRI), dim3(256), 0, stream,
                       eh, esq, rmx, rmn);
    hipLaunchKernelGGL(k_merge, dim3(NZ / 256), dim3(256), 0, stream,
                       ps1, ps2, pix, idxb, out + (size_t)NZ * D, cnt8, lists);
    hipLaunchKernelGGL(k_fix_split, dim3(8, 8), dim3(256), 0, stream,
                       z, emb, zsq, esq, cnt8, lists, pack);
    hipLaunchKernelGGL(k_fixdecode, dim3(NZ / 256), dim3(256), 0, stream,
                       pack, idxb, out + (size_t)NZ * D);
    hipLaunchKernelGGL(k_gather, dim3(NZ / 4), dim3(256), 0, stream,
                       z, emb, idxb, out, sums);
    hipLaunchKernelGGL(k_mm_sum, dim3(NE / 256), dim3(256), 0, stream,
                       rmx, rmn, sums);
    hipLaunchKernelGGL(k_final, dim3(1), dim3(1), 0, stream, sums, out);
}

// Round 8
// 803.967 us; speedup vs baseline: 1.3805x; 1.0319x over previous
//
#include <hip/hip_runtime.h>

#define D 256
#define DA 288                     // augmented K (one extra 32-block)
#define NKB 9                      // DA/32
#define NKB_P 8                    // pairwise uses un-augmented 256
#define NE 8192
#define NZ 16384
#define BM 128
#define BK 32
#define LDA (BM + 4)               // fp32 k-major LDS stride (k_fix_split)
#define NB (NE / BM)
#define NTRI (NB * (NB + 1) / 2)
#define NSPLIT_A 8
#define SPLIT_NA (NE / NSPLIT_A)   // 1024
#define GAPTH_A 0.4096f            // 1e-4 score units * 2^12 (acc units)
#define LDM 17

// fp32-path LDS swizzle (verified R4-R7, k_fix_split only)
#define SROT(kk) (8 * ((((kk) >> 2)) & 3))
#define SWZR(kk, r) ((((r) + SROT(kk)) & 127))

typedef _Float16 f16x8 __attribute__((ext_vector_type(8)));
typedef _Float16 f16x4 __attribute__((ext_vector_type(4)));
typedef float f32x4 __attribute__((ext_vector_type(4)));

#define MFMA16(a, b, c) __builtin_amdgcn_mfma_f32_16x16x32_f16(a, b, c, 0, 0, 0)

// ---------------- workspace layout (bytes) ----------------
#define WS_SUMS   0                            // double[4]
#define WS_CNT8   64                           // int[8]
#define WS_ZSQ    256                          // float[NZ]
#define WS_ESQ    (WS_ZSQ + NZ * 4)            // float[NE]
#define WS_IDX    (WS_ESQ + NE * 4)            // int[NZ]
#define WS_PS1    (WS_IDX + NZ * 4)            // float[NZ*8]
#define WS_PS2    (WS_PS1 + NZ * NSPLIT_A * 4)
#define WS_PIX    (WS_PS2 + NZ * NSPLIT_A * 4)
#define WS_RMX    (WS_PIX + NZ * NSPLIT_A * 4) // uint[NE]
#define WS_RMN    (WS_RMX + NE * 4)            // uint[NE]
#define WS_PACK   (WS_RMN + NE * 4)            // u64[NZ]
#define WS_LISTS  (WS_PACK + NZ * 8)           // int[8][NZ]
#define WS_ZHF    (WS_LISTS + NZ * NSPLIT_A * 4)   // frag-major f16 z (NZ/16*9*64*8)
#define WS_EHF    (WS_ZHF + (NZ / 16) * NKB * 64 * 8 * 2)

__device__ __forceinline__ float waveReduceSumF(float v) {
    v += __shfl_down(v, 32); v += __shfl_down(v, 16); v += __shfl_down(v, 8);
    v += __shfl_down(v, 4);  v += __shfl_down(v, 2);  v += __shfl_down(v, 1);
    return v;
}
__device__ __forceinline__ double waveReduceSumD(double v) {
    v += __shfl_down(v, 32); v += __shfl_down(v, 16); v += __shfl_down(v, 8);
    v += __shfl_down(v, 4);  v += __shfl_down(v, 2);  v += __shfl_down(v, 1);
    return v;
}

__global__ void k_init(double* sums, int* cnt8) {
    sums[0] = 0.0; sums[1] = 0.0; sums[2] = 0.0; sums[3] = 0.0;
#pragma unroll
    for (int s = 0; s < 8; ++s) cnt8[s] = 0;
}

__global__ __launch_bounds__(256) void k_initmm(unsigned* __restrict__ rmx,
                                                unsigned* __restrict__ rmn,
                                                unsigned long long* __restrict__ pack) {
    const int n = blockIdx.x * 256 + threadIdx.x;
    if (n < NE) { rmx[n] = 0u; rmn[n] = 0x7F800000u; }
    pack[n] = ~0ull;
}

// np.sum(x*x, axis=1) bit-exact (numpy pairwise summation, n=256)
__global__ __launch_bounds__(256) void k_rowsq(const float* __restrict__ src,
                                               float* __restrict__ rsq,
                                               double* __restrict__ sums) {
    const int row = blockIdx.x * 256 + threadIdx.x;
    const float* p = src + (size_t)row * D;
    float h[2];
#pragma unroll
    for (int half = 0; half < 2; ++half) {
        const float* q = p + half * 128;
        float4 a0 = *(const float4*)&q[0];
        float4 a1 = *(const float4*)&q[4];
        float r0 = __fmul_rn(a0.x, a0.x);
        float r1 = __fmul_rn(a0.y, a0.y);
        float r2 = __fmul_rn(a0.z, a0.z);
        float r3 = __fmul_rn(a0.w, a0.w);
        float r4 = __fmul_rn(a1.x, a1.x);
        float r5 = __fmul_rn(a1.y, a1.y);
        float r6 = __fmul_rn(a1.z, a1.z);
        float r7 = __fmul_rn(a1.w, a1.w);
#pragma unroll
        for (int i = 8; i < 128; i += 8) {
            const float4 b0 = *(const float4*)&q[i];
            const float4 b1 = *(const float4*)&q[i + 4];
            r0 = __fadd_rn(r0, __fmul_rn(b0.x, b0.x));
            r1 = __fadd_rn(r1, __fmul_rn(b0.y, b0.y));
            r2 = __fadd_rn(r2, __fmul_rn(b0.z, b0.z));
            r3 = __fadd_rn(r3, __fmul_rn(b0.w, b0.w));
            r4 = __fadd_rn(r4, __fmul_rn(b1.x, b1.x));
            r5 = __fadd_rn(r5, __fmul_rn(b1.y, b1.y));
            r6 = __fadd_rn(r6, __fmul_rn(b1.z, b1.z));
            r7 = __fadd_rn(r7, __fmul_rn(b1.w, b1.w));
        }
        const float t01 = __fadd_rn(r0, r1);
        const float t23 = __fadd_rn(r2, r3);
        const float t45 = __fadd_rn(r4, r5);
        const float t67 = __fadd_rn(r6, r7);
        h[half] = __fadd_rn(__fadd_rn(t01, t23), __fadd_rn(t45, t67));
    }
    const float tot = __fadd_rn(h[0], h[1]);
    rsq[row] = tot;
    if (sums != nullptr) {
        double s = waveReduceSumD((double)tot);
        if ((threadIdx.x & 63) == 0) atomicAdd(&sums[0], s);
    }
}

// ---- fragment-major converters (64 rows per block, LDS transpose) ----
// frag layout: frag[rb][kb][lane] = X[rb*16 + (lane&15)][kb*32 + (lane>>4)*8 .. +7]
__global__ __launch_bounds__(256) void k_cvt_zf(const float* __restrict__ z,
                                                f16x8* __restrict__ zf) {
    __shared__ _Float16 Ls[64 * 296];
    const int t = threadIdx.x;
    const int row0 = blockIdx.x * 64;
#pragma unroll
    for (int i = 0; i < 16; ++i) {
        const int f4 = i * 256 + t;
        const int r = f4 >> 6, c4 = f4 & 63;
        const float4 v = *(const float4*)&z[(size_t)(row0 + r) * D + c4 * 4];
        f16x4 h;
        h[0] = (_Float16)v.x; h[1] = (_Float16)v.y;
        h[2] = (_Float16)v.z; h[3] = (_Float16)v.w;
        *(f16x4*)&Ls[r * 296 + c4 * 4] = h;
    }
#pragma unroll
    for (int i = 0; i < 8; ++i) {
        const int idx = i * 256 + t;
        const int r = idx >> 5, c = idx & 31;
        Ls[r * 296 + 256 + c] = (c == 0) ? (_Float16)1.0f : (_Float16)0.0f;
    }
    __syncthreads();
    const int l = t & 63, w = t >> 6;
#pragma unroll
    for (int kb = 0; kb < NKB; ++kb) {
        const f16x8 fr = *(const f16x8*)&Ls[(w * 16 + (l & 15)) * 296 + kb * 32 + (l >> 4) * 8];
        zf[((size_t)(blockIdx.x * 4 + w) * NKB + kb) * 64 + l] = fr;
    }
}

__global__ __launch_bounds__(256) void k_cvt_ef(const float* __restrict__ e,
                                                const float* __restrict__ esq,
                                                f16x8* __restrict__ ef) {
    __shared__ _Float16 Ls[64 * 296];
    const int t = threadIdx.x;
    const int row0 = blockIdx.x * 64;
#pragma unroll
    for (int i = 0; i < 16; ++i) {
        const int f4 = i * 256 + t;
        const int r = f4 >> 6, c4 = f4 & 63;
        const float4 v = *(const float4*)&e[(size_t)(row0 + r) * D + c4 * 4];
        f16x4 h;
        h[0] = (_Float16)(v.x * 8192.0f); h[1] = (_Float16)(v.y * 8192.0f);
        h[2] = (_Float16)(v.z * 8192.0f); h[3] = (_Float16)(v.w * 8192.0f);
        *(f16x4*)&Ls[r * 296 + c4 * 4] = h;
    }
#pragma unroll
    for (int i = 0; i < 8; ++i) {
        const int idx = i * 256 + t;
        const int r = idx >> 5, c = idx & 31;
        Ls[r * 296 + 256 + c] =
            (c == 0) ? (_Float16)(esq[row0 + r] * -4096.0f) : (_Float16)0.0f;
    }
    __syncthreads();
    const int l = t & 63, w = t >> 6;
#pragma unroll
    for (int kb = 0; kb < NKB; ++kb) {
        const f16x8 fr = *(const f16x8*)&Ls[(w * 16 + (l & 15)) * 296 + kb * 32 + (l >> 4) * 8];
        ef[((size_t)(blockIdx.x * 4 + w) * NKB + kb) * 64 + l] = fr;
    }
}

// ---- LDS-free MFMA argmin: acc = (dot - esq/2)*2^13, argmin score = argmax acc ----
__global__ __launch_bounds__(256) void k_argmin_f(
        const f16x8* __restrict__ zf, const f16x8* __restrict__ ef,
        float* __restrict__ ps1, float* __restrict__ ps2, int* __restrict__ pix) {
    const int t = threadIdx.x;
    const int l = t & 63;
    const int w = t >> 6;
    const int quad = l >> 4;
    const int l15 = l & 15;
    const int row0 = blockIdx.x * BM;
    const int sp = blockIdx.y;
    const int arb0 = blockIdx.x * 8 + w * 2;

    float b1[8], b2[8];
    int i1[8];
#pragma unroll
    for (int s = 0; s < 8; ++s) { b1[s] = -3.4e38f; b2[s] = -3.4e38f; i1[s] = 0; }

    for (int ch = 0; ch < 16; ++ch) {
        const int cb16 = sp * 64 + ch * 4;
        const int c0 = sp * SPLIT_NA + ch * 64;

        f32x4 acc[2][4];
#pragma unroll
        for (int mi = 0; mi < 2; ++mi)
#pragma unroll
            for (int nj = 0; nj < 4; ++nj) acc[mi][nj] = (f32x4){0.f, 0.f, 0.f, 0.f};

#pragma unroll
        for (int kb = 0; kb < NKB; ++kb) {
            const f16x8 ah0 = zf[((size_t)arb0 * NKB + kb) * 64 + l];
            const f16x8 ah1 = zf[((size_t)(arb0 + 1) * NKB + kb) * 64 + l];
            f16x8 bh[4];
#pragma unroll
            for (int nj = 0; nj < 4; ++nj)
                bh[nj] = ef[((size_t)(cb16 + nj) * NKB + kb) * 64 + l];
#pragma unroll
            for (int nj = 0; nj < 4; ++nj) {
                acc[0][nj] = MFMA16(ah0, bh[nj], acc[0][nj]);
                acc[1][nj] = MFMA16(ah1, bh[nj], acc[1][nj]);
            }
        }

        // top-2 max of acc (cols ascending per lane subset)
#pragma unroll
        for (int nj = 0; nj < 4; ++nj) {
            const int gcol = c0 + nj * 16 + l15;
#pragma unroll
            for (int mi = 0; mi < 2; ++mi)
#pragma unroll
                for (int r = 0; r < 4; ++r) {
                    const int s = mi * 4 + r;
                    const float a = acc[mi][nj][r];
                    b2[s] = fmaxf(b2[s], fminf(a, b1[s]));
                    i1[s] = (a > b1[s]) ? gcol : i1[s];
                    b1[s] = fmaxf(b1[s], a);
                }
        }
    }

    // cross-lane top-2 merge across the 16 lanes of each quad group
    float V1[8], V2[8];
    int II[8];
#pragma unroll
    for (int s = 0; s < 8; ++s) {
        float v1 = b1[s], v2 = b2[s];
        int ii = i1[s];
#pragma unroll
        for (int m = 1; m <= 8; m <<= 1) {
            const float o1 = __shfl_xor(v1, m);
            const float o2 = __shfl_xor(v2, m);
            const int oi = __shfl_xor(ii, m);
            const float n2 = fmaxf(fminf(v1, o1), fmaxf(v2, o2));
            const bool take = (o1 > v1) || (o1 == v1 && oi < ii);
            ii = take ? oi : ii;
            v1 = fmaxf(v1, o1);
            v2 = n2;
        }
        V1[s] = v1; V2[s] = v2; II[s] = ii;
    }
    if (l15 == 0) {
#pragma unroll
        for (int s = 0; s < 8; ++s) {
            const int mi = s >> 2, r = s & 3;
            const int row = row0 + w * 32 + mi * 16 + quad * 4 + r;
            ps1[(size_t)row * NSPLIT_A + sp] = -V1[s];   // back to min semantics
            ps2[(size_t)row * NSPLIT_A + sp] = -V2[s];
            pix[(size_t)row * NSPLIT_A + sp] = II[s];
        }
    }
}

// merge splits; provisional idx; append near-tie rows to candidate-split lists
__global__ __launch_bounds__(256) void k_merge(const float* __restrict__ ps1,
                                               const float* __restrict__ ps2,
                                               const int* __restrict__ pi,
                                               int* __restrict__ idxbuf,
                                               float* __restrict__ outidx,
                                               int* __restrict__ cnt8,
                                               int* __restrict__ lists) {
    const int n = blockIdx.x * 256 + threadIdx.x;
    float v1 = ps1[n * NSPLIT_A];
    float v2 = ps2[n * NSPLIT_A];
    int ii1 = pi[n * NSPLIT_A];
#pragma unroll
    for (int s = 1; s < NSPLIT_A; ++s) {
        const float s1 = ps1[n * NSPLIT_A + s];
        const float s2 = ps2[n * NSPLIT_A + s];
        const int ii = pi[n * NSPLIT_A + s];
        if (s1 < v1 || (s1 == v1 && ii < ii1)) {
            v2 = fminf(fminf(v2, v1), s2);
            v1 = s1; ii1 = ii;
        } else {
            v2 = fminf(v2, s1);
        }
    }
    idxbuf[n] = ii1;
    outidx[n] = (float)ii1;
    if (v2 - v1 < GAPTH_A) {
        const float lim = v1 + GAPTH_A;
#pragma unroll
        for (int s = 0; s < NSPLIT_A; ++s)
            if (ps1[n * NSPLIT_A + s] <= lim) {
                const int p = atomicAdd(&cnt8[s], 1);
                lists[s * NZ + p] = n;
            }
    }
}

// np-bit-exact fp32 repair (verified R4-R7): gathered flagged rows x split's 1024 cols
__global__ __launch_bounds__(256) void k_fix_split(const float* __restrict__ z,
                                                   const float* __restrict__ emb,
                                                   const float* __restrict__ zsq,
                                                   const float* __restrict__ esq,
                                                   const int* __restrict__ cnt8,
                                                   const int* __restrict__ lists,
                                                   unsigned long long* __restrict__ pack) {
    __shared__ float As[BK * LDA];
    __shared__ float Bs[BK * LDA];
    __shared__ float Sq[BM];
    __shared__ int frow[BM];

    const int s = blockIdx.y;
    const int ns = cnt8[s];
    const int cbase = s * SPLIT_NA;
    const int t = threadIdx.x;
    const int tr = t >> 4;
    const int tc = t & 15;
    const int sr = t >> 3;
    const int skq = t & 7;
    const int wrot = 8 * (skq & 3);

    for (int rb = blockIdx.x; rb * BM < ns; rb += gridDim.x) {
        __syncthreads();
        if (t < BM) {
            const int fi = rb * BM + t;
            frow[t] = (fi < ns) ? lists[s * NZ + fi] : lists[s * NZ];
        }
        __syncthreads();

        float zqr[8];
#pragma unroll
        for (int i = 0; i < 8; ++i) zqr[i] = zsq[frow[tr * 8 + i]];

        float best[8];
        int bidx[8];
#pragma unroll
        for (int i = 0; i < 8; ++i) { best[i] = 3.4e38f; bidx[i] = 0; }

        for (int ch = 0; ch < 8; ++ch) {
            const int c0 = cbase + ch * BM;
            if (t < BM) Sq[t] = esq[c0 + t];

            float acc[8][8];
#pragma unroll
            for (int i = 0; i < 8; ++i)
#pragma unroll
                for (int j = 0; j < 8; ++j) acc[i][j] = 0.f;

            for (int kb = 0; kb < D; kb += BK) {
                __syncthreads();
#pragma unroll
                for (int q = 0; q < 4; ++q) {
                    const int r = sr + 32 * q;
                    const int rr = (r + wrot) & 127;
                    const float4 av = *(const float4*)&z[(size_t)frow[r] * D + kb + 4 * skq];
                    const float4 bv = *(const float4*)&emb[(size_t)(c0 + r) * D + kb + 4 * skq];
                    As[(4 * skq + 0) * LDA + rr] = av.x;
                    As[(4 * skq + 1) * LDA + rr] = av.y;
                    As[(4 * skq + 2) * LDA + rr] = av.z;
                    As[(4 * skq + 3) * LDA + rr] = av.w;
                    Bs[(4 * skq + 0) * LDA + rr] = bv.x;
                    Bs[(4 * skq + 1) * LDA + rr] = bv.y;
                    Bs[(4 * skq + 2) * LDA + rr] = bv.z;
                    Bs[(4 * skq + 3) * LDA + rr] = bv.w;
                }
                __syncthreads();
#pragma unroll
                for (int k = 0; k < BK; ++k) {
                    const float4 a0 = *(const float4*)&As[k * LDA + SWZR(k, tr * 8)];
                    const float4 a1 = *(const float4*)&As[k * LDA + SWZR(k, tr * 8 + 4)];
                    const float4 b0 = *(const float4*)&Bs[k * LDA + SWZR(k, tc * 4)];
                    const float4 b1 = *(const float4*)&Bs[k * LDA + SWZR(k, 64 + tc * 4)];
                    const float a[8] = {a0.x, a0.y, a0.z, a0.w, a1.x, a1.y, a1.z, a1.w};
                    const float b[8] = {b0.x, b0.y, b0.z, b0.w, b1.x, b1.y, b1.z, b1.w};
#pragma unroll
                    for (int i = 0; i < 8; ++i)
#pragma unroll
                        for (int j = 0; j < 8; ++j)
                            acc[i][j] = fmaf(a[i], b[j], acc[i][j]);
                }
            }
#pragma unroll
            for (int jj = 0; jj < 8; ++jj) {
                const int cloc = (jj < 4) ? (tc * 4 + jj) : (64 + tc * 4 + (jj - 4));
                const float sq = Sq[cloc];
                const int gcol = c0 + cloc;
#pragma unroll
                for (int i = 0; i < 8; ++i) {
                    const float t1 = __fadd_rn(zqr[i], sq);
                    const float sc = fmaf(-2.f, acc[i][jj], t1);
                    if (sc < best[i]) { best[i] = sc; bidx[i] = gcol; }
                }
            }
            __syncthreads();
        }

        float* Rs = As;
        int* Ri = (int*)Bs;
#pragma unroll
        for (int i = 0; i < 8; ++i) {
            Rs[(tr * 8 + i) * LDM + tc] = best[i];
            Ri[(tr * 8 + i) * LDM + tc] = bidx[i];
        }
        __syncthreads();
        if (t < BM) {
            float bs = Rs[t * LDM];
            int bi = Ri[t * LDM];
#pragma unroll
            for (int c = 1; c < 16; ++c) {
                const float sc = Rs[t * LDM + c];
                const int ii = Ri[t * LDM + c];
                if (sc < bs || (sc == bs && ii < bi)) { bs = sc; bi = ii; }
            }
            const int fi = rb * BM + t;
            if (fi < ns) {
                const unsigned long long pk =
                    ((unsigned long long)__float_as_uint(bs) << 32) | (unsigned)bi;
                atomicMin(&pack[frow[t]], pk);
            }
        }
    }
}

__global__ __launch_bounds__(256) void k_fixdecode(const unsigned long long* __restrict__ pack,
                                                   int* __restrict__ idxbuf,
                                                   float* __restrict__ outidx) {
    const int n = blockIdx.x * 256 + threadIdx.x;
    const unsigned long long p = pack[n];
    if (p != ~0ull) {
        const int idx = (int)(p & 0xffffffffu);
        idxbuf[n] = idx;
        outidx[n] = (float)idx;
    }
}

__global__ __launch_bounds__(256) void k_gather(const float* __restrict__ z,
                                                const float* __restrict__ emb,
                                                const int* __restrict__ idxbuf,
                                                float* __restrict__ out,
                                                double* __restrict__ sums) {
    const int row = blockIdx.x * 4 + (threadIdx.x >> 6);
    const int lane = threadIdx.x & 63;
    const int idx = idxbuf[row];
    const float4 e4 = *(const float4*)&emb[(size_t)idx * D + lane * 4];
    const float4 z4 = *(const float4*)&z[(size_t)row * D + lane * 4];
    *(float4*)&out[(size_t)row * D + lane * 4] = e4;
    const float dx = e4.x - z4.x, dy = e4.y - z4.y;
    const float dzv = e4.z - z4.z, dw = e4.w - z4.w;
    float s = dx * dx + dy * dy + dzv * dzv + dw * dw;
    s = waveReduceSumF(s);
    if (lane == 0) atomicAdd(&sums[1], (double)s);
}

// ---- pairwise cdist row min/max via frag-direct MFMA, triangular tiles ----
__global__ __launch_bounds__(256) void k_pairwise_f(const f16x8* __restrict__ ef,
                                                    const float* __restrict__ esq,
                                                    unsigned* __restrict__ rmxg,
                                                    unsigned* __restrict__ rmng) {
    __shared__ float cmnS[4][128];
    __shared__ float cmxS[4][128];

    int p = blockIdx.x;
    int bi = 0;
    while (p >= NB - bi) { p -= NB - bi; ++bi; }
    const int bj = bi + p;
    const int row0 = bi * BM;
    const int c0 = bj * BM;

    const int t = threadIdx.x;
    const int l = t & 63;
    const int w = t >> 6;
    const int quad = l >> 4;
    const int l15 = l & 15;

    float sR[8], sC[8];
#pragma unroll
    for (int mi = 0; mi < 2; ++mi)
#pragma unroll
        for (int r = 0; r < 4; ++r)
            sR[mi * 4 + r] = esq[row0 + w * 32 + mi * 16 + quad * 4 + r];
#pragma unroll
    for (int nj = 0; nj < 8; ++nj) sC[nj] = esq[c0 + nj * 16 + l15];

    const int arb = bi * 8 + w * 2;
    const int cfb = bj * 8;

    f32x4 acc[2][8];
#pragma unroll
    for (int mi = 0; mi < 2; ++mi)
#pragma unroll
        for (int nj = 0; nj < 8; ++nj) acc[mi][nj] = (f32x4){0.f, 0.f, 0.f, 0.f};

#pragma unroll
    for (int kb = 0; kb < NKB_P; ++kb) {     // un-augmented 256 K only
        const f16x8 ah0 = ef[((size_t)arb * NKB + kb) * 64 + l];
        const f16x8 ah1 = ef[((size_t)(arb + 1) * NKB + kb) * 64 + l];
        f16x8 bh[8];
#pragma unroll
        for (int nj = 0; nj < 8; ++nj)
            bh[nj] = ef[((size_t)(cfb + nj) * NKB + kb) * 64 + l];
#pragma unroll
        for (int nj = 0; nj < 8; ++nj) {
            acc[0][nj] = MFMA16(ah0, bh[nj], acc[0][nj]);
            acc[1][nj] = MFMA16(ah1, bh[nj], acc[1][nj]);
        }
    }

    float rmn[8], rmx[8], cmn[8], cmx[8];
#pragma unroll
    for (int s = 0; s < 8; ++s) { rmn[s] = 3.4e38f; rmx[s] = 0.f; cmn[s] = 3.4e38f; cmx[s] = 0.f; }
#pragma unroll
    for (int mi = 0; mi < 2; ++mi)
#pragma unroll
        for (int nj = 0; nj < 8; ++nj)
#pragma unroll
            for (int r = 0; r < 4; ++r) {
                const int s = mi * 4 + r;
                const float t1 = __fadd_rn(sR[s], sC[nj]);
                const float d2 = fmaf(-0x1p-25f, acc[mi][nj][r], t1);
                const float d2c = fmaxf(d2, 0.f);
                rmn[s] = fminf(rmn[s], d2c);
                rmx[s] = fmaxf(rmx[s], d2c);
                cmn[nj] = fminf(cmn[nj], d2c);
                cmx[nj] = fmaxf(cmx[nj], d2c);
            }

    // rows: butterfly across the 16 lanes of the quad group, then atomics
#pragma unroll
    for (int s = 0; s < 8; ++s) {
#pragma unroll
        for (int m = 1; m <= 8; m <<= 1) {
            rmn[s] = fminf(rmn[s], __shfl_xor(rmn[s], m));
            rmx[s] = fmaxf(rmx[s], __shfl_xor(rmx[s], m));
        }
    }
    if (l15 == 0) {
#pragma unroll
        for (int s = 0; s < 8; ++s) {
            const int mi = s >> 2, r = s & 3;
            const int row = row0 + w * 32 + mi * 16 + quad * 4 + r;
            atomicMax(&rmxg[row], __float_as_uint(rmx[s]));
            atomicMin(&rmng[row], __float_as_uint(rmn[s]));
        }
    }

    // cols: butterfly across quads, LDS across waves, then atomics
#pragma unroll
    for (int nj = 0; nj < 8; ++nj) {
#pragma unroll
        for (int m = 16; m <= 32; m <<= 1) {
            cmn[nj] = fminf(cmn[nj], __shfl_xor(cmn[nj], m));
            cmx[nj] = fmaxf(cmx[nj], __shfl_xor(cmx[nj], m));
        }
    }
    if (quad == 0) {
#pragma unroll
        for (int nj = 0; nj < 8; ++nj) {
            cmnS[w][nj * 16 + l15] = cmn[nj];
            cmxS[w][nj * 16 + l15] = cmx[nj];
        }
    }
    __syncthreads();
    if (t < BM) {
        float mn = cmnS[0][t], mx = cmxS[0][t];
#pragma unroll
        for (int ww = 1; ww < 4; ++ww) {
            mn = fminf(mn, cmnS[ww][t]);
            mx = fmaxf(mx, cmxS[ww][t]);
        }
        atomicMax(&rmxg[c0 + t], __float_as_uint(mx));
        atomicMin(&rmng[c0 + t], __float_as_uint(mn));
    }
}

__global__ __launch_bounds__(256) void k_mm_sum(const unsigned* __restrict__ rmxg,
                                                const unsigned* __restrict__ rmng,
                                                double* __restrict__ sums) {
    const int n = blockIdx.x * 256 + threadIdx.x;
    const float mx = sqrtf(__uint_as_float(rmxg[n]));
    const float mn = sqrtf(__uint_as_float(rmng[n]));
    float v = mx - mn;
    v = waveReduceSumF(v);
    __shared__ float part[4];
    if ((threadIdx.x & 63) == 0) part[threadIdx.x >> 6] = v;
    __syncthreads();
    if (threadIdx.x == 0)
        atomicAdd(&sums[2], (double)(part[0] + part[1] + part[2] + part[3]));
}

__global__ void k_final(const double* __restrict__ sums, float* __restrict__ out) {
    const double loss = 1.25 * (sums[1] / (double)((size_t)NZ * D));
    const double qq = 0.1 * (sums[2] / (double)NE) + 0.1 * sums[0];
    out[(size_t)NZ * D + NZ] = (float)loss;
    out[(size_t)NZ * D + NZ + 1] = (float)qq;
}

extern "C" void kernel_launch(void* const* d_in, const int* in_sizes, int n_in,
                              void* d_out, int out_size, void* d_ws, size_t ws_size,
                              hipStream_t stream) {
    const float* z = (const float*)d_in[0];
    const float* emb = (const float*)d_in[1];
    float* out = (float*)d_out;
    char* ws = (char*)d_ws;

    double* sums = (double*)(ws + WS_SUMS);
    int* cnt8 = (int*)(ws + WS_CNT8);
    float* zsq = (float*)(ws + WS_ZSQ);
    float* esq = (float*)(ws + WS_ESQ);
    int* idxb = (int*)(ws + WS_IDX);
    float* ps1 = (float*)(ws + WS_PS1);
    float* ps2 = (float*)(ws + WS_PS2);
    int* pix = (int*)(ws + WS_PIX);
    unsigned* rmx = (unsigned*)(ws + WS_RMX);
    unsigned* rmn = (unsigned*)(ws + WS_RMN);
    unsigned long long* pack = (unsigned long long*)(ws + WS_PACK);
    int* lists = (int*)(ws + WS_LISTS);
    f16x8* zhf = (f16x8*)(ws + WS_ZHF);
    f16x8* ehf = (f16x8*)(ws + WS_EHF);

    hipLaunchKernelGGL(k_init, dim3(1), dim3(1), 0, stream, sums, cnt8);
    hipLaunchKernelGGL(k_initmm, dim3(NZ / 256), dim3(256), 0, stream, rmx, rmn, pack);
    hipLaunchKernelGGL(k_rowsq, dim3(NZ / 256), dim3(256), 0, stream, z, zsq, (double*)nullptr);
    hipLaunchKernelGGL(k_rowsq, dim3(NE / 256), dim3(256), 0, stream, emb, esq, sums);
    hipLaunchKernelGGL(k_cvt_zf, dim3(NZ / 64), dim3(256), 0, stream, z, zhf);
    hipLaunchKernelGGL(k_cvt_ef, dim3(NE / 64), dim3(256), 0, stream, emb, esq, ehf);
    hipLaunchKernelGGL(k_argmin_f, dim3(NZ / BM, NSPLIT_A), dim3(256), 0, stream,
                       zhf, ehf, ps1, ps2, pix);
    hipLaunchKernelGGL(k_pairwise_f, dim3(NTRI), dim3(256), 0, stream,
                       ehf, esq, rmx, rmn);
    hipLaunchKernelGGL(k_merge, dim3(NZ / 256), dim3(256), 0, stream,
                       ps1, ps2, pix, idxb, out + (size_t)NZ * D, cnt8, lists);
    hipLaunchKernelGGL(k_fix_split, dim3(8, 8), dim3(256), 0, stream,
                       z, emb, zsq, esq, cnt8, lists, pack);
    hipLaunchKernelGGL(k_fixdecode, dim3(NZ / 256), dim3(256), 0, stream,
                       pack, idxb, out + (size_t)NZ * D);
    hipLaunchKernelGGL(k_gather, dim3(NZ / 4), dim3(256), 0, stream,
                       z, emb, idxb, out, sums);
    hipLaunchKernelGGL(k_mm_sum, dim3(NE / 256), dim3(256), 0, stream,
                       rmx, rmn, sums);
    hipLaunchKernelGGL(k_final, dim3(1), dim3(1), 0, stream, sums, out);
}

// Round 9
// 671.427 us; speedup vs baseline: 1.6531x; 1.1974x over previous
//
#include <hip/hip_runtime.h>

#define D 256
#define DA 288                     // augmented K (one extra 32-block)
#define NKB 9                      // DA/32
#define NKB_P 8                    // pairwise uses un-augmented 256
#define NE 8192
#define NZ 16384
#define BM 128
#define BK 32
#define LDA (BM + 4)               // fp32 k-major LDS stride (k_fix_split)
#define NB (NE / BM)
#define NTRI (NB * (NB + 1) / 2)
#define NSPLIT_A 8
#define SPLIT_NA (NE / NSPLIT_A)   // 1024
#define GAPTH_A 0.4096f            // 1e-4 score units * 2^12 (acc units)
#define LDM 17

// fp32-path LDS swizzle (verified R4-R8, k_fix_split only)
#define SROT(kk) (8 * ((((kk) >> 2)) & 3))
#define SWZR(kk, r) ((((r) + SROT(kk)) & 127))

typedef _Float16 f16x8 __attribute__((ext_vector_type(8)));
typedef _Float16 f16x4 __attribute__((ext_vector_type(4)));
typedef float f32x4 __attribute__((ext_vector_type(4)));

#define MFMA16(a, b, c) __builtin_amdgcn_mfma_f32_16x16x32_f16(a, b, c, 0, 0, 0)

// ---------------- workspace layout (bytes) ----------------
#define WS_SUMS   0                            // double[4]
#define WS_CNT8   64                           // int[8]
#define WS_ZSQ    256                          // float[NZ]
#define WS_ESQ    (WS_ZSQ + NZ * 4)            // float[NE]
#define WS_IDX    (WS_ESQ + NE * 4)            // int[NZ]
#define WS_PS1    (WS_IDX + NZ * 4)            // float[NZ*8]
#define WS_PS2    (WS_PS1 + NZ * NSPLIT_A * 4)
#define WS_PIX    (WS_PS2 + NZ * NSPLIT_A * 4)
#define WS_RMX    (WS_PIX + NZ * NSPLIT_A * 4) // uint[NE]
#define WS_RMN    (WS_RMX + NE * 4)            // uint[NE]
#define WS_PACK   (WS_RMN + NE * 4)            // u64[NZ]
#define WS_LISTS  (WS_PACK + NZ * 8)           // int[8][NZ]
#define WS_ZHF    (WS_LISTS + NZ * NSPLIT_A * 4)   // frag-major f16 z
#define WS_EHF    (WS_ZHF + (size_t)(NZ / 16) * NKB * 64 * 8 * 2)

__device__ __forceinline__ float waveReduceSumF(float v) {
    v += __shfl_down(v, 32); v += __shfl_down(v, 16); v += __shfl_down(v, 8);
    v += __shfl_down(v, 4);  v += __shfl_down(v, 2);  v += __shfl_down(v, 1);
    return v;
}
__device__ __forceinline__ double waveReduceSumD(double v) {
    v += __shfl_down(v, 32); v += __shfl_down(v, 16); v += __shfl_down(v, 8);
    v += __shfl_down(v, 4);  v += __shfl_down(v, 2);  v += __shfl_down(v, 1);
    return v;
}

__global__ void k_init(double* sums, int* cnt8) {
    sums[0] = 0.0; sums[1] = 0.0; sums[2] = 0.0; sums[3] = 0.0;
#pragma unroll
    for (int s = 0; s < 8; ++s) cnt8[s] = 0;
}

__global__ __launch_bounds__(256) void k_initmm(unsigned* __restrict__ rmx,
                                                unsigned* __restrict__ rmn,
                                                unsigned long long* __restrict__ pack) {
    const int n = blockIdx.x * 256 + threadIdx.x;
    if (n < NE) { rmx[n] = 0u; rmn[n] = 0x7F800000u; }
    pack[n] = ~0ull;
}

// np.sum(x*x, axis=1) bit-exact (numpy pairwise summation, n=256)
__global__ __launch_bounds__(256) void k_rowsq(const float* __restrict__ src,
                                               float* __restrict__ rsq,
                                               double* __restrict__ sums) {
    const int row = blockIdx.x * 256 + threadIdx.x;
    const float* p = src + (size_t)row * D;
    float h[2];
#pragma unroll
    for (int half = 0; half < 2; ++half) {
        const float* q = p + half * 128;
        float4 a0 = *(const float4*)&q[0];
        float4 a1 = *(const float4*)&q[4];
        float r0 = __fmul_rn(a0.x, a0.x);
        float r1 = __fmul_rn(a0.y, a0.y);
        float r2 = __fmul_rn(a0.z, a0.z);
        float r3 = __fmul_rn(a0.w, a0.w);
        float r4 = __fmul_rn(a1.x, a1.x);
        float r5 = __fmul_rn(a1.y, a1.y);
        float r6 = __fmul_rn(a1.z, a1.z);
        float r7 = __fmul_rn(a1.w, a1.w);
#pragma unroll
        for (int i = 8; i < 128; i += 8) {
            const float4 b0 = *(const float4*)&q[i];
            const float4 b1 = *(const float4*)&q[i + 4];
            r0 = __fadd_rn(r0, __fmul_rn(b0.x, b0.x));
            r1 = __fadd_rn(r1, __fmul_rn(b0.y, b0.y));
            r2 = __fadd_rn(r2, __fmul_rn(b0.z, b0.z));
            r3 = __fadd_rn(r3, __fmul_rn(b0.w, b0.w));
            r4 = __fadd_rn(r4, __fmul_rn(b1.x, b1.x));
            r5 = __fadd_rn(r5, __fmul_rn(b1.y, b1.y));
            r6 = __fadd_rn(r6, __fmul_rn(b1.z, b1.z));
            r7 = __fadd_rn(r7, __fmul_rn(b1.w, b1.w));
        }
        const float t01 = __fadd_rn(r0, r1);
        const float t23 = __fadd_rn(r2, r3);
        const float t45 = __fadd_rn(r4, r5);
        const float t67 = __fadd_rn(r6, r7);
        h[half] = __fadd_rn(__fadd_rn(t01, t23), __fadd_rn(t45, t67));
    }
    const float tot = __fadd_rn(h[0], h[1]);
    rsq[row] = tot;
    if (sums != nullptr) {
        double s = waveReduceSumD((double)tot);
        if ((threadIdx.x & 63) == 0) atomicAdd(&sums[0], s);
    }
}

// ---- fragment-major converters (64 rows per block, LDS transpose) ----
__global__ __launch_bounds__(256) void k_cvt_zf(const float* __restrict__ z,
                                                f16x8* __restrict__ zf) {
    __shared__ _Float16 Ls[64 * 296];
    const int t = threadIdx.x;
    const int row0 = blockIdx.x * 64;
#pragma unroll
    for (int i = 0; i < 16; ++i) {
        const int f4 = i * 256 + t;
        const int r = f4 >> 6, c4 = f4 & 63;
        const float4 v = *(const float4*)&z[(size_t)(row0 + r) * D + c4 * 4];
        f16x4 h;
        h[0] = (_Float16)v.x; h[1] = (_Float16)v.y;
        h[2] = (_Float16)v.z; h[3] = (_Float16)v.w;
        *(f16x4*)&Ls[r * 296 + c4 * 4] = h;
    }
#pragma unroll
    for (int i = 0; i < 8; ++i) {
        const int idx = i * 256 + t;
        const int r = idx >> 5, c = idx & 31;
        Ls[r * 296 + 256 + c] = (c == 0) ? (_Float16)1.0f : (_Float16)0.0f;
    }
    __syncthreads();
    const int l = t & 63, w = t >> 6;
#pragma unroll
    for (int kb = 0; kb < NKB; ++kb) {
        const f16x8 fr = *(const f16x8*)&Ls[(w * 16 + (l & 15)) * 296 + kb * 32 + (l >> 4) * 8];
        zf[((size_t)(blockIdx.x * 4 + w) * NKB + kb) * 64 + l] = fr;
    }
}

__global__ __launch_bounds__(256) void k_cvt_ef(const float* __restrict__ e,
                                                const float* __restrict__ esq,
                                                f16x8* __restrict__ ef) {
    __shared__ _Float16 Ls[64 * 296];
    const int t = threadIdx.x;
    const int row0 = blockIdx.x * 64;
#pragma unroll
    for (int i = 0; i < 16; ++i) {
        const int f4 = i * 256 + t;
        const int r = f4 >> 6, c4 = f4 & 63;
        const float4 v = *(const float4*)&e[(size_t)(row0 + r) * D + c4 * 4];
        f16x4 h;
        h[0] = (_Float16)(v.x * 8192.0f); h[1] = (_Float16)(v.y * 8192.0f);
        h[2] = (_Float16)(v.z * 8192.0f); h[3] = (_Float16)(v.w * 8192.0f);
        *(f16x4*)&Ls[r * 296 + c4 * 4] = h;
    }
#pragma unroll
    for (int i = 0; i < 8; ++i) {
        const int idx = i * 256 + t;
        const int r = idx >> 5, c = idx & 31;
        Ls[r * 296 + 256 + c] =
            (c == 0) ? (_Float16)(esq[row0 + r] * -4096.0f) : (_Float16)0.0f;
    }
    __syncthreads();
    const int l = t & 63, w = t >> 6;
#pragma unroll
    for (int kb = 0; kb < NKB; ++kb) {
        const f16x8 fr = *(const f16x8*)&Ls[(w * 16 + (l & 15)) * 296 + kb * 32 + (l >> 4) * 8];
        ef[((size_t)(blockIdx.x * 4 + w) * NKB + kb) * 64 + l] = fr;
    }
}

// ---- LDS-free MFMA argmin, A-fragments resident in VGPRs ----
__global__ __launch_bounds__(256) void k_argmin_f(
        const f16x8* __restrict__ zf, const f16x8* __restrict__ ef,
        float* __restrict__ ps1, float* __restrict__ ps2, int* __restrict__ pix) {
    const int t = threadIdx.x;
    const int l = t & 63;
    const int w = t >> 6;
    const int quad = l >> 4;
    const int l15 = l & 15;
    const int row0 = blockIdx.x * BM;
    const int sp = blockIdx.y;
    const int arb0 = blockIdx.x * 8 + w * 2;

    // hoist A fragments (2 row-tiles x 9 kb) into registers for the whole block
    f16x8 ah[2][NKB];
#pragma unroll
    for (int kb = 0; kb < NKB; ++kb) {
        ah[0][kb] = zf[((size_t)arb0 * NKB + kb) * 64 + l];
        ah[1][kb] = zf[((size_t)(arb0 + 1) * NKB + kb) * 64 + l];
    }

    float b1[8], b2[8];
    int i1[8];
#pragma unroll
    for (int s = 0; s < 8; ++s) { b1[s] = -3.4e38f; b2[s] = -3.4e38f; i1[s] = 0; }

    for (int ch = 0; ch < 16; ++ch) {
        const int cb16 = sp * 64 + ch * 4;
        const int c0 = sp * SPLIT_NA + ch * 64;

        f32x4 acc[2][4];
#pragma unroll
        for (int mi = 0; mi < 2; ++mi)
#pragma unroll
            for (int nj = 0; nj < 4; ++nj) acc[mi][nj] = (f32x4){0.f, 0.f, 0.f, 0.f};

#pragma unroll
        for (int kb = 0; kb < NKB; ++kb) {
            f16x8 bh[4];
#pragma unroll
            for (int nj = 0; nj < 4; ++nj)
                bh[nj] = ef[((size_t)(cb16 + nj) * NKB + kb) * 64 + l];
#pragma unroll
            for (int nj = 0; nj < 4; ++nj) {
                acc[0][nj] = MFMA16(ah[0][kb], bh[nj], acc[0][nj]);
                acc[1][nj] = MFMA16(ah[1][kb], bh[nj], acc[1][nj]);
            }
        }

#pragma unroll
        for (int nj = 0; nj < 4; ++nj) {
            const int gcol = c0 + nj * 16 + l15;
#pragma unroll
            for (int mi = 0; mi < 2; ++mi)
#pragma unroll
                for (int r = 0; r < 4; ++r) {
                    const int s = mi * 4 + r;
                    const float a = acc[mi][nj][r];
                    b2[s] = fmaxf(b2[s], fminf(a, b1[s]));
                    i1[s] = (a > b1[s]) ? gcol : i1[s];
                    b1[s] = fmaxf(b1[s], a);
                }
        }
    }

    float V1[8], V2[8];
    int II[8];
#pragma unroll
    for (int s = 0; s < 8; ++s) {
        float v1 = b1[s], v2 = b2[s];
        int ii = i1[s];
#pragma unroll
        for (int m = 1; m <= 8; m <<= 1) {
            const float o1 = __shfl_xor(v1, m);
            const float o2 = __shfl_xor(v2, m);
            const int oi = __shfl_xor(ii, m);
            const float n2 = fmaxf(fminf(v1, o1), fmaxf(v2, o2));
            const bool take = (o1 > v1) || (o1 == v1 && oi < ii);
            ii = take ? oi : ii;
            v1 = fmaxf(v1, o1);
            v2 = n2;
        }
        V1[s] = v1; V2[s] = v2; II[s] = ii;
    }
    if (l15 == 0) {
#pragma unroll
        for (int s = 0; s < 8; ++s) {
            const int mi = s >> 2, r = s & 3;
            const int row = row0 + w * 32 + mi * 16 + quad * 4 + r;
            ps1[(size_t)row * NSPLIT_A + sp] = -V1[s];
            ps2[(size_t)row * NSPLIT_A + sp] = -V2[s];
            pix[(size_t)row * NSPLIT_A + sp] = II[s];
        }
    }
}

// merge splits; provisional idx; append near-tie rows to candidate-split lists
__global__ __launch_bounds__(256) void k_merge(const float* __restrict__ ps1,
                                               const float* __restrict__ ps2,
                                               const int* __restrict__ pi,
                                               int* __restrict__ idxbuf,
                                               float* __restrict__ outidx,
                                               int* __restrict__ cnt8,
                                               int* __restrict__ lists) {
    const int n = blockIdx.x * 256 + threadIdx.x;
    float v1 = ps1[n * NSPLIT_A];
    float v2 = ps2[n * NSPLIT_A];
    int ii1 = pi[n * NSPLIT_A];
#pragma unroll
    for (int s = 1; s < NSPLIT_A; ++s) {
        const float s1 = ps1[n * NSPLIT_A + s];
        const float s2 = ps2[n * NSPLIT_A + s];
        const int ii = pi[n * NSPLIT_A + s];
        if (s1 < v1 || (s1 == v1 && ii < ii1)) {
            v2 = fminf(fminf(v2, v1), s2);
            v1 = s1; ii1 = ii;
        } else {
            v2 = fminf(v2, s1);
        }
    }
    idxbuf[n] = ii1;
    outidx[n] = (float)ii1;
    if (v2 - v1 < GAPTH_A) {
        const float lim = v1 + GAPTH_A;
#pragma unroll
        for (int s = 0; s < NSPLIT_A; ++s)
            if (ps1[n * NSPLIT_A + s] <= lim) {
                const int p = atomicAdd(&cnt8[s], 1);
                lists[s * NZ + p] = n;
            }
    }
}

// np-bit-exact fp32 repair: one block = 128 gathered rows x ONE 128-col chunk
// blockIdx.y = split*8 + chunk
__global__ __launch_bounds__(256) void k_fix_split(const float* __restrict__ z,
                                                   const float* __restrict__ emb,
                                                   const float* __restrict__ zsq,
                                                   const float* __restrict__ esq,
                                                   const int* __restrict__ cnt8,
                                                   const int* __restrict__ lists,
                                                   unsigned long long* __restrict__ pack) {
    __shared__ float As[BK * LDA];
    __shared__ float Bs[BK * LDA];
    __shared__ float Sq[BM];
    __shared__ int frow[BM];

    const int s = blockIdx.y >> 3;
    const int chunk = blockIdx.y & 7;
    const int ns = cnt8[s];
    const int c0 = s * SPLIT_NA + chunk * BM;
    const int t = threadIdx.x;
    const int tr = t >> 4;
    const int tc = t & 15;
    const int sr = t >> 3;
    const int skq = t & 7;
    const int wrot = 8 * (skq & 3);

    for (int rb = blockIdx.x; rb * BM < ns; rb += gridDim.x) {
        __syncthreads();
        if (t < BM) {
            const int fi = rb * BM + t;
            frow[t] = (fi < ns) ? lists[s * NZ + fi] : lists[s * NZ];
            Sq[t] = esq[c0 + t];
        }
        __syncthreads();

        float zqr[8];
#pragma unroll
        for (int i = 0; i < 8; ++i) zqr[i] = zsq[frow[tr * 8 + i]];

        float best[8];
        int bidx[8];
#pragma unroll
        for (int i = 0; i < 8; ++i) { best[i] = 3.4e38f; bidx[i] = 0; }

        float acc[8][8];
#pragma unroll
        for (int i = 0; i < 8; ++i)
#pragma unroll
            for (int j = 0; j < 8; ++j) acc[i][j] = 0.f;

        for (int kb = 0; kb < D; kb += BK) {
            __syncthreads();
#pragma unroll
            for (int q = 0; q < 4; ++q) {
                const int r = sr + 32 * q;
                const int rr = (r + wrot) & 127;
                const float4 av = *(const float4*)&z[(size_t)frow[r] * D + kb + 4 * skq];
                const float4 bv = *(const float4*)&emb[(size_t)(c0 + r) * D + kb + 4 * skq];
                As[(4 * skq + 0) * LDA + rr] = av.x;
                As[(4 * skq + 1) * LDA + rr] = av.y;
                As[(4 * skq + 2) * LDA + rr] = av.z;
                As[(4 * skq + 3) * LDA + rr] = av.w;
                Bs[(4 * skq + 0) * LDA + rr] = bv.x;
                Bs[(4 * skq + 1) * LDA + rr] = bv.y;
                Bs[(4 * skq + 2) * LDA + rr] = bv.z;
                Bs[(4 * skq + 3) * LDA + rr] = bv.w;
            }
            __syncthreads();
#pragma unroll
            for (int k = 0; k < BK; ++k) {
                const float4 a0 = *(const float4*)&As[k * LDA + SWZR(k, tr * 8)];
                const float4 a1 = *(const float4*)&As[k * LDA + SWZR(k, tr * 8 + 4)];
                const float4 b0 = *(const float4*)&Bs[k * LDA + SWZR(k, tc * 4)];
                const float4 b1 = *(const float4*)&Bs[k * LDA + SWZR(k, 64 + tc * 4)];
                const float a[8] = {a0.x, a0.y, a0.z, a0.w, a1.x, a1.y, a1.z, a1.w};
                const float b[8] = {b0.x, b0.y, b0.z, b0.w, b1.x, b1.y, b1.z, b1.w};
#pragma unroll
                for (int i = 0; i < 8; ++i)
#pragma unroll
                    for (int j = 0; j < 8; ++j)
                        acc[i][j] = fmaf(a[i], b[j], acc[i][j]);
            }
        }
#pragma unroll
        for (int jj = 0; jj < 8; ++jj) {
            const int cloc = (jj < 4) ? (tc * 4 + jj) : (64 + tc * 4 + (jj - 4));
            const float sq = Sq[cloc];
            const int gcol = c0 + cloc;
#pragma unroll
            for (int i = 0; i < 8; ++i) {
                const float t1 = __fadd_rn(zqr[i], sq);
                const float sc = fmaf(-2.f, acc[i][jj], t1);
                if (sc < best[i]) { best[i] = sc; bidx[i] = gcol; }
            }
        }
        __syncthreads();

        float* Rs = As;
        int* Ri = (int*)Bs;
#pragma unroll
        for (int i = 0; i < 8; ++i) {
            Rs[(tr * 8 + i) * LDM + tc] = best[i];
            Ri[(tr * 8 + i) * LDM + tc] = bidx[i];
        }
        __syncthreads();
        if (t < BM) {
            float bs = Rs[t * LDM];
            int bi = Ri[t * LDM];
#pragma unroll
            for (int c = 1; c < 16; ++c) {
                const float sc = Rs[t * LDM + c];
                const int ii = Ri[t * LDM + c];
                if (sc < bs || (sc == bs && ii < bi)) { bs = sc; bi = ii; }
            }
            const int fi = rb * BM + t;
            if (fi < ns) {
                const unsigned long long pk =
                    ((unsigned long long)__float_as_uint(bs) << 32) | (unsigned)bi;
                atomicMin(&pack[frow[t]], pk);
            }
        }
    }
}

__global__ __launch_bounds__(256) void k_fixdecode(const unsigned long long* __restrict__ pack,
                                                   int* __restrict__ idxbuf,
                                                   float* __restrict__ outidx) {
    const int n = blockIdx.x * 256 + threadIdx.x;
    const unsigned long long p = pack[n];
    if (p != ~0ull) {
        const int idx = (int)(p & 0xffffffffu);
        idxbuf[n] = idx;
        outidx[n] = (float)idx;
    }
}

__global__ __launch_bounds__(256) void k_gather(const float* __restrict__ z,
                                                const float* __restrict__ emb,
                                                const int* __restrict__ idxbuf,
                                                float* __restrict__ out,
                                                double* __restrict__ sums) {
    const int row = blockIdx.x * 4 + (threadIdx.x >> 6);
    const int lane = threadIdx.x & 63;
    const int idx = idxbuf[row];
    const float4 e4 = *(const float4*)&emb[(size_t)idx * D + lane * 4];
    const float4 z4 = *(const float4*)&z[(size_t)row * D + lane * 4];
    *(float4*)&out[(size_t)row * D + lane * 4] = e4;
    const float dx = e4.x - z4.x, dy = e4.y - z4.y;
    const float dzv = e4.z - z4.z, dw = e4.w - z4.w;
    float s = dx * dx + dy * dy + dzv * dzv + dw * dw;
    s = waveReduceSumF(s);
    if (lane == 0) atomicAdd(&sums[1], (double)s);
}

// ---- pairwise cdist row min/max via frag-direct MFMA, triangular tiles ----
__global__ __launch_bounds__(256) void k_pairwise_f(const f16x8* __restrict__ ef,
                                                    const float* __restrict__ esq,
                                                    unsigned* __restrict__ rmxg,
                                                    unsigned* __restrict__ rmng) {
    __shared__ float cmnS[4][128];
    __shared__ float cmxS[4][128];

    int p = blockIdx.x;
    int bi = 0;
    while (p >= NB - bi) { p -= NB - bi; ++bi; }
    const int bj = bi + p;
    const int row0 = bi * BM;
    const int c0 = bj * BM;

    const int t = threadIdx.x;
    const int l = t & 63;
    const int w = t >> 6;
    const int quad = l >> 4;
    const int l15 = l & 15;

    float sR[8], sC[8];
#pragma unroll
    for (int mi = 0; mi < 2; ++mi)
#pragma unroll
        for (int r = 0; r < 4; ++r)
            sR[mi * 4 + r] = esq[row0 + w * 32 + mi * 16 + quad * 4 + r];
#pragma unroll
    for (int nj = 0; nj < 8; ++nj) sC[nj] = esq[c0 + nj * 16 + l15];

    const int arb = bi * 8 + w * 2;
    const int cfb = bj * 8;

    f32x4 acc[2][8];
#pragma unroll
    for (int mi = 0; mi < 2; ++mi)
#pragma unroll
        for (int nj = 0; nj < 8; ++nj) acc[mi][nj] = (f32x4){0.f, 0.f, 0.f, 0.f};

#pragma unroll
    for (int kb = 0; kb < NKB_P; ++kb) {
        const f16x8 ah0 = ef[((size_t)arb * NKB + kb) * 64 + l];
        const f16x8 ah1 = ef[((size_t)(arb + 1) * NKB + kb) * 64 + l];
        f16x8 bh[8];
#pragma unroll
        for (int nj = 0; nj < 8; ++nj)
            bh[nj] = ef[((size_t)(cfb + nj) * NKB + kb) * 64 + l];
#pragma unroll
        for (int nj = 0; nj < 8; ++nj) {
            acc[0][nj] = MFMA16(ah0, bh[nj], acc[0][nj]);
            acc[1][nj] = MFMA16(ah1, bh[nj], acc[1][nj]);
        }
    }

    float rmn[8], rmx[8], cmn[8], cmx[8];
#pragma unroll
    for (int s = 0; s < 8; ++s) { rmn[s] = 3.4e38f; rmx[s] = 0.f; cmn[s] = 3.4e38f; cmx[s] = 0.f; }
#pragma unroll
    for (int mi = 0; mi < 2; ++mi)
#pragma unroll
        for (int nj = 0; nj < 8; ++nj)
#pragma unroll
            for (int r = 0; r < 4; ++r) {
                const int s = mi * 4 + r;
                const float t1 = __fadd_rn(sR[s], sC[nj]);
                const float d2 = fmaf(-0x1p-25f, acc[mi][nj][r], t1);
                const float d2c = fmaxf(d2, 0.f);
                rmn[s] = fminf(rmn[s], d2c);
                rmx[s] = fmaxf(rmx[s], d2c);
                cmn[nj] = fminf(cmn[nj], d2c);
                cmx[nj] = fmaxf(cmx[nj], d2c);
            }

#pragma unroll
    for (int s = 0; s < 8; ++s) {
#pragma unroll
        for (int m = 1; m <= 8; m <<= 1) {
            rmn[s] = fminf(rmn[s], __shfl_xor(rmn[s], m));
            rmx[s] = fmaxf(rmx[s], __shfl_xor(rmx[s], m));
        }
    }
    if (l15 == 0) {
#pragma unroll
        for (int s = 0; s < 8; ++s) {
            const int mi = s >> 2, r = s & 3;
            const int row = row0 + w * 32 + mi * 16 + quad * 4 + r;
            atomicMax(&rmxg[row], __float_as_uint(rmx[s]));
            atomicMin(&rmng[row], __float_as_uint(rmn[s]));
        }
    }

#pragma unroll
    for (int nj = 0; nj < 8; ++nj) {
#pragma unroll
        for (int m = 16; m <= 32; m <<= 1) {
            cmn[nj] = fminf(cmn[nj], __shfl_xor(cmn[nj], m));
            cmx[nj] = fmaxf(cmx[nj], __shfl_xor(cmx[nj], m));
        }
    }
    if (quad == 0) {
#pragma unroll
        for (int nj = 0; nj < 8; ++nj) {
            cmnS[w][nj * 16 + l15] = cmn[nj];
            cmxS[w][nj * 16 + l15] = cmx[nj];
        }
    }
    __syncthreads();
    if (t < BM) {
        float mn = cmnS[0][t], mx = cmxS[0][t];
#pragma unroll
        for (int ww = 1; ww < 4; ++ww) {
            mn = fminf(mn, cmnS[ww][t]);
            mx = fmaxf(mx, cmxS[ww][t]);
        }
        atomicMax(&rmxg[c0 + t], __float_as_uint(mx));
        atomicMin(&rmng[c0 + t], __float_as_uint(mn));
    }
}

__global__ __launch_bounds__(256) void k_mm_sum(const unsigned* __restrict__ rmxg,
                                                const unsigned* __restrict__ rmng,
                                                double* __restrict__ sums) {
    const int n = blockIdx.x * 256 + threadIdx.x;
    const float mx = sqrtf(__uint_as_float(rmxg[n]));
    const float mn = sqrtf(__uint_as_float(rmng[n]));
    float v = mx - mn;
    v = waveReduceSumF(v);
    __shared__ float part[4];
    if ((threadIdx.x & 63) == 0) part[threadIdx.x >> 6] = v;
    __syncthreads();
    if (threadIdx.x == 0)
        atomicAdd(&sums[2], (double)(part[0] + part[1] + part[2] + part[3]));
}

__global__ void k_final(const double* __restrict__ sums, float* __restrict__ out) {
    const double loss = 1.25 * (sums[1] / (double)((size_t)NZ * D));
    const double qq = 0.1 * (sums[2] / (double)NE) + 0.1 * sums[0];
    out[(size_t)NZ * D + NZ] = (float)loss;
    out[(size_t)NZ * D + NZ + 1] = (float)qq;
}

extern "C" void kernel_launch(void* const* d_in, const int* in_sizes, int n_in,
                              void* d_out, int out_size, void* d_ws, size_t ws_size,
                              hipStream_t stream) {
    const float* z = (const float*)d_in[0];
    const float* emb = (const float*)d_in[1];
    float* out = (float*)d_out;
    char* ws = (char*)d_ws;

    double* sums = (double*)(ws + WS_SUMS);
    int* cnt8 = (int*)(ws + WS_CNT8);
    float* zsq = (float*)(ws + WS_ZSQ);
    float* esq = (float*)(ws + WS_ESQ);
    int* idxb = (int*)(ws + WS_IDX);
    float* ps1 = (float*)(ws + WS_PS1);
    float* ps2 = (float*)(ws + WS_PS2);
    int* pix = (int*)(ws + WS_PIX);
    unsigned* rmx = (unsigned*)(ws + WS_RMX);
    unsigned* rmn = (unsigned*)(ws + WS_RMN);
    unsigned long long* pack = (unsigned long long*)(ws + WS_PACK);
    int* lists = (int*)(ws + WS_LISTS);
    f16x8* zhf = (f16x8*)(ws + WS_ZHF);
    f16x8* ehf = (f16x8*)(ws + WS_EHF);

    hipLaunchKernelGGL(k_init, dim3(1), dim3(1), 0, stream, sums, cnt8);
    hipLaunchKernelGGL(k_initmm, dim3(NZ / 256), dim3(256), 0, stream, rmx, rmn, pack);
    hipLaunchKernelGGL(k_rowsq, dim3(NZ / 256), dim3(256), 0, stream, z, zsq, (double*)nullptr);
    hipLaunchKernelGGL(k_rowsq, dim3(NE / 256), dim3(256), 0, stream, emb, esq, sums);
    hipLaunchKernelGGL(k_cvt_zf, dim3(NZ / 64), dim3(256), 0, stream, z, zhf);
    hipLaunchKernelGGL(k_cvt_ef, dim3(NE / 64), dim3(256), 0, stream, emb, esq, ehf);
    hipLaunchKernelGGL(k_argmin_f, dim3(NZ / BM, NSPLIT_A), dim3(256), 0, stream,
                       zhf, ehf, ps1, ps2, pix);
    hipLaunchKernelGGL(k_pairwise_f, dim3(NTRI), dim3(256), 0, stream,
                       ehf, esq, rmx, rmn);
    hipLaunchKernelGGL(k_merge, dim3(NZ / 256), dim3(256), 0, stream,
                       ps1, ps2, pix, idxb, out + (size_t)NZ * D, cnt8, lists);
    hipLaunchKernelGGL(k_fix_split, dim3(16, 64), dim3(256), 0, stream,
                       z, emb, zsq, esq, cnt8, lists, pack);
    hipLaunchKernelGGL(k_fixdecode, dim3(NZ / 256), dim3(256), 0, stream,
                       pack, idxb, out + (size_t)NZ * D);
    hipLaunchKernelGGL(k_gather, dim3(NZ / 4), dim3(256), 0, stream,
                       z, emb, idxb, out, sums);
    hipLaunchKernelGGL(k_mm_sum, dim3(NE / 256), dim3(256), 0, stream,
                       rmx, rmn, sums);
    hipLaunchKernelGGL(k_final, dim3(1), dim3(1), 0, stream, sums, out);
}

// Round 10
// 474.598 us; speedup vs baseline: 2.3386x; 1.4147x over previous
//
#include <hip/hip_runtime.h>

#define D 256
#define DA 288                     // augmented K (one extra 32-block)
#define NKB 9                      // DA/32
#define NKB_P 8                    // pairwise uses un-augmented 256
#define NE 8192
#define NZ 16384
#define BM 128
#define BK 32
#define LDA (BM + 4)               // fp32 k-major LDS stride (k_fix_split)
#define NB (NE / BM)
#define NTRI (NB * (NB + 1) / 2)
#define NSPLIT_A 8
#define SPLIT_NA (NE / NSPLIT_A)   // 1024
#define GAPTH_A 0.4096f            // 1e-4 score units * 2^12 (acc units)
#define LDM 17
#define NGB (NZ / 4)               // gather blocks = 4096

// fp32-path LDS swizzle (verified R4-R9, k_fix_split only)
#define SROT(kk) (8 * ((((kk) >> 2)) & 3))
#define SWZR(kk, r) ((((r) + SROT(kk)) & 127))

typedef _Float16 f16x8 __attribute__((ext_vector_type(8)));
typedef _Float16 f16x4 __attribute__((ext_vector_type(4)));
typedef float f32x4 __attribute__((ext_vector_type(4)));

#define MFMA16(a, b, c) __builtin_amdgcn_mfma_f32_16x16x32_f16(a, b, c, 0, 0, 0)

// ---------------- workspace layout (bytes) ----------------
#define WS_SUMS   0                            // double[4]
#define WS_CNT8   64                           // int[8]
#define WS_ZSQ    256                          // float[NZ]
#define WS_ESQ    (WS_ZSQ + NZ * 4)            // float[NE]
#define WS_IDX    (WS_ESQ + NE * 4)            // int[NZ]
#define WS_PS1    (WS_IDX + NZ * 4)            // float[NZ*8]
#define WS_PS2    (WS_PS1 + NZ * NSPLIT_A * 4)
#define WS_PIX    (WS_PS2 + NZ * NSPLIT_A * 4)
#define WS_RMX    (WS_PIX + NZ * NSPLIT_A * 4) // uint[NE]
#define WS_RMN    (WS_RMX + NE * 4)            // uint[NE]
#define WS_PACK   (WS_RMN + NE * 4)            // u64[NZ]
#define WS_GPART  (WS_PACK + NZ * 8)           // double[NGB]
#define WS_LISTS  (WS_GPART + NGB * 8)         // int[8][NZ]
#define WS_ZHF    (WS_LISTS + NZ * NSPLIT_A * 4)   // frag-major f16 z
#define WS_EHF    (WS_ZHF + (size_t)(NZ / 16) * NKB * 64 * 8 * 2)

__device__ __forceinline__ float waveReduceSumF(float v) {
    v += __shfl_down(v, 32); v += __shfl_down(v, 16); v += __shfl_down(v, 8);
    v += __shfl_down(v, 4);  v += __shfl_down(v, 2);  v += __shfl_down(v, 1);
    return v;
}
__device__ __forceinline__ double waveReduceSumD(double v) {
    v += __shfl_down(v, 32); v += __shfl_down(v, 16); v += __shfl_down(v, 8);
    v += __shfl_down(v, 4);  v += __shfl_down(v, 2);  v += __shfl_down(v, 1);
    return v;
}

__global__ void k_init(double* sums, int* cnt8) {
    sums[0] = 0.0; sums[1] = 0.0; sums[2] = 0.0; sums[3] = 0.0;
#pragma unroll
    for (int s = 0; s < 8; ++s) cnt8[s] = 0;
}

__global__ __launch_bounds__(256) void k_initmm(unsigned* __restrict__ rmx,
                                                unsigned* __restrict__ rmn,
                                                unsigned long long* __restrict__ pack) {
    const int n = blockIdx.x * 256 + threadIdx.x;
    if (n < NE) { rmx[n] = 0u; rmn[n] = 0x7F800000u; }
    pack[n] = ~0ull;
}

// np.sum(x*x, axis=1) bit-exact (numpy pairwise summation, n=256)
__global__ __launch_bounds__(256) void k_rowsq(const float* __restrict__ src,
                                               float* __restrict__ rsq,
                                               double* __restrict__ sums) {
    const int row = blockIdx.x * 256 + threadIdx.x;
    const float* p = src + (size_t)row * D;
    float h[2];
#pragma unroll
    for (int half = 0; half < 2; ++half) {
        const float* q = p + half * 128;
        float4 a0 = *(const float4*)&q[0];
        float4 a1 = *(const float4*)&q[4];
        float r0 = __fmul_rn(a0.x, a0.x);
        float r1 = __fmul_rn(a0.y, a0.y);
        float r2 = __fmul_rn(a0.z, a0.z);
        float r3 = __fmul_rn(a0.w, a0.w);
        float r4 = __fmul_rn(a1.x, a1.x);
        float r5 = __fmul_rn(a1.y, a1.y);
        float r6 = __fmul_rn(a1.z, a1.z);
        float r7 = __fmul_rn(a1.w, a1.w);
#pragma unroll
        for (int i = 8; i < 128; i += 8) {
            const float4 b0 = *(const float4*)&q[i];
            const float4 b1 = *(const float4*)&q[i + 4];
            r0 = __fadd_rn(r0, __fmul_rn(b0.x, b0.x));
            r1 = __fadd_rn(r1, __fmul_rn(b0.y, b0.y));
            r2 = __fadd_rn(r2, __fmul_rn(b0.z, b0.z));
            r3 = __fadd_rn(r3, __fmul_rn(b0.w, b0.w));
            r4 = __fadd_rn(r4, __fmul_rn(b1.x, b1.x));
            r5 = __fadd_rn(r5, __fmul_rn(b1.y, b1.y));
            r6 = __fadd_rn(r6, __fmul_rn(b1.z, b1.z));
            r7 = __fadd_rn(r7, __fmul_rn(b1.w, b1.w));
        }
        const float t01 = __fadd_rn(r0, r1);
        const float t23 = __fadd_rn(r2, r3);
        const float t45 = __fadd_rn(r4, r5);
        const float t67 = __fadd_rn(r6, r7);
        h[half] = __fadd_rn(__fadd_rn(t01, t23), __fadd_rn(t45, t67));
    }
    const float tot = __fadd_rn(h[0], h[1]);
    rsq[row] = tot;
    if (sums != nullptr) {
        double s = waveReduceSumD((double)tot);
        if ((threadIdx.x & 63) == 0) atomicAdd(&sums[0], s);
    }
}

// ---- fragment-major converters (64 rows per block, LDS transpose) ----
__global__ __launch_bounds__(256) void k_cvt_zf(const float* __restrict__ z,
                                                f16x8* __restrict__ zf) {
    __shared__ _Float16 Ls[64 * 296];
    const int t = threadIdx.x;
    const int row0 = blockIdx.x * 64;
#pragma unroll
    for (int i = 0; i < 16; ++i) {
        const int f4 = i * 256 + t;
        const int r = f4 >> 6, c4 = f4 & 63;
        const float4 v = *(const float4*)&z[(size_t)(row0 + r) * D + c4 * 4];
        f16x4 h;
        h[0] = (_Float16)v.x; h[1] = (_Float16)v.y;
        h[2] = (_Float16)v.z; h[3] = (_Float16)v.w;
        *(f16x4*)&Ls[r * 296 + c4 * 4] = h;
    }
#pragma unroll
    for (int i = 0; i < 8; ++i) {
        const int idx = i * 256 + t;
        const int r = idx >> 5, c = idx & 31;
        Ls[r * 296 + 256 + c] = (c == 0) ? (_Float16)1.0f : (_Float16)0.0f;
    }
    __syncthreads();
    const int l = t & 63, w = t >> 6;
#pragma unroll
    for (int kb = 0; kb < NKB; ++kb) {
        const f16x8 fr = *(const f16x8*)&Ls[(w * 16 + (l & 15)) * 296 + kb * 32 + (l >> 4) * 8];
        zf[((size_t)(blockIdx.x * 4 + w) * NKB + kb) * 64 + l] = fr;
    }
}

__global__ __launch_bounds__(256) void k_cvt_ef(const float* __restrict__ e,
                                                const float* __restrict__ esq,
                                                f16x8* __restrict__ ef) {
    __shared__ _Float16 Ls[64 * 296];
    const int t = threadIdx.x;
    const int row0 = blockIdx.x * 64;
#pragma unroll
    for (int i = 0; i < 16; ++i) {
        const int f4 = i * 256 + t;
        const int r = f4 >> 6, c4 = f4 & 63;
        const float4 v = *(const float4*)&e[(size_t)(row0 + r) * D + c4 * 4];
        f16x4 h;
        h[0] = (_Float16)(v.x * 8192.0f); h[1] = (_Float16)(v.y * 8192.0f);
        h[2] = (_Float16)(v.z * 8192.0f); h[3] = (_Float16)(v.w * 8192.0f);
        *(f16x4*)&Ls[r * 296 + c4 * 4] = h;
    }
#pragma unroll
    for (int i = 0; i < 8; ++i) {
        const int idx = i * 256 + t;
        const int r = idx >> 5, c = idx & 31;
        Ls[r * 296 + 256 + c] =
            (c == 0) ? (_Float16)(esq[row0 + r] * -4096.0f) : (_Float16)0.0f;
    }
    __syncthreads();
    const int l = t & 63, w = t >> 6;
#pragma unroll
    for (int kb = 0; kb < NKB; ++kb) {
        const f16x8 fr = *(const f16x8*)&Ls[(w * 16 + (l & 15)) * 296 + kb * 32 + (l >> 4) * 8];
        ef[((size_t)(blockIdx.x * 4 + w) * NKB + kb) * 64 + l] = fr;
    }
}

// ---- LDS-free MFMA argmin, A-fragments resident in VGPRs ----
__global__ __launch_bounds__(256) void k_argmin_f(
        const f16x8* __restrict__ zf, const f16x8* __restrict__ ef,
        float* __restrict__ ps1, float* __restrict__ ps2, int* __restrict__ pix) {
    const int t = threadIdx.x;
    const int l = t & 63;
    const int w = t >> 6;
    const int quad = l >> 4;
    const int l15 = l & 15;
    const int row0 = blockIdx.x * BM;
    const int sp = blockIdx.y;
    const int arb0 = blockIdx.x * 8 + w * 2;

    f16x8 ah[2][NKB];
#pragma unroll
    for (int kb = 0; kb < NKB; ++kb) {
        ah[0][kb] = zf[((size_t)arb0 * NKB + kb) * 64 + l];
        ah[1][kb] = zf[((size_t)(arb0 + 1) * NKB + kb) * 64 + l];
    }

    float b1[8], b2[8];
    int i1[8];
#pragma unroll
    for (int s = 0; s < 8; ++s) { b1[s] = -3.4e38f; b2[s] = -3.4e38f; i1[s] = 0; }

    for (int ch = 0; ch < 16; ++ch) {
        const int cb16 = sp * 64 + ch * 4;
        const int c0 = sp * SPLIT_NA + ch * 64;

        f32x4 acc[2][4];
#pragma unroll
        for (int mi = 0; mi < 2; ++mi)
#pragma unroll
            for (int nj = 0; nj < 4; ++nj) acc[mi][nj] = (f32x4){0.f, 0.f, 0.f, 0.f};

#pragma unroll
        for (int kb = 0; kb < NKB; ++kb) {
            f16x8 bh[4];
#pragma unroll
            for (int nj = 0; nj < 4; ++nj)
                bh[nj] = ef[((size_t)(cb16 + nj) * NKB + kb) * 64 + l];
#pragma unroll
            for (int nj = 0; nj < 4; ++nj) {
                acc[0][nj] = MFMA16(ah[0][kb], bh[nj], acc[0][nj]);
                acc[1][nj] = MFMA16(ah[1][kb], bh[nj], acc[1][nj]);
            }
        }

#pragma unroll
        for (int nj = 0; nj < 4; ++nj) {
            const int gcol = c0 + nj * 16 + l15;
#pragma unroll
            for (int mi = 0; mi < 2; ++mi)
#pragma unroll
                for (int r = 0; r < 4; ++r) {
                    const int s = mi * 4 + r;
                    const float a = acc[mi][nj][r];
                    b2[s] = fmaxf(b2[s], fminf(a, b1[s]));
                    i1[s] = (a > b1[s]) ? gcol : i1[s];
                    b1[s] = fmaxf(b1[s], a);
                }
        }
    }

    float V1[8], V2[8];
    int II[8];
#pragma unroll
    for (int s = 0; s < 8; ++s) {
        float v1 = b1[s], v2 = b2[s];
        int ii = i1[s];
#pragma unroll
        for (int m = 1; m <= 8; m <<= 1) {
            const float o1 = __shfl_xor(v1, m);
            const float o2 = __shfl_xor(v2, m);
            const int oi = __shfl_xor(ii, m);
            const float n2 = fmaxf(fminf(v1, o1), fmaxf(v2, o2));
            const bool take = (o1 > v1) || (o1 == v1 && oi < ii);
            ii = take ? oi : ii;
            v1 = fmaxf(v1, o1);
            v2 = n2;
        }
        V1[s] = v1; V2[s] = v2; II[s] = ii;
    }
    if (l15 == 0) {
#pragma unroll
        for (int s = 0; s < 8; ++s) {
            const int mi = s >> 2, r = s & 3;
            const int row = row0 + w * 32 + mi * 16 + quad * 4 + r;
            ps1[(size_t)row * NSPLIT_A + sp] = -V1[s];
            ps2[(size_t)row * NSPLIT_A + sp] = -V2[s];
            pix[(size_t)row * NSPLIT_A + sp] = II[s];
        }
    }
}

// merge splits; provisional idx; append near-tie rows to candidate-split lists
__global__ __launch_bounds__(256) void k_merge(const float* __restrict__ ps1,
                                               const float* __restrict__ ps2,
                                               const int* __restrict__ pi,
                                               int* __restrict__ idxbuf,
                                               float* __restrict__ outidx,
                                               int* __restrict__ cnt8,
                                               int* __restrict__ lists) {
    const int n = blockIdx.x * 256 + threadIdx.x;
    float v1 = ps1[n * NSPLIT_A];
    float v2 = ps2[n * NSPLIT_A];
    int ii1 = pi[n * NSPLIT_A];
#pragma unroll
    for (int s = 1; s < NSPLIT_A; ++s) {
        const float s1 = ps1[n * NSPLIT_A + s];
        const float s2 = ps2[n * NSPLIT_A + s];
        const int ii = pi[n * NSPLIT_A + s];
        if (s1 < v1 || (s1 == v1 && ii < ii1)) {
            v2 = fminf(fminf(v2, v1), s2);
            v1 = s1; ii1 = ii;
        } else {
            v2 = fminf(v2, s1);
        }
    }
    idxbuf[n] = ii1;
    outidx[n] = (float)ii1;
    if (v2 - v1 < GAPTH_A) {
        const float lim = v1 + GAPTH_A;
#pragma unroll
        for (int s = 0; s < NSPLIT_A; ++s)
            if (ps1[n * NSPLIT_A + s] <= lim) {
                const int p = atomicAdd(&cnt8[s], 1);
                lists[s * NZ + p] = n;
            }
    }
}

// np-bit-exact fp32 repair: one block = 128 gathered rows x ONE 128-col chunk
__global__ __launch_bounds__(256) void k_fix_split(const float* __restrict__ z,
                                                   const float* __restrict__ emb,
                                                   const float* __restrict__ zsq,
                                                   const float* __restrict__ esq,
                                                   const int* __restrict__ cnt8,
                                                   const int* __restrict__ lists,
                                                   unsigned long long* __restrict__ pack) {
    __shared__ float As[BK * LDA];
    __shared__ float Bs[BK * LDA];
    __shared__ float Sq[BM];
    __shared__ int frow[BM];

    const int s = blockIdx.y >> 3;
    const int chunk = blockIdx.y & 7;
    const int ns = cnt8[s];
    const int c0 = s * SPLIT_NA + chunk * BM;
    const int t = threadIdx.x;
    const int tr = t >> 4;
    const int tc = t & 15;
    const int sr = t >> 3;
    const int skq = t & 7;
    const int wrot = 8 * (skq & 3);

    for (int rb = blockIdx.x; rb * BM < ns; rb += gridDim.x) {
        __syncthreads();
        if (t < BM) {
            const int fi = rb * BM + t;
            frow[t] = (fi < ns) ? lists[s * NZ + fi] : lists[s * NZ];
            Sq[t] = esq[c0 + t];
        }
        __syncthreads();

        float zqr[8];
#pragma unroll
        for (int i = 0; i < 8; ++i) zqr[i] = zsq[frow[tr * 8 + i]];

        float best[8];
        int bidx[8];
#pragma unroll
        for (int i = 0; i < 8; ++i) { best[i] = 3.4e38f; bidx[i] = 0; }

        float acc[8][8];
#pragma unroll
        for (int i = 0; i < 8; ++i)
#pragma unroll
            for (int j = 0; j < 8; ++j) acc[i][j] = 0.f;

        for (int kb = 0; kb < D; kb += BK) {
            __syncthreads();
#pragma unroll
            for (int q = 0; q < 4; ++q) {
                const int r = sr + 32 * q;
                const int rr = (r + wrot) & 127;
                const float4 av = *(const float4*)&z[(size_t)frow[r] * D + kb + 4 * skq];
                const float4 bv = *(const float4*)&emb[(size_t)(c0 + r) * D + kb + 4 * skq];
                As[(4 * skq + 0) * LDA + rr] = av.x;
                As[(4 * skq + 1) * LDA + rr] = av.y;
                As[(4 * skq + 2) * LDA + rr] = av.z;
                As[(4 * skq + 3) * LDA + rr] = av.w;
                Bs[(4 * skq + 0) * LDA + rr] = bv.x;
                Bs[(4 * skq + 1) * LDA + rr] = bv.y;
                Bs[(4 * skq + 2) * LDA + rr] = bv.z;
                Bs[(4 * skq + 3) * LDA + rr] = bv.w;
            }
            __syncthreads();
#pragma unroll
            for (int k = 0; k < BK; ++k) {
                const float4 a0 = *(const float4*)&As[k * LDA + SWZR(k, tr * 8)];
                const float4 a1 = *(const float4*)&As[k * LDA + SWZR(k, tr * 8 + 4)];
                const float4 b0 = *(const float4*)&Bs[k * LDA + SWZR(k, tc * 4)];
                const float4 b1 = *(const float4*)&Bs[k * LDA + SWZR(k, 64 + tc * 4)];
                const float a[8] = {a0.x, a0.y, a0.z, a0.w, a1.x, a1.y, a1.z, a1.w};
                const float b[8] = {b0.x, b0.y, b0.z, b0.w, b1.x, b1.y, b1.z, b1.w};
#pragma unroll
                for (int i = 0; i < 8; ++i)
#pragma unroll
                    for (int j = 0; j < 8; ++j)
                        acc[i][j] = fmaf(a[i], b[j], acc[i][j]);
            }
        }
#pragma unroll
        for (int jj = 0; jj < 8; ++jj) {
            const int cloc = (jj < 4) ? (tc * 4 + jj) : (64 + tc * 4 + (jj - 4));
            const float sq = Sq[cloc];
            const int gcol = c0 + cloc;
#pragma unroll
            for (int i = 0; i < 8; ++i) {
                const float t1 = __fadd_rn(zqr[i], sq);
                const float sc = fmaf(-2.f, acc[i][jj], t1);
                if (sc < best[i]) { best[i] = sc; bidx[i] = gcol; }
            }
        }
        __syncthreads();

        float* Rs = As;
        int* Ri = (int*)Bs;
#pragma unroll
        for (int i = 0; i < 8; ++i) {
            Rs[(tr * 8 + i) * LDM + tc] = best[i];
            Ri[(tr * 8 + i) * LDM + tc] = bidx[i];
        }
        __syncthreads();
        if (t < BM) {
            float bs = Rs[t * LDM];
            int bi = Ri[t * LDM];
#pragma unroll
            for (int c = 1; c < 16; ++c) {
                const float sc = Rs[t * LDM + c];
                const int ii = Ri[t * LDM + c];
                if (sc < bs || (sc == bs && ii < bi)) { bs = sc; bi = ii; }
            }
            const int fi = rb * BM + t;
            if (fi < ns) {
                const unsigned long long pk =
                    ((unsigned long long)__float_as_uint(bs) << 32) | (unsigned)bi;
                atomicMin(&pack[frow[t]], pk);
            }
        }
    }
}

__global__ __launch_bounds__(256) void k_fixdecode(const unsigned long long* __restrict__ pack,
                                                   int* __restrict__ idxbuf,
                                                   float* __restrict__ outidx) {
    const int n = blockIdx.x * 256 + threadIdx.x;
    const unsigned long long p = pack[n];
    if (p != ~0ull) {
        const int idx = (int)(p & 0xffffffffu);
        idxbuf[n] = idx;
        outidx[n] = (float)idx;
    }
}

// gather z_q into out; per-block partial of sum((z_q-z)^2) -> gpart (NO atomics)
__global__ __launch_bounds__(256) void k_gather(const float* __restrict__ z,
                                                const float* __restrict__ emb,
                                                const int* __restrict__ idxbuf,
                                                float* __restrict__ out,
                                                double* __restrict__ gpart) {
    __shared__ double part[4];
    const int row = blockIdx.x * 4 + (threadIdx.x >> 6);
    const int lane = threadIdx.x & 63;
    const int idx = idxbuf[row];
    const float4 e4 = *(const float4*)&emb[(size_t)idx * D + lane * 4];
    const float4 z4 = *(const float4*)&z[(size_t)row * D + lane * 4];
    *(float4*)&out[(size_t)row * D + lane * 4] = e4;
    const float dx = e4.x - z4.x, dy = e4.y - z4.y;
    const float dzv = e4.z - z4.z, dw = e4.w - z4.w;
    float s = dx * dx + dy * dy + dzv * dzv + dw * dw;
    s = waveReduceSumF(s);
    if (lane == 0) part[threadIdx.x >> 6] = (double)s;
    __syncthreads();
    if (threadIdx.x == 0)
        gpart[blockIdx.x] = part[0] + part[1] + part[2] + part[3];
}

// ---- pairwise cdist row min/max via frag-direct MFMA, triangular tiles ----
__global__ __launch_bounds__(256) void k_pairwise_f(const f16x8* __restrict__ ef,
                                                    const float* __restrict__ esq,
                                                    unsigned* __restrict__ rmxg,
                                                    unsigned* __restrict__ rmng) {
    __shared__ float cmnS[4][128];
    __shared__ float cmxS[4][128];

    int p = blockIdx.x;
    int bi = 0;
    while (p >= NB - bi) { p -= NB - bi; ++bi; }
    const int bj = bi + p;
    const int row0 = bi * BM;
    const int c0 = bj * BM;

    const int t = threadIdx.x;
    const int l = t & 63;
    const int w = t >> 6;
    const int quad = l >> 4;
    const int l15 = l & 15;

    float sR[8], sC[8];
#pragma unroll
    for (int mi = 0; mi < 2; ++mi)
#pragma unroll
        for (int r = 0; r < 4; ++r)
            sR[mi * 4 + r] = esq[row0 + w * 32 + mi * 16 + quad * 4 + r];
#pragma unroll
    for (int nj = 0; nj < 8; ++nj) sC[nj] = esq[c0 + nj * 16 + l15];

    const int arb = bi * 8 + w * 2;
    const int cfb = bj * 8;

    f32x4 acc[2][8];
#pragma unroll
    for (int mi = 0; mi < 2; ++mi)
#pragma unroll
        for (int nj = 0; nj < 8; ++nj) acc[mi][nj] = (f32x4){0.f, 0.f, 0.f, 0.f};

#pragma unroll
    for (int kb = 0; kb < NKB_P; ++kb) {
        const f16x8 ah0 = ef[((size_t)arb * NKB + kb) * 64 + l];
        const f16x8 ah1 = ef[((size_t)(arb + 1) * NKB + kb) * 64 + l];
        f16x8 bh[8];
#pragma unroll
        for (int nj = 0; nj < 8; ++nj)
            bh[nj] = ef[((size_t)(cfb + nj) * NKB + kb) * 64 + l];
#pragma unroll
        for (int nj = 0; nj < 8; ++nj) {
            acc[0][nj] = MFMA16(ah0, bh[nj], acc[0][nj]);
            acc[1][nj] = MFMA16(ah1, bh[nj], acc[1][nj]);
        }
    }

    float rmn[8], rmx[8], cmn[8], cmx[8];
#pragma unroll
    for (int s = 0; s < 8; ++s) { rmn[s] = 3.4e38f; rmx[s] = 0.f; cmn[s] = 3.4e38f; cmx[s] = 0.f; }
#pragma unroll
    for (int mi = 0; mi < 2; ++mi)
#pragma unroll
        for (int nj = 0; nj < 8; ++nj)
#pragma unroll
            for (int r = 0; r < 4; ++r) {
                const int s = mi * 4 + r;
                const float t1 = __fadd_rn(sR[s], sC[nj]);
                const float d2 = fmaf(-0x1p-25f, acc[mi][nj][r], t1);
                const float d2c = fmaxf(d2, 0.f);
                rmn[s] = fminf(rmn[s], d2c);
                rmx[s] = fmaxf(rmx[s], d2c);
                cmn[nj] = fminf(cmn[nj], d2c);
                cmx[nj] = fmaxf(cmx[nj], d2c);
            }

#pragma unroll
    for (int s = 0; s < 8; ++s) {
#pragma unroll
        for (int m = 1; m <= 8; m <<= 1) {
            rmn[s] = fminf(rmn[s], __shfl_xor(rmn[s], m));
            rmx[s] = fmaxf(rmx[s], __shfl_xor(rmx[s], m));
        }
    }
    if (l15 == 0) {
#pragma unroll
        for (int s = 0; s < 8; ++s) {
            const int mi = s >> 2, r = s & 3;
            const int row = row0 + w * 32 + mi * 16 + quad * 4 + r;
            atomicMax(&rmxg[row], __float_as_uint(rmx[s]));
            atomicMin(&rmng[row], __float_as_uint(rmn[s]));
        }
    }

#pragma unroll
    for (int nj = 0; nj < 8; ++nj) {
#pragma unroll
        for (int m = 16; m <= 32; m <<= 1) {
            cmn[nj] = fminf(cmn[nj], __shfl_xor(cmn[nj], m));
            cmx[nj] = fmaxf(cmx[nj], __shfl_xor(cmx[nj], m));
        }
    }
    if (quad == 0) {
#pragma unroll
        for (int nj = 0; nj < 8; ++nj) {
            cmnS[w][nj * 16 + l15] = cmn[nj];
            cmxS[w][nj * 16 + l15] = cmx[nj];
        }
    }
    __syncthreads();
    if (t < BM) {
        float mn = cmnS[0][t], mx = cmxS[0][t];
#pragma unroll
        for (int ww = 1; ww < 4; ++ww) {
            mn = fminf(mn, cmnS[ww][t]);
            mx = fmaxf(mx, cmxS[ww][t]);
        }
        atomicMax(&rmxg[c0 + t], __float_as_uint(mx));
        atomicMin(&rmng[c0 + t], __float_as_uint(mn));
    }
}

__global__ __launch_bounds__(256) void k_mm_sum(const unsigned* __restrict__ rmxg,
                                                const unsigned* __restrict__ rmng,
                                                double* __restrict__ sums) {
    const int n = blockIdx.x * 256 + threadIdx.x;
    const float mx = sqrtf(__uint_as_float(rmxg[n]));
    const float mn = sqrtf(__uint_as_float(rmng[n]));
    float v = mx - mn;
    v = waveReduceSumF(v);
    __shared__ float part[4];
    if ((threadIdx.x & 63) == 0) part[threadIdx.x >> 6] = v;
    __syncthreads();
    if (threadIdx.x == 0)
        atomicAdd(&sums[2], (double)(part[0] + part[1] + part[2] + part[3]));
}

// final reduce: sum 4096 gather-partials + emit both scalars
__global__ __launch_bounds__(256) void k_final(const double* __restrict__ sums,
                                               const double* __restrict__ gpart,
                                               float* __restrict__ out) {
    __shared__ double part[4];
    const int t = threadIdx.x;
    double s = 0.0;
#pragma unroll
    for (int i = 0; i < NGB / 256; ++i) s += gpart[i * 256 + t];
    s = waveReduceSumD(s);
    if ((t & 63) == 0) part[t >> 6] = s;
    __syncthreads();
    if (t == 0) {
        const double diff2 = part[0] + part[1] + part[2] + part[3];
        const double loss = 1.25 * (diff2 / (double)((size_t)NZ * D));
        const double qq = 0.1 * (sums[2] / (double)NE) + 0.1 * sums[0];
        out[(size_t)NZ * D + NZ] = (float)loss;
        out[(size_t)NZ * D + NZ + 1] = (float)qq;
    }
}

extern "C" void kernel_launch(void* const* d_in, const int* in_sizes, int n_in,
                              void* d_out, int out_size, void* d_ws, size_t ws_size,
                              hipStream_t stream) {
    const float* z = (const float*)d_in[0];
    const float* emb = (const float*)d_in[1];
    float* out = (float*)d_out;
    char* ws = (char*)d_ws;

    double* sums = (double*)(ws + WS_SUMS);
    int* cnt8 = (int*)(ws + WS_CNT8);
    float* zsq = (float*)(ws + WS_ZSQ);
    float* esq = (float*)(ws + WS_ESQ);
    int* idxb = (int*)(ws + WS_IDX);
    float* ps1 = (float*)(ws + WS_PS1);
    float* ps2 = (float*)(ws + WS_PS2);
    int* pix = (int*)(ws + WS_PIX);
    unsigned* rmx = (unsigned*)(ws + WS_RMX);
    unsigned* rmn = (unsigned*)(ws + WS_RMN);
    unsigned long long* pack = (unsigned long long*)(ws + WS_PACK);
    double* gpart = (double*)(ws + WS_GPART);
    int* lists = (int*)(ws + WS_LISTS);
    f16x8* zhf = (f16x8*)(ws + WS_ZHF);
    f16x8* ehf = (f16x8*)(ws + WS_EHF);

    hipLaunchKernelGGL(k_init, dim3(1), dim3(1), 0, stream, sums, cnt8);
    hipLaunchKernelGGL(k_initmm, dim3(NZ / 256), dim3(256), 0, stream, rmx, rmn, pack);
    hipLaunchKernelGGL(k_rowsq, dim3(NZ / 256), dim3(256), 0, stream, z, zsq, (double*)nullptr);
    hipLaunchKernelGGL(k_rowsq, dim3(NE / 256), dim3(256), 0, stream, emb, esq, sums);
    hipLaunchKernelGGL(k_cvt_zf, dim3(NZ / 64), dim3(256), 0, stream, z, zhf);
    hipLaunchKernelGGL(k_cvt_ef, dim3(NE / 64), dim3(256), 0, stream, emb, esq, ehf);
    hipLaunchKernelGGL(k_argmin_f, dim3(NZ / BM, NSPLIT_A), dim3(256), 0, stream,
                       zhf, ehf, ps1, ps2, pix);
    hipLaunchKernelGGL(k_pairwise_f, dim3(NTRI), dim3(256), 0, stream,
                       ehf, esq, rmx, rmn);
    hipLaunchKernelGGL(k_merge, dim3(NZ / 256), dim3(256), 0, stream,
                       ps1, ps2, pix, idxb, out + (size_t)NZ * D, cnt8, lists);
    hipLaunchKernelGGL(k_fix_split, dim3(16, 64), dim3(256), 0, stream,
                       z, emb, zsq, esq, cnt8, lists, pack);
    hipLaunchKernelGGL(k_fixdecode, dim3(NZ / 256), dim3(256), 0, stream,
                       pack, idxb, out + (size_t)NZ * D);
    hipLaunchKernelGGL(k_gather, dim3(NGB), dim3(256), 0, stream,
                       z, emb, idxb, out, gpart);
    hipLaunchKernelGGL(k_mm_sum, dim3(NE / 256), dim3(256), 0, stream,
                       rmx, rmn, sums);
    hipLaunchKernelGGL(k_final, dim3(1), dim3(256), 0, stream, sums, gpart, out);
}

// Round 11
// 460.636 us; speedup vs baseline: 2.4095x; 1.0303x over previous
//
#include <hip/hip_runtime.h>

#define D 256
#define DA 288                     // augmented K (one extra 32-block)
#define NKB 9                      // DA/32
#define NKB_P 8                    // pairwise uses un-augmented 256
#define NE 8192
#define NZ 16384
#define BM 128
#define BK 32
#define LDA (BM + 4)               // fp32 k-major LDS stride (k_fix_split)
#define NB (NE / BM)
#define NTRI (NB * (NB + 1) / 2)
#define NSPLIT_A 8
#define SPLIT_NA (NE / NSPLIT_A)   // 1024
#define GAPTH_A 0.4096f            // 1e-4 score units * 2^12 (acc units)
#define LDM 17
#define NGB (NZ / 4)               // gather blocks = 4096

// fp32-path LDS swizzle (verified R4-R10, k_fix_split only)
#define SROT(kk) (8 * ((((kk) >> 2)) & 3))
#define SWZR(kk, r) ((((r) + SROT(kk)) & 127))

typedef _Float16 f16x8 __attribute__((ext_vector_type(8)));
typedef _Float16 f16x4 __attribute__((ext_vector_type(4)));
typedef float f32x4 __attribute__((ext_vector_type(4)));

#define MFMA16(a, b, c) __builtin_amdgcn_mfma_f32_16x16x32_f16(a, b, c, 0, 0, 0)

// ---------------- workspace layout (bytes) ----------------
#define WS_SUMS   0                            // double[4]
#define WS_CNT8   64                           // int[8]
#define WS_ZSQ    256                          // float[NZ]
#define WS_ESQ    (WS_ZSQ + NZ * 4)            // float[NE]
#define WS_IDX    (WS_ESQ + NE * 4)            // int[NZ]
#define WS_PS1    (WS_IDX + NZ * 4)            // float[NZ*8]
#define WS_PS2    (WS_PS1 + NZ * NSPLIT_A * 4)
#define WS_PIX    (WS_PS2 + NZ * NSPLIT_A * 4)
#define WS_RMX    (WS_PIX + NZ * NSPLIT_A * 4) // uint[NE]
#define WS_RMN    (WS_RMX + NE * 4)            // uint[NE]
#define WS_PACK   (WS_RMN + NE * 4)            // u64[NZ]
#define WS_GPART  (WS_PACK + NZ * 8)           // double[NGB]
#define WS_LISTS  (WS_GPART + NGB * 8)         // int[8][NZ]
#define WS_ZHF    (WS_LISTS + NZ * NSPLIT_A * 4)   // frag-major f16 z
#define WS_EHF    (WS_ZHF + (size_t)(NZ / 16) * NKB * 64 * 8 * 2)

__device__ __forceinline__ float waveReduceSumF(float v) {
    v += __shfl_down(v, 32); v += __shfl_down(v, 16); v += __shfl_down(v, 8);
    v += __shfl_down(v, 4);  v += __shfl_down(v, 2);  v += __shfl_down(v, 1);
    return v;
}
__device__ __forceinline__ double waveReduceSumD(double v) {
    v += __shfl_down(v, 32); v += __shfl_down(v, 16); v += __shfl_down(v, 8);
    v += __shfl_down(v, 4);  v += __shfl_down(v, 2);  v += __shfl_down(v, 1);
    return v;
}

__global__ void k_init(double* sums, int* cnt8) {
    sums[0] = 0.0; sums[1] = 0.0; sums[2] = 0.0; sums[3] = 0.0;
#pragma unroll
    for (int s = 0; s < 8; ++s) cnt8[s] = 0;
}

__global__ __launch_bounds__(256) void k_initmm(unsigned* __restrict__ rmx,
                                                unsigned* __restrict__ rmn,
                                                unsigned long long* __restrict__ pack) {
    const int n = blockIdx.x * 256 + threadIdx.x;
    if (n < NE) { rmx[n] = 0u; rmn[n] = 0x7F800000u; }
    pack[n] = ~0ull;
}

// np.sum(x*x, axis=1) bit-exact (numpy pairwise summation, n=256)
__global__ __launch_bounds__(256) void k_rowsq(const float* __restrict__ src,
                                               float* __restrict__ rsq,
                                               double* __restrict__ sums) {
    const int row = blockIdx.x * 256 + threadIdx.x;
    const float* p = src + (size_t)row * D;
    float h[2];
#pragma unroll
    for (int half = 0; half < 2; ++half) {
        const float* q = p + half * 128;
        float4 a0 = *(const float4*)&q[0];
        float4 a1 = *(const float4*)&q[4];
        float r0 = __fmul_rn(a0.x, a0.x);
        float r1 = __fmul_rn(a0.y, a0.y);
        float r2 = __fmul_rn(a0.z, a0.z);
        float r3 = __fmul_rn(a0.w, a0.w);
        float r4 = __fmul_rn(a1.x, a1.x);
        float r5 = __fmul_rn(a1.y, a1.y);
        float r6 = __fmul_rn(a1.z, a1.z);
        float r7 = __fmul_rn(a1.w, a1.w);
#pragma unroll
        for (int i = 8; i < 128; i += 8) {
            const float4 b0 = *(const float4*)&q[i];
            const float4 b1 = *(const float4*)&q[i + 4];
            r0 = __fadd_rn(r0, __fmul_rn(b0.x, b0.x));
            r1 = __fadd_rn(r1, __fmul_rn(b0.y, b0.y));
            r2 = __fadd_rn(r2, __fmul_rn(b0.z, b0.z));
            r3 = __fadd_rn(r3, __fmul_rn(b0.w, b0.w));
            r4 = __fadd_rn(r4, __fmul_rn(b1.x, b1.x));
            r5 = __fadd_rn(r5, __fmul_rn(b1.y, b1.y));
            r6 = __fadd_rn(r6, __fmul_rn(b1.z, b1.z));
            r7 = __fadd_rn(r7, __fmul_rn(b1.w, b1.w));
        }
        const float t01 = __fadd_rn(r0, r1);
        const float t23 = __fadd_rn(r2, r3);
        const float t45 = __fadd_rn(r4, r5);
        const float t67 = __fadd_rn(r6, r7);
        h[half] = __fadd_rn(__fadd_rn(t01, t23), __fadd_rn(t45, t67));
    }
    const float tot = __fadd_rn(h[0], h[1]);
    rsq[row] = tot;
    if (sums != nullptr) {
        double s = waveReduceSumD((double)tot);
        if ((threadIdx.x & 63) == 0) atomicAdd(&sums[0], s);
    }
}

// ---- fragment-major converters (64 rows per block, LDS transpose) ----
__global__ __launch_bounds__(256) void k_cvt_zf(const float* __restrict__ z,
                                                f16x8* __restrict__ zf) {
    __shared__ _Float16 Ls[64 * 296];
    const int t = threadIdx.x;
    const int row0 = blockIdx.x * 64;
#pragma unroll
    for (int i = 0; i < 16; ++i) {
        const int f4 = i * 256 + t;
        const int r = f4 >> 6, c4 = f4 & 63;
        const float4 v = *(const float4*)&z[(size_t)(row0 + r) * D + c4 * 4];
        f16x4 h;
        h[0] = (_Float16)v.x; h[1] = (_Float16)v.y;
        h[2] = (_Float16)v.z; h[3] = (_Float16)v.w;
        *(f16x4*)&Ls[r * 296 + c4 * 4] = h;
    }
#pragma unroll
    for (int i = 0; i < 8; ++i) {
        const int idx = i * 256 + t;
        const int r = idx >> 5, c = idx & 31;
        Ls[r * 296 + 256 + c] = (c == 0) ? (_Float16)1.0f : (_Float16)0.0f;
    }
    __syncthreads();
    const int l = t & 63, w = t >> 6;
#pragma unroll
    for (int kb = 0; kb < NKB; ++kb) {
        const f16x8 fr = *(const f16x8*)&Ls[(w * 16 + (l & 15)) * 296 + kb * 32 + (l >> 4) * 8];
        zf[((size_t)(blockIdx.x * 4 + w) * NKB + kb) * 64 + l] = fr;
    }
}

__global__ __launch_bounds__(256) void k_cvt_ef(const float* __restrict__ e,
                                                const float* __restrict__ esq,
                                                f16x8* __restrict__ ef) {
    __shared__ _Float16 Ls[64 * 296];
    const int t = threadIdx.x;
    const int row0 = blockIdx.x * 64;
#pragma unroll
    for (int i = 0; i < 16; ++i) {
        const int f4 = i * 256 + t;
        const int r = f4 >> 6, c4 = f4 & 63;
        const float4 v = *(const float4*)&e[(size_t)(row0 + r) * D + c4 * 4];
        f16x4 h;
        h[0] = (_Float16)(v.x * 8192.0f); h[1] = (_Float16)(v.y * 8192.0f);
        h[2] = (_Float16)(v.z * 8192.0f); h[3] = (_Float16)(v.w * 8192.0f);
        *(f16x4*)&Ls[r * 296 + c4 * 4] = h;
    }
#pragma unroll
    for (int i = 0; i < 8; ++i) {
        const int idx = i * 256 + t;
        const int r = idx >> 5, c = idx & 31;
        Ls[r * 296 + 256 + c] =
            (c == 0) ? (_Float16)(esq[row0 + r] * -4096.0f) : (_Float16)0.0f;
    }
    __syncthreads();
    const int l = t & 63, w = t >> 6;
#pragma unroll
    for (int kb = 0; kb < NKB; ++kb) {
        const f16x8 fr = *(const f16x8*)&Ls[(w * 16 + (l & 15)) * 296 + kb * 32 + (l >> 4) * 8];
        ef[((size_t)(blockIdx.x * 4 + w) * NKB + kb) * 64 + l] = fr;
    }
}

// ---- LDS-free MFMA argmin: 64 rows/wave resident A, 32-col chunks ----
// acc = (dot - esq/2)*2^13, argmin score = argmax acc
__global__ __launch_bounds__(256, 2) void k_argmin_f(
        const f16x8* __restrict__ zf, const f16x8* __restrict__ ef,
        float* __restrict__ ps1, float* __restrict__ ps2, int* __restrict__ pix) {
    const int t = threadIdx.x;
    const int l = t & 63;
    const int w = t >> 6;
    const int quad = l >> 4;
    const int l15 = l & 15;
    const int row0 = blockIdx.x * 256;          // 256 rows per block
    const int sp = blockIdx.y;
    const int arb0 = blockIdx.x * 16 + w * 4;   // 4 row-frags per wave (64 rows)

    // A fragments resident for the whole kernel: 4 row-tiles x 9 kb
    f16x8 ah[4][NKB];
#pragma unroll
    for (int mi = 0; mi < 4; ++mi)
#pragma unroll
        for (int kb = 0; kb < NKB; ++kb)
            ah[mi][kb] = zf[((size_t)(arb0 + mi) * NKB + kb) * 64 + l];

    float b1[16], b2[16];
    int i1[16];
#pragma unroll
    for (int s = 0; s < 16; ++s) { b1[s] = -3.4e38f; b2[s] = -3.4e38f; i1[s] = 0; }

    for (int ch = 0; ch < 32; ++ch) {           // 32 chunks x 32 cols = 1024
        const int cb16 = sp * 64 + ch * 2;
        const int c0 = sp * SPLIT_NA + ch * 32;

        f32x4 acc[4][2];
#pragma unroll
        for (int mi = 0; mi < 4; ++mi)
#pragma unroll
            for (int nj = 0; nj < 2; ++nj) acc[mi][nj] = (f32x4){0.f, 0.f, 0.f, 0.f};

#pragma unroll
        for (int kb = 0; kb < NKB; ++kb) {
            f16x8 bh[2];
#pragma unroll
            for (int nj = 0; nj < 2; ++nj)
                bh[nj] = ef[((size_t)(cb16 + nj) * NKB + kb) * 64 + l];
#pragma unroll
            for (int mi = 0; mi < 4; ++mi) {
                acc[mi][0] = MFMA16(ah[mi][kb], bh[0], acc[mi][0]);
                acc[mi][1] = MFMA16(ah[mi][kb], bh[1], acc[mi][1]);
            }
        }

        // top-2 max of acc (cols ascending per lane subset)
#pragma unroll
        for (int nj = 0; nj < 2; ++nj) {
            const int gcol = c0 + nj * 16 + l15;
#pragma unroll
            for (int mi = 0; mi < 4; ++mi)
#pragma unroll
                for (int r = 0; r < 4; ++r) {
                    const int s = mi * 4 + r;
                    const float a = acc[mi][nj][r];
                    b2[s] = fmaxf(b2[s], fminf(a, b1[s]));
                    i1[s] = (a > b1[s]) ? gcol : i1[s];
                    b1[s] = fmaxf(b1[s], a);
                }
        }
    }

    // cross-lane top-2 merge across the 16 lanes of each quad group
#pragma unroll
    for (int s = 0; s < 16; ++s) {
        float v1 = b1[s], v2 = b2[s];
        int ii = i1[s];
#pragma unroll
        for (int m = 1; m <= 8; m <<= 1) {
            const float o1 = __shfl_xor(v1, m);
            const float o2 = __shfl_xor(v2, m);
            const int oi = __shfl_xor(ii, m);
            const float n2 = fmaxf(fminf(v1, o1), fmaxf(v2, o2));
            const bool take = (o1 > v1) || (o1 == v1 && oi < ii);
            ii = take ? oi : ii;
            v1 = fmaxf(v1, o1);
            v2 = n2;
        }
        if (l15 == 0) {
            const int mi = s >> 2, r = s & 3;
            const int row = row0 + w * 64 + mi * 16 + quad * 4 + r;
            ps1[(size_t)row * NSPLIT_A + sp] = -v1;   // back to min semantics
            ps2[(size_t)row * NSPLIT_A + sp] = -v2;
            pix[(size_t)row * NSPLIT_A + sp] = ii;
        }
    }
}

// merge splits; provisional idx; append near-tie rows to candidate-split lists
__global__ __launch_bounds__(256) void k_merge(const float* __restrict__ ps1,
                                               const float* __restrict__ ps2,
                                               const int* __restrict__ pi,
                                               int* __restrict__ idxbuf,
                                               float* __restrict__ outidx,
                                               int* __restrict__ cnt8,
                                               int* __restrict__ lists) {
    const int n = blockIdx.x * 256 + threadIdx.x;
    float v1 = ps1[n * NSPLIT_A];
    float v2 = ps2[n * NSPLIT_A];
    int ii1 = pi[n * NSPLIT_A];
#pragma unroll
    for (int s = 1; s < NSPLIT_A; ++s) {
        const float s1 = ps1[n * NSPLIT_A + s];
        const float s2 = ps2[n * NSPLIT_A + s];
        const int ii = pi[n * NSPLIT_A + s];
        if (s1 < v1 || (s1 == v1 && ii < ii1)) {
            v2 = fminf(fminf(v2, v1), s2);
            v1 = s1; ii1 = ii;
        } else {
            v2 = fminf(v2, s1);
        }
    }
    idxbuf[n] = ii1;
    outidx[n] = (float)ii1;
    if (v2 - v1 < GAPTH_A) {
        const float lim = v1 + GAPTH_A;
#pragma unroll
        for (int s = 0; s < NSPLIT_A; ++s)
            if (ps1[n * NSPLIT_A + s] <= lim) {
                const int p = atomicAdd(&cnt8[s], 1);
                lists[s * NZ + p] = n;
            }
    }
}

// np-bit-exact fp32 repair: one block = 128 gathered rows x ONE 128-col chunk
__global__ __launch_bounds__(256) void k_fix_split(const float* __restrict__ z,
                                                   const float* __restrict__ emb,
                                                   const float* __restrict__ zsq,
                                                   const float* __restrict__ esq,
                                                   const int* __restrict__ cnt8,
                                                   const int* __restrict__ lists,
                                                   unsigned long long* __restrict__ pack) {
    __shared__ float As[BK * LDA];
    __shared__ float Bs[BK * LDA];
    __shared__ float Sq[BM];
    __shared__ int frow[BM];

    const int s = blockIdx.y >> 3;
    const int chunk = blockIdx.y & 7;
    const int ns = cnt8[s];
    const int c0 = s * SPLIT_NA + chunk * BM;
    const int t = threadIdx.x;
    const int tr = t >> 4;
    const int tc = t & 15;
    const int sr = t >> 3;
    const int skq = t & 7;
    const int wrot = 8 * (skq & 3);

    for (int rb = blockIdx.x; rb * BM < ns; rb += gridDim.x) {
        __syncthreads();
        if (t < BM) {
            const int fi = rb * BM + t;
            frow[t] = (fi < ns) ? lists[s * NZ + fi] : lists[s * NZ];
            Sq[t] = esq[c0 + t];
        }
        __syncthreads();

        float zqr[8];
#pragma unroll
        for (int i = 0; i < 8; ++i) zqr[i] = zsq[frow[tr * 8 + i]];

        float best[8];
        int bidx[8];
#pragma unroll
        for (int i = 0; i < 8; ++i) { best[i] = 3.4e38f; bidx[i] = 0; }

        float acc[8][8];
#pragma unroll
        for (int i = 0; i < 8; ++i)
#pragma unroll
            for (int j = 0; j < 8; ++j) acc[i][j] = 0.f;

        for (int kb = 0; kb < D; kb += BK) {
            __syncthreads();
#pragma unroll
            for (int q = 0; q < 4; ++q) {
                const int r = sr + 32 * q;
                const int rr = (r + wrot) & 127;
                const float4 av = *(const float4*)&z[(size_t)frow[r] * D + kb + 4 * skq];
                const float4 bv = *(const float4*)&emb[(size_t)(c0 + r) * D + kb + 4 * skq];
                As[(4 * skq + 0) * LDA + rr] = av.x;
                As[(4 * skq + 1) * LDA + rr] = av.y;
                As[(4 * skq + 2) * LDA + rr] = av.z;
                As[(4 * skq + 3) * LDA + rr] = av.w;
                Bs[(4 * skq + 0) * LDA + rr] = bv.x;
                Bs[(4 * skq + 1) * LDA + rr] = bv.y;
                Bs[(4 * skq + 2) * LDA + rr] = bv.z;
                Bs[(4 * skq + 3) * LDA + rr] = bv.w;
            }
            __syncthreads();
#pragma unroll
            for (int k = 0; k < BK; ++k) {
                const float4 a0 = *(const float4*)&As[k * LDA + SWZR(k, tr * 8)];
                const float4 a1 = *(const float4*)&As[k * LDA + SWZR(k, tr * 8 + 4)];
                const float4 b0 = *(const float4*)&Bs[k * LDA + SWZR(k, tc * 4)];
                const float4 b1 = *(const float4*)&Bs[k * LDA + SWZR(k, 64 + tc * 4)];
                const float a[8] = {a0.x, a0.y, a0.z, a0.w, a1.x, a1.y, a1.z, a1.w};
                const float b[8] = {b0.x, b0.y, b0.z, b0.w, b1.x, b1.y, b1.z, b1.w};
#pragma unroll
                for (int i = 0; i < 8; ++i)
#pragma unroll
                    for (int j = 0; j < 8; ++j)
                        acc[i][j] = fmaf(a[i], b[j], acc[i][j]);
            }
        }
#pragma unroll
        for (int jj = 0; jj < 8; ++jj) {
            const int cloc = (jj < 4) ? (tc * 4 + jj) : (64 + tc * 4 + (jj - 4));
            const float sq = Sq[cloc];
            const int gcol = c0 + cloc;
#pragma unroll
            for (int i = 0; i < 8; ++i) {
                const float t1 = __fadd_rn(zqr[i], sq);
                const float sc = fmaf(-2.f, acc[i][jj], t1);
                if (sc < best[i]) { best[i] = sc; bidx[i] = gcol; }
            }
        }
        __syncthreads();

        float* Rs = As;
        int* Ri = (int*)Bs;
#pragma unroll
        for (int i = 0; i < 8; ++i) {
            Rs[(tr * 8 + i) * LDM + tc] = best[i];
            Ri[(tr * 8 + i) * LDM + tc] = bidx[i];
        }
        __syncthreads();
        if (t < BM) {
            float bs = Rs[t * LDM];
            int bi = Ri[t * LDM];
#pragma unroll
            for (int c = 1; c < 16; ++c) {
                const float sc = Rs[t * LDM + c];
                const int ii = Ri[t * LDM + c];
                if (sc < bs || (sc == bs && ii < bi)) { bs = sc; bi = ii; }
            }
            const int fi = rb * BM + t;
            if (fi < ns) {
                const unsigned long long pk =
                    ((unsigned long long)__float_as_uint(bs) << 32) | (unsigned)bi;
                atomicMin(&pack[frow[t]], pk);
            }
        }
    }
}

__global__ __launch_bounds__(256) void k_fixdecode(const unsigned long long* __restrict__ pack,
                                                   int* __restrict__ idxbuf,
                                                   float* __restrict__ outidx) {
    const int n = blockIdx.x * 256 + threadIdx.x;
    const unsigned long long p = pack[n];
    if (p != ~0ull) {
        const int idx = (int)(p & 0xffffffffu);
        idxbuf[n] = idx;
        outidx[n] = (float)idx;
    }
}

// gather z_q into out; per-block partial of sum((z_q-z)^2) -> gpart (NO atomics)
__global__ __launch_bounds__(256) void k_gather(const float* __restrict__ z,
                                                const float* __restrict__ emb,
                                                const int* __restrict__ idxbuf,
                                                float* __restrict__ out,
                                                double* __restrict__ gpart) {
    __shared__ double part[4];
    const int row = blockIdx.x * 4 + (threadIdx.x >> 6);
    const int lane = threadIdx.x & 63;
    const int idx = idxbuf[row];
    const float4 e4 = *(const float4*)&emb[(size_t)idx * D + lane * 4];
    const float4 z4 = *(const float4*)&z[(size_t)row * D + lane * 4];
    *(float4*)&out[(size_t)row * D + lane * 4] = e4;
    const float dx = e4.x - z4.x, dy = e4.y - z4.y;
    const float dzv = e4.z - z4.z, dw = e4.w - z4.w;
    float s = dx * dx + dy * dy + dzv * dzv + dw * dw;
    s = waveReduceSumF(s);
    if (lane == 0) part[threadIdx.x >> 6] = (double)s;
    __syncthreads();
    if (threadIdx.x == 0)
        gpart[blockIdx.x] = part[0] + part[1] + part[2] + part[3];
}

// ---- pairwise cdist row min/max via frag-direct MFMA, triangular tiles ----
__global__ __launch_bounds__(256) void k_pairwise_f(const f16x8* __restrict__ ef,
                                                    const float* __restrict__ esq,
                                                    unsigned* __restrict__ rmxg,
                                                    unsigned* __restrict__ rmng) {
    __shared__ float cmnS[4][128];
    __shared__ float cmxS[4][128];

    int p = blockIdx.x;
    int bi = 0;
    while (p >= NB - bi) { p -= NB - bi; ++bi; }
    const int bj = bi + p;
    const int row0 = bi * BM;
    const int c0 = bj * BM;

    const int t = threadIdx.x;
    const int l = t & 63;
    const int w = t >> 6;
    const int quad = l >> 4;
    const int l15 = l & 15;

    float sR[8], sC[8];
#pragma unroll
    for (int mi = 0; mi < 2; ++mi)
#pragma unroll
        for (int r = 0; r < 4; ++r)
            sR[mi * 4 + r] = esq[row0 + w * 32 + mi * 16 + quad * 4 + r];
#pragma unroll
    for (int nj = 0; nj < 8; ++nj) sC[nj] = esq[c0 + nj * 16 + l15];

    const int arb = bi * 8 + w * 2;
    const int cfb = bj * 8;

    f32x4 acc[2][8];
#pragma unroll
    for (int mi = 0; mi < 2; ++mi)
#pragma unroll
        for (int nj = 0; nj < 8; ++nj) acc[mi][nj] = (f32x4){0.f, 0.f, 0.f, 0.f};

#pragma unroll
    for (int kb = 0; kb < NKB_P; ++kb) {
        const f16x8 ah0 = ef[((size_t)arb * NKB + kb) * 64 + l];
        const f16x8 ah1 = ef[((size_t)(arb + 1) * NKB + kb) * 64 + l];
        f16x8 bh[8];
#pragma unroll
        for (int nj = 0; nj < 8; ++nj)
            bh[nj] = ef[((size_t)(cfb + nj) * NKB + kb) * 64 + l];
#pragma unroll
        for (int nj = 0; nj < 8; ++nj) {
            acc[0][nj] = MFMA16(ah0, bh[nj], acc[0][nj]);
            acc[1][nj] = MFMA16(ah1, bh[nj], acc[1][nj]);
        }
    }

    float rmn[8], rmx[8], cmn[8], cmx[8];
#pragma unroll
    for (int s = 0; s < 8; ++s) { rmn[s] = 3.4e38f; rmx[s] = 0.f; cmn[s] = 3.4e38f; cmx[s] = 0.f; }
#pragma unroll
    for (int mi = 0; mi < 2; ++mi)
#pragma unroll
        for (int nj = 0; nj < 8; ++nj)
#pragma unroll
            for (int r = 0; r < 4; ++r) {
                const int s = mi * 4 + r;
                const float t1 = __fadd_rn(sR[s], sC[nj]);
                const float d2 = fmaf(-0x1p-25f, acc[mi][nj][r], t1);
                const float d2c = fmaxf(d2, 0.f);
                rmn[s] = fminf(rmn[s], d2c);
                rmx[s] = fmaxf(rmx[s], d2c);
                cmn[nj] = fminf(cmn[nj], d2c);
                cmx[nj] = fmaxf(cmx[nj], d2c);
            }

#pragma unroll
    for (int s = 0; s < 8; ++s) {
#pragma unroll
        for (int m = 1; m <= 8; m <<= 1) {
            rmn[s] = fminf(rmn[s], __shfl_xor(rmn[s], m));
            rmx[s] = fmaxf(rmx[s], __shfl_xor(rmx[s], m));
        }
    }
    if (l15 == 0) {
#pragma unroll
        for (int s = 0; s < 8; ++s) {
            const int mi = s >> 2, r = s & 3;
            const int row = row0 + w * 32 + mi * 16 + quad * 4 + r;
            atomicMax(&rmxg[row], __float_as_uint(rmx[s]));
            atomicMin(&rmng[row], __float_as_uint(rmn[s]));
        }
    }

#pragma unroll
    for (int nj = 0; nj < 8; ++nj) {
#pragma unroll
        for (int m = 16; m <= 32; m <<= 1) {
            cmn[nj] = fminf(cmn[nj], __shfl_xor(cmn[nj], m));
            cmx[nj] = fmaxf(cmx[nj], __shfl_xor(cmx[nj], m));
        }
    }
    if (quad == 0) {
#pragma unroll
        for (int nj = 0; nj < 8; ++nj) {
            cmnS[w][nj * 16 + l15] = cmn[nj];
            cmxS[w][nj * 16 + l15] = cmx[nj];
        }
    }
    __syncthreads();
    if (t < BM) {
        float mn = cmnS[0][t], mx = cmxS[0][t];
#pragma unroll
        for (int ww = 1; ww < 4; ++ww) {
            mn = fminf(mn, cmnS[ww][t]);
            mx = fmaxf(mx, cmxS[ww][t]);
        }
        atomicMax(&rmxg[c0 + t], __float_as_uint(mx));
        atomicMin(&rmng[c0 + t], __float_as_uint(mn));
    }
}

__global__ __launch_bounds__(256) void k_mm_sum(const unsigned* __restrict__ rmxg,
                                                const unsigned* __restrict__ rmng,
                                                double* __restrict__ sums) {
    const int n = blockIdx.x * 256 + threadIdx.x;
    const float mx = sqrtf(__uint_as_float(rmxg[n]));
    const float mn = sqrtf(__uint_as_float(rmng[n]));
    float v = mx - mn;
    v = waveReduceSumF(v);
    __shared__ float part[4];
    if ((threadIdx.x & 63) == 0) part[threadIdx.x >> 6] = v;
    __syncthreads();
    if (threadIdx.x == 0)
        atomicAdd(&sums[2], (double)(part[0] + part[1] + part[2] + part[3]));
}

// final reduce: sum 4096 gather-partials + emit both scalars
__global__ __launch_bounds__(256) void k_final(const double* __restrict__ sums,
                                               const double* __restrict__ gpart,
                                               float* __restrict__ out) {
    __shared__ double part[4];
    const int t = threadIdx.x;
    double s = 0.0;
#pragma unroll
    for (int i = 0; i < NGB / 256; ++i) s += gpart[i * 256 + t];
    s = waveReduceSumD(s);
    if ((t & 63) == 0) part[t >> 6] = s;
    __syncthreads();
    if (t == 0) {
        const double diff2 = part[0] + part[1] + part[2] + part[3];
        const double loss = 1.25 * (diff2 / (double)((size_t)NZ * D));
        const double qq = 0.1 * (sums[2] / (double)NE) + 0.1 * sums[0];
        out[(size_t)NZ * D + NZ] = (float)loss;
        out[(size_t)NZ * D + NZ + 1] = (float)qq;
    }
}

extern "C" void kernel_launch(void* const* d_in, const int* in_sizes, int n_in,
                              void* d_out, int out_size, void* d_ws, size_t ws_size,
                              hipStream_t stream) {
    const float* z = (const float*)d_in[0];
    const float* emb = (const float*)d_in[1];
    float* out = (float*)d_out;
    char* ws = (char*)d_ws;

    double* sums = (double*)(ws + WS_SUMS);
    int* cnt8 = (int*)(ws + WS_CNT8);
    float* zsq = (float*)(ws + WS_ZSQ);
    float* esq = (float*)(ws + WS_ESQ);
    int* idxb = (int*)(ws + WS_IDX);
    float* ps1 = (float*)(ws + WS_PS1);
    float* ps2 = (float*)(ws + WS_PS2);
    int* pix = (int*)(ws + WS_PIX);
    unsigned* rmx = (unsigned*)(ws + WS_RMX);
    unsigned* rmn = (unsigned*)(ws + WS_RMN);
    unsigned long long* pack = (unsigned long long*)(ws + WS_PACK);
    double* gpart = (double*)(ws + WS_GPART);
    int* lists = (int*)(ws + WS_LISTS);
    f16x8* zhf = (f16x8*)(ws + WS_ZHF);
    f16x8* ehf = (f16x8*)(ws + WS_EHF);

    hipLaunchKernelGGL(k_init, dim3(1), dim3(1), 0, stream, sums, cnt8);
    hipLaunchKernelGGL(k_initmm, dim3(NZ / 256), dim3(256), 0, stream, rmx, rmn, pack);
    hipLaunchKernelGGL(k_rowsq, dim3(NZ / 256), dim3(256), 0, stream, z, zsq, (double*)nullptr);
    hipLaunchKernelGGL(k_rowsq, dim3(NE / 256), dim3(256), 0, stream, emb, esq, sums);
    hipLaunchKernelGGL(k_cvt_zf, dim3(NZ / 64), dim3(256), 0, stream, z, zhf);
    hipLaunchKernelGGL(k_cvt_ef, dim3(NE / 64), dim3(256), 0, stream, emb, esq, ehf);
    hipLaunchKernelGGL(k_argmin_f, dim3(NZ / 256, NSPLIT_A), dim3(256), 0, stream,
                       zhf, ehf, ps1, ps2, pix);
    hipLaunchKernelGGL(k_pairwise_f, dim3(NTRI), dim3(256), 0, stream,
                       ehf, esq, rmx, rmn);
    hipLaunchKernelGGL(k_merge, dim3(NZ / 256), dim3(256), 0, stream,
                       ps1, ps2, pix, idxb, out + (size_t)NZ * D, cnt8, lists);
    hipLaunchKernelGGL(k_fix_split, dim3(16, 64), dim3(256), 0, stream,
                       z, emb, zsq, esq, cnt8, lists, pack);
    hipLaunchKernelGGL(k_fixdecode, dim3(NZ / 256), dim3(256), 0, stream,
                       pack, idxb, out + (size_t)NZ * D);
    hipLaunchKernelGGL(k_gather, dim3(NGB), dim3(256), 0, stream,
                       z, emb, idxb, out, gpart);
    hipLaunchKernelGGL(k_mm_sum, dim3(NE / 256), dim3(256), 0, stream,
                       rmx, rmn, sums);
    hipLaunchKernelGGL(k_final, dim3(1), dim3(256), 0, stream, sums, gpart, out);
}

// Round 12
// 359.583 us; speedup vs baseline: 3.0867x; 1.2810x over previous
//
#include <hip/hip_runtime.h>

#define D 256
#define DA 288                     // augmented K (one extra 32-block)
#define NKB 9                      // DA/32
#define NKB_P 8                    // pairwise uses un-augmented 256
#define NE 8192
#define NZ 16384
#define BM 128
#define BK 32
#define LDA (BM + 4)               // fp32 k-major LDS stride (k_fix_split)
#define NB (NE / BM)
#define NTRI (NB * (NB + 1) / 2)
#define NSPLIT_A 8
#define SPLIT_NA (NE / NSPLIT_A)   // 1024
#define GAPTH_A 0.4096f            // 1e-4 score units * 2^12 (acc units)
#define LDM 17
#define NGB (NZ / 4)               // gather blocks = 4096
#define NCH_A (SPLIT_NA / 32)      // 32 chunks of 32 cols (argmin)
#define AUNITS (2 * NKB)           // 18 staging units per argmin chunk
#define PUNITS (2 * NKB_P)         // 16 staging units per pairwise chunk

// fp32-path LDS swizzle (verified R4-R11, k_fix_split only)
#define SROT(kk) (8 * ((((kk) >> 2)) & 3))
#define SWZR(kk, r) ((((r) + SROT(kk)) & 127))

typedef _Float16 f16x8 __attribute__((ext_vector_type(8)));
typedef _Float16 f16x4 __attribute__((ext_vector_type(4)));
typedef float f32x4 __attribute__((ext_vector_type(4)));

#define MFMA16(a, b, c) __builtin_amdgcn_mfma_f32_16x16x32_f16(a, b, c, 0, 0, 0)

// async global->LDS, 16B/lane; LDS dest = uniform base + lane*16
__device__ __forceinline__ void g2l16(const void* g, void* lds) {
    __builtin_amdgcn_global_load_lds(
        (const __attribute__((address_space(1))) void*)g,
        (__attribute__((address_space(3))) void*)lds, 16, 0, 0);
}

// ---------------- workspace layout (bytes) ----------------
#define WS_SUMS   0                            // double[4]
#define WS_CNT8   64                           // int[8]
#define WS_ZSQ    256                          // float[NZ]
#define WS_ESQ    (WS_ZSQ + NZ * 4)            // float[NE]
#define WS_IDX    (WS_ESQ + NE * 4)            // int[NZ]
#define WS_PS1    (WS_IDX + NZ * 4)            // float[NZ*8]
#define WS_PS2    (WS_PS1 + NZ * NSPLIT_A * 4)
#define WS_PIX    (WS_PS2 + NZ * NSPLIT_A * 4)
#define WS_RMX    (WS_PIX + NZ * NSPLIT_A * 4) // uint[NE]
#define WS_RMN    (WS_RMX + NE * 4)            // uint[NE]
#define WS_PACK   (WS_RMN + NE * 4)            // u64[NZ]
#define WS_GPART  (WS_PACK + NZ * 8)           // double[NGB]
#define WS_LISTS  (WS_GPART + NGB * 8)         // int[8][NZ]
#define WS_ZHF    (WS_LISTS + NZ * NSPLIT_A * 4)   // frag-major f16 z
#define WS_EHF    (WS_ZHF + (size_t)(NZ / 16) * NKB * 64 * 8 * 2)

__device__ __forceinline__ float waveReduceSumF(float v) {
    v += __shfl_down(v, 32); v += __shfl_down(v, 16); v += __shfl_down(v, 8);
    v += __shfl_down(v, 4);  v += __shfl_down(v, 2);  v += __shfl_down(v, 1);
    return v;
}
__device__ __forceinline__ double waveReduceSumD(double v) {
    v += __shfl_down(v, 32); v += __shfl_down(v, 16); v += __shfl_down(v, 8);
    v += __shfl_down(v, 4);  v += __shfl_down(v, 2);  v += __shfl_down(v, 1);
    return v;
}

__global__ void k_init(double* sums, int* cnt8) {
    sums[0] = 0.0; sums[1] = 0.0; sums[2] = 0.0; sums[3] = 0.0;
#pragma unroll
    for (int s = 0; s < 8; ++s) cnt8[s] = 0;
}

__global__ __launch_bounds__(256) void k_initmm(unsigned* __restrict__ rmx,
                                                unsigned* __restrict__ rmn,
                                                unsigned long long* __restrict__ pack) {
    const int n = blockIdx.x * 256 + threadIdx.x;
    if (n < NE) { rmx[n] = 0u; rmn[n] = 0x7F800000u; }
    pack[n] = ~0ull;
}

// np.sum(x*x, axis=1) bit-exact (numpy pairwise summation, n=256)
__global__ __launch_bounds__(256) void k_rowsq(const float* __restrict__ src,
                                               float* __restrict__ rsq,
                                               double* __restrict__ sums) {
    const int row = blockIdx.x * 256 + threadIdx.x;
    const float* p = src + (size_t)row * D;
    float h[2];
#pragma unroll
    for (int half = 0; half < 2; ++half) {
        const float* q = p + half * 128;
        float4 a0 = *(const float4*)&q[0];
        float4 a1 = *(const float4*)&q[4];
        float r0 = __fmul_rn(a0.x, a0.x);
        float r1 = __fmul_rn(a0.y, a0.y);
        float r2 = __fmul_rn(a0.z, a0.z);
        float r3 = __fmul_rn(a0.w, a0.w);
        float r4 = __fmul_rn(a1.x, a1.x);
        float r5 = __fmul_rn(a1.y, a1.y);
        float r6 = __fmul_rn(a1.z, a1.z);
        float r7 = __fmul_rn(a1.w, a1.w);
#pragma unroll
        for (int i = 8; i < 128; i += 8) {
            const float4 b0 = *(const float4*)&q[i];
            const float4 b1 = *(const float4*)&q[i + 4];
            r0 = __fadd_rn(r0, __fmul_rn(b0.x, b0.x));
            r1 = __fadd_rn(r1, __fmul_rn(b0.y, b0.y));
            r2 = __fadd_rn(r2, __fmul_rn(b0.z, b0.z));
            r3 = __fadd_rn(r3, __fmul_rn(b0.w, b0.w));
            r4 = __fadd_rn(r4, __fmul_rn(b1.x, b1.x));
            r5 = __fadd_rn(r5, __fmul_rn(b1.y, b1.y));
            r6 = __fadd_rn(r6, __fmul_rn(b1.z, b1.z));
            r7 = __fadd_rn(r7, __fmul_rn(b1.w, b1.w));
        }
        const float t01 = __fadd_rn(r0, r1);
        const float t23 = __fadd_rn(r2, r3);
        const float t45 = __fadd_rn(r4, r5);
        const float t67 = __fadd_rn(r6, r7);
        h[half] = __fadd_rn(__fadd_rn(t01, t23), __fadd_rn(t45, t67));
    }
    const float tot = __fadd_rn(h[0], h[1]);
    rsq[row] = tot;
    if (sums != nullptr) {
        double s = waveReduceSumD((double)tot);
        if ((threadIdx.x & 63) == 0) atomicAdd(&sums[0], s);
    }
}

// ---- fragment-major converters (64 rows per block, LDS transpose) ----
__global__ __launch_bounds__(256) void k_cvt_zf(const float* __restrict__ z,
                                                f16x8* __restrict__ zf) {
    __shared__ _Float16 Ls[64 * 296];
    const int t = threadIdx.x;
    const int row0 = blockIdx.x * 64;
#pragma unroll
    for (int i = 0; i < 16; ++i) {
        const int f4 = i * 256 + t;
        const int r = f4 >> 6, c4 = f4 & 63;
        const float4 v = *(const float4*)&z[(size_t)(row0 + r) * D + c4 * 4];
        f16x4 h;
        h[0] = (_Float16)v.x; h[1] = (_Float16)v.y;
        h[2] = (_Float16)v.z; h[3] = (_Float16)v.w;
        *(f16x4*)&Ls[r * 296 + c4 * 4] = h;
    }
#pragma unroll
    for (int i = 0; i < 8; ++i) {
        const int idx = i * 256 + t;
        const int r = idx >> 5, c = idx & 31;
        Ls[r * 296 + 256 + c] = (c == 0) ? (_Float16)1.0f : (_Float16)0.0f;
    }
    __syncthreads();
    const int l = t & 63, w = t >> 6;
#pragma unroll
    for (int kb = 0; kb < NKB; ++kb) {
        const f16x8 fr = *(const f16x8*)&Ls[(w * 16 + (l & 15)) * 296 + kb * 32 + (l >> 4) * 8];
        zf[((size_t)(blockIdx.x * 4 + w) * NKB + kb) * 64 + l] = fr;
    }
}

__global__ __launch_bounds__(256) void k_cvt_ef(const float* __restrict__ e,
                                                const float* __restrict__ esq,
                                                f16x8* __restrict__ ef) {
    __shared__ _Float16 Ls[64 * 296];
    const int t = threadIdx.x;
    const int row0 = blockIdx.x * 64;
#pragma unroll
    for (int i = 0; i < 16; ++i) {
        const int f4 = i * 256 + t;
        const int r = f4 >> 6, c4 = f4 & 63;
        const float4 v = *(const float4*)&e[(size_t)(row0 + r) * D + c4 * 4];
        f16x4 h;
        h[0] = (_Float16)(v.x * 8192.0f); h[1] = (_Float16)(v.y * 8192.0f);
        h[2] = (_Float16)(v.z * 8192.0f); h[3] = (_Float16)(v.w * 8192.0f);
        *(f16x4*)&Ls[r * 296 + c4 * 4] = h;
    }
#pragma unroll
    for (int i = 0; i < 8; ++i) {
        const int idx = i * 256 + t;
        const int r = idx >> 5, c = idx & 31;
        Ls[r * 296 + 256 + c] =
            (c == 0) ? (_Float16)(esq[row0 + r] * -4096.0f) : (_Float16)0.0f;
    }
    __syncthreads();
    const int l = t & 63, w = t >> 6;
#pragma unroll
    for (int kb = 0; kb < NKB; ++kb) {
        const f16x8 fr = *(const f16x8*)&Ls[(w * 16 + (l & 15)) * 296 + kb * 32 + (l >> 4) * 8];
        ef[((size_t)(blockIdx.x * 4 + w) * NKB + kb) * 64 + l] = fr;
    }
}

// ---- MFMA argmin: resident A (2 frags/wave) + B via global_load_lds double buffer ----
// acc = (dot - esq/2)*2^13, argmin score = argmax acc
__global__ __launch_bounds__(256) void k_argmin_f(
        const f16x8* __restrict__ zf, const f16x8* __restrict__ ef,
        float* __restrict__ ps1, float* __restrict__ ps2, int* __restrict__ pix) {
    __shared__ __align__(16) _Float16 Bsm[2][AUNITS * 512];   // 2 x 18 KB

    const int t = threadIdx.x;
    const int l = t & 63;
    const int w = t >> 6;
    const int quad = l >> 4;
    const int l15 = l & 15;
    const int row0 = blockIdx.x * BM;
    const int sp = blockIdx.y;
    const int arb0 = blockIdx.x * 8 + w * 2;

    // resident A fragments (2 row-tiles x 9 kb)
    f16x8 ah[2][NKB];
#pragma unroll
    for (int kb = 0; kb < NKB; ++kb) {
        ah[0][kb] = zf[((size_t)arb0 * NKB + kb) * 64 + l];
        ah[1][kb] = zf[((size_t)(arb0 + 1) * NKB + kb) * 64 + l];
    }

    float b1[8], b2[8];
    int i1[8];
#pragma unroll
    for (int s = 0; s < 8; ++s) { b1[s] = -3.4e38f; b2[s] = -3.4e38f; i1[s] = 0; }

    // stage chunk ch into buffer buf (18 units of 1 KB, spread over the 4 waves)
    auto stage = [&](int ch, int buf) {
        const int cb16 = sp * 64 + ch * 2;
        for (int u = w; u < AUNITS; u += 4) {
            const int nj = u / NKB, kb = u - nj * NKB;
            g2l16(&ef[((size_t)(cb16 + nj) * NKB + kb) * 64 + l],
                  &Bsm[buf][u * 512]);
        }
    };

    stage(0, 0);
    for (int ch = 0; ch < NCH_A; ++ch) {
        const int buf = ch & 1;
        __syncthreads();                 // staging of buf complete (vmcnt drain)
        if (ch + 1 < NCH_A) stage(ch + 1, buf ^ 1);
        const int c0 = sp * SPLIT_NA + ch * 32;

        f32x4 acc[2][2];
#pragma unroll
        for (int mi = 0; mi < 2; ++mi)
#pragma unroll
            for (int nj = 0; nj < 2; ++nj) acc[mi][nj] = (f32x4){0.f, 0.f, 0.f, 0.f};

#pragma unroll
        for (int kb = 0; kb < NKB; ++kb) {
            const f16x8 bh0 = *(const f16x8*)&Bsm[buf][(0 * NKB + kb) * 512 + l * 8];
            const f16x8 bh1 = *(const f16x8*)&Bsm[buf][(1 * NKB + kb) * 512 + l * 8];
#pragma unroll
            for (int mi = 0; mi < 2; ++mi) {
                acc[mi][0] = MFMA16(ah[mi][kb], bh0, acc[mi][0]);
                acc[mi][1] = MFMA16(ah[mi][kb], bh1, acc[mi][1]);
            }
        }

        // top-2 max of acc (cols ascending per lane subset)
#pragma unroll
        for (int nj = 0; nj < 2; ++nj) {
            const int gcol = c0 + nj * 16 + l15;
#pragma unroll
            for (int mi = 0; mi < 2; ++mi)
#pragma unroll
                for (int r = 0; r < 4; ++r) {
                    const int s = mi * 4 + r;
                    const float a = acc[mi][nj][r];
                    b2[s] = fmaxf(b2[s], fminf(a, b1[s]));
                    i1[s] = (a > b1[s]) ? gcol : i1[s];
                    b1[s] = fmaxf(b1[s], a);
                }
        }
    }

    // cross-lane top-2 merge across the 16 lanes of each quad group
#pragma unroll
    for (int s = 0; s < 8; ++s) {
        float v1 = b1[s], v2 = b2[s];
        int ii = i1[s];
#pragma unroll
        for (int m = 1; m <= 8; m <<= 1) {
            const float o1 = __shfl_xor(v1, m);
            const float o2 = __shfl_xor(v2, m);
            const int oi = __shfl_xor(ii, m);
            const float n2 = fmaxf(fminf(v1, o1), fmaxf(v2, o2));
            const bool take = (o1 > v1) || (o1 == v1 && oi < ii);
            ii = take ? oi : ii;
            v1 = fmaxf(v1, o1);
            v2 = n2;
        }
        if (l15 == 0) {
            const int mi = s >> 2, r = s & 3;
            const int row = row0 + w * 32 + mi * 16 + quad * 4 + r;
            ps1[(size_t)row * NSPLIT_A + sp] = -v1;   // back to min semantics
            ps2[(size_t)row * NSPLIT_A + sp] = -v2;
            pix[(size_t)row * NSPLIT_A + sp] = ii;
        }
    }
}

// merge splits; provisional idx; append near-tie rows to candidate-split lists
__global__ __launch_bounds__(256) void k_merge(const float* __restrict__ ps1,
                                               const float* __restrict__ ps2,
                                               const int* __restrict__ pi,
                                               int* __restrict__ idxbuf,
                                               float* __restrict__ outidx,
                                               int* __restrict__ cnt8,
                                               int* __restrict__ lists) {
    const int n = blockIdx.x * 256 + threadIdx.x;
    float v1 = ps1[n * NSPLIT_A];
    float v2 = ps2[n * NSPLIT_A];
    int ii1 = pi[n * NSPLIT_A];
#pragma unroll
    for (int s = 1; s < NSPLIT_A; ++s) {
        const float s1 = ps1[n * NSPLIT_A + s];
        const float s2 = ps2[n * NSPLIT_A + s];
        const int ii = pi[n * NSPLIT_A + s];
        if (s1 < v1 || (s1 == v1 && ii < ii1)) {
            v2 = fminf(fminf(v2, v1), s2);
            v1 = s1; ii1 = ii;
        } else {
            v2 = fminf(v2, s1);
        }
    }
    idxbuf[n] = ii1;
    outidx[n] = (float)ii1;
    if (v2 - v1 < GAPTH_A) {
        const float lim = v1 + GAPTH_A;
#pragma unroll
        for (int s = 0; s < NSPLIT_A; ++s)
            if (ps1[n * NSPLIT_A + s] <= lim) {
                const int p = atomicAdd(&cnt8[s], 1);
                lists[s * NZ + p] = n;
            }
    }
}

// np-bit-exact fp32 repair: one block = 128 gathered rows x ONE 128-col chunk
__global__ __launch_bounds__(256) void k_fix_split(const float* __restrict__ z,
                                                   const float* __restrict__ emb,
                                                   const float* __restrict__ zsq,
                                                   const float* __restrict__ esq,
                                                   const int* __restrict__ cnt8,
                                                   const int* __restrict__ lists,
                                                   unsigned long long* __restrict__ pack) {
    __shared__ float As[BK * LDA];
    __shared__ float Bs[BK * LDA];
    __shared__ float Sq[BM];
    __shared__ int frow[BM];

    const int s = blockIdx.y >> 3;
    const int chunk = blockIdx.y & 7;
    const int ns = cnt8[s];
    const int c0 = s * SPLIT_NA + chunk * BM;
    const int t = threadIdx.x;
    const int tr = t >> 4;
    const int tc = t & 15;
    const int sr = t >> 3;
    const int skq = t & 7;
    const int wrot = 8 * (skq & 3);

    for (int rb = blockIdx.x; rb * BM < ns; rb += gridDim.x) {
        __syncthreads();
        if (t < BM) {
            const int fi = rb * BM + t;
            frow[t] = (fi < ns) ? lists[s * NZ + fi] : lists[s * NZ];
            Sq[t] = esq[c0 + t];
        }
        __syncthreads();

        float zqr[8];
#pragma unroll
        for (int i = 0; i < 8; ++i) zqr[i] = zsq[frow[tr * 8 + i]];

        float best[8];
        int bidx[8];
#pragma unroll
        for (int i = 0; i < 8; ++i) { best[i] = 3.4e38f; bidx[i] = 0; }

        float acc[8][8];
#pragma unroll
        for (int i = 0; i < 8; ++i)
#pragma unroll
            for (int j = 0; j < 8; ++j) acc[i][j] = 0.f;

        for (int kb = 0; kb < D; kb += BK) {
            __syncthreads();
#pragma unroll
            for (int q = 0; q < 4; ++q) {
                const int r = sr + 32 * q;
                const int rr = (r + wrot) & 127;
                const float4 av = *(const float4*)&z[(size_t)frow[r] * D + kb + 4 * skq];
                const float4 bv = *(const float4*)&emb[(size_t)(c0 + r) * D + kb + 4 * skq];
                As[(4 * skq + 0) * LDA + rr] = av.x;
                As[(4 * skq + 1) * LDA + rr] = av.y;
                As[(4 * skq + 2) * LDA + rr] = av.z;
                As[(4 * skq + 3) * LDA + rr] = av.w;
                Bs[(4 * skq + 0) * LDA + rr] = bv.x;
                Bs[(4 * skq + 1) * LDA + rr] = bv.y;
                Bs[(4 * skq + 2) * LDA + rr] = bv.z;
                Bs[(4 * skq + 3) * LDA + rr] = bv.w;
            }
            __syncthreads();
#pragma unroll
            for (int k = 0; k < BK; ++k) {
                const float4 a0 = *(const float4*)&As[k * LDA + SWZR(k, tr * 8)];
                const float4 a1 = *(const float4*)&As[k * LDA + SWZR(k, tr * 8 + 4)];
                const float4 b0 = *(const float4*)&Bs[k * LDA + SWZR(k, tc * 4)];
                const float4 b1 = *(const float4*)&Bs[k * LDA + SWZR(k, 64 + tc * 4)];
                const float a[8] = {a0.x, a0.y, a0.z, a0.w, a1.x, a1.y, a1.z, a1.w};
                const float b[8] = {b0.x, b0.y, b0.z, b0.w, b1.x, b1.y, b1.z, b1.w};
#pragma unroll
                for (int i = 0; i < 8; ++i)
#pragma unroll
                    for (int j = 0; j < 8; ++j)
                        acc[i][j] = fmaf(a[i], b[j], acc[i][j]);
            }
        }
#pragma unroll
        for (int jj = 0; jj < 8; ++jj) {
            const int cloc = (jj < 4) ? (tc * 4 + jj) : (64 + tc * 4 + (jj - 4));
            const float sq = Sq[cloc];
            const int gcol = c0 + cloc;
#pragma unroll
            for (int i = 0; i < 8; ++i) {
                const float t1 = __fadd_rn(zqr[i], sq);
                const float sc = fmaf(-2.f, acc[i][jj], t1);
                if (sc < best[i]) { best[i] = sc; bidx[i] = gcol; }
            }
        }
        __syncthreads();

        float* Rs = As;
        int* Ri = (int*)Bs;
#pragma unroll
        for (int i = 0; i < 8; ++i) {
            Rs[(tr * 8 + i) * LDM + tc] = best[i];
            Ri[(tr * 8 + i) * LDM + tc] = bidx[i];
        }
        __syncthreads();
        if (t < BM) {
            float bs = Rs[t * LDM];
            int bi = Ri[t * LDM];
#pragma unroll
            for (int c = 1; c < 16; ++c) {
                const float sc = Rs[t * LDM + c];
                const int ii = Ri[t * LDM + c];
                if (sc < bs || (sc == bs && ii < bi)) { bs = sc; bi = ii; }
            }
            const int fi = rb * BM + t;
            if (fi < ns) {
                const unsigned long long pk =
                    ((unsigned long long)__float_as_uint(bs) << 32) | (unsigned)bi;
                atomicMin(&pack[frow[t]], pk);
            }
        }
    }
}

__global__ __launch_bounds__(256) void k_fixdecode(const unsigned long long* __restrict__ pack,
                                                   int* __restrict__ idxbuf,
                                                   float* __restrict__ outidx) {
    const int n = blockIdx.x * 256 + threadIdx.x;
    const unsigned long long p = pack[n];
    if (p != ~0ull) {
        const int idx = (int)(p & 0xffffffffu);
        idxbuf[n] = idx;
        outidx[n] = (float)idx;
    }
}

// gather z_q into out; per-block partial of sum((z_q-z)^2) -> gpart (NO atomics)
__global__ __launch_bounds__(256) void k_gather(const float* __restrict__ z,
                                                const float* __restrict__ emb,
                                                const int* __restrict__ idxbuf,
                                                float* __restrict__ out,
                                                double* __restrict__ gpart) {
    __shared__ double part[4];
    const int row = blockIdx.x * 4 + (threadIdx.x >> 6);
    const int lane = threadIdx.x & 63;
    const int idx = idxbuf[row];
    const float4 e4 = *(const float4*)&emb[(size_t)idx * D + lane * 4];
    const float4 z4 = *(const float4*)&z[(size_t)row * D + lane * 4];
    *(float4*)&out[(size_t)row * D + lane * 4] = e4;
    const float dx = e4.x - z4.x, dy = e4.y - z4.y;
    const float dzv = e4.z - z4.z, dw = e4.w - z4.w;
    float s = dx * dx + dy * dy + dzv * dzv + dw * dw;
    s = waveReduceSumF(s);
    if (lane == 0) part[threadIdx.x >> 6] = (double)s;
    __syncthreads();
    if (threadIdx.x == 0)
        gpart[blockIdx.x] = part[0] + part[1] + part[2] + part[3];
}

// ---- pairwise cdist row min/max: resident A + B via global_load_lds dbuf ----
__global__ __launch_bounds__(256) void k_pairwise_f(const f16x8* __restrict__ ef,
                                                    const float* __restrict__ esq,
                                                    unsigned* __restrict__ rmxg,
                                                    unsigned* __restrict__ rmng) {
    __shared__ __align__(16) _Float16 Bsm[2][PUNITS * 512];   // 2 x 16 KB

    int p = blockIdx.x;
    int bi = 0;
    while (p >= NB - bi) { p -= NB - bi; ++bi; }
    const int bj = bi + p;
    const int row0 = bi * BM;
    const int c0 = bj * BM;

    const int t = threadIdx.x;
    const int l = t & 63;
    const int w = t >> 6;
    const int quad = l >> 4;
    const int l15 = l & 15;

    float sR[8], sC[8];
#pragma unroll
    for (int mi = 0; mi < 2; ++mi)
#pragma unroll
        for (int r = 0; r < 4; ++r)
            sR[mi * 4 + r] = esq[row0 + w * 32 + mi * 16 + quad * 4 + r];
#pragma unroll
    for (int nj = 0; nj < 8; ++nj) sC[nj] = esq[c0 + nj * 16 + l15];

    const int arb = bi * 8 + w * 2;
    const int cfb = bj * 8;

    // resident A fragments (2 row-tiles x 8 kb)
    f16x8 ah[2][NKB_P];
#pragma unroll
    for (int kb = 0; kb < NKB_P; ++kb) {
        ah[0][kb] = ef[((size_t)arb * NKB + kb) * 64 + l];
        ah[1][kb] = ef[((size_t)(arb + 1) * NKB + kb) * 64 + l];
    }

    float rmn[8], rmx[8], cmn[8], cmx[8];
#pragma unroll
    for (int s = 0; s < 8; ++s) { rmn[s] = 3.4e38f; rmx[s] = 0.f; cmn[s] = 3.4e38f; cmx[s] = 0.f; }

    auto stage = [&](int ch, int buf) {
        for (int u = w; u < PUNITS; u += 4) {
            const int nj = u >> 3, kb = u & 7;
            g2l16(&ef[((size_t)(cfb + ch * 2 + nj) * NKB + kb) * 64 + l],
                  &Bsm[buf][u * 512]);
        }
    };

    stage(0, 0);
    for (int ch = 0; ch < 4; ++ch) {            // 4 chunks x 32 cols = 128
        const int buf = ch & 1;
        __syncthreads();
        if (ch + 1 < 4) stage(ch + 1, buf ^ 1);

        f32x4 acc[2][2];
#pragma unroll
        for (int mi = 0; mi < 2; ++mi)
#pragma unroll
            for (int nj = 0; nj < 2; ++nj) acc[mi][nj] = (f32x4){0.f, 0.f, 0.f, 0.f};

#pragma unroll
        for (int kb = 0; kb < NKB_P; ++kb) {
            const f16x8 bh0 = *(const f16x8*)&Bsm[buf][(0 * 8 + kb) * 512 + l * 8];
            const f16x8 bh1 = *(const f16x8*)&Bsm[buf][(1 * 8 + kb) * 512 + l * 8];
#pragma unroll
            for (int mi = 0; mi < 2; ++mi) {
                acc[mi][0] = MFMA16(ah[mi][kb], bh0, acc[mi][0]);
                acc[mi][1] = MFMA16(ah[mi][kb], bh1, acc[mi][1]);
            }
        }

#pragma unroll
        for (int nj = 0; nj < 2; ++nj) {
            const int cidx = ch * 2 + nj;
#pragma unroll
            for (int mi = 0; mi < 2; ++mi)
#pragma unroll
                for (int r = 0; r < 4; ++r) {
                    const int s = mi * 4 + r;
                    const float t1 = __fadd_rn(sR[s], sC[cidx]);
                    const float d2 = fmaf(-0x1p-25f, acc[mi][nj][r], t1);
                    const float d2c = fmaxf(d2, 0.f);
                    rmn[s] = fminf(rmn[s], d2c);
                    rmx[s] = fmaxf(rmx[s], d2c);
                    cmn[cidx] = fminf(cmn[cidx], d2c);
                    cmx[cidx] = fmaxf(cmx[cidx], d2c);
                }
        }
    }

    // rows: butterfly across the 16 lanes of the quad group, then atomics
#pragma unroll
    for (int s = 0; s < 8; ++s) {
#pragma unroll
        for (int m = 1; m <= 8; m <<= 1) {
            rmn[s] = fminf(rmn[s], __shfl_xor(rmn[s], m));
            rmx[s] = fmaxf(rmx[s], __shfl_xor(rmx[s], m));
        }
    }
    if (l15 == 0) {
#pragma unroll
        for (int s = 0; s < 8; ++s) {
            const int mi = s >> 2, r = s & 3;
            const int row = row0 + w * 32 + mi * 16 + quad * 4 + r;
            atomicMax(&rmxg[row], __float_as_uint(rmx[s]));
            atomicMin(&rmng[row], __float_as_uint(rmn[s]));
        }
    }

    // cols: butterfly across quads, LDS across waves (reuse Bsm), then atomics
#pragma unroll
    for (int nj = 0; nj < 8; ++nj) {
#pragma unroll
        for (int m = 16; m <= 32; m <<= 1) {
            cmn[nj] = fminf(cmn[nj], __shfl_xor(cmn[nj], m));
            cmx[nj] = fmaxf(cmx[nj], __shfl_xor(cmx[nj], m));
        }
    }
    __syncthreads();   // all chunk reads done; Bsm reusable
    float* Mn = (float*)&Bsm[0][0];          // [4][128]
    float* Mx = (float*)&Bsm[0][0] + 512;    // [4][128]
    if (quad == 0) {
#pragma unroll
        for (int nj = 0; nj < 8; ++nj) {
            Mn[w * 128 + nj * 16 + l15] = cmn[nj];
            Mx[w * 128 + nj * 16 + l15] = cmx[nj];
        }
    }
    __syncthreads();
    if (t < BM) {
        float mn = Mn[t], mx = Mx[t];
#pragma unroll
        for (int ww = 1; ww < 4; ++ww) {
            mn = fminf(mn, Mn[ww * 128 + t]);
            mx = fmaxf(mx, Mx[ww * 128 + t]);
        }
        atomicMax(&rmxg[c0 + t], __float_as_uint(mx));
        atomicMin(&rmng[c0 + t], __float_as_uint(mn));
    }
}

__global__ __launch_bounds__(256) void k_mm_sum(const unsigned* __restrict__ rmxg,
                                                const unsigned* __restrict__ rmng,
                                                double* __restrict__ sums) {
    const int n = blockIdx.x * 256 + threadIdx.x;
    const float mx = sqrtf(__uint_as_float(rmxg[n]));
    const float mn = sqrtf(__uint_as_float(rmng[n]));
    float v = mx - mn;
    v = waveReduceSumF(v);
    __shared__ float part[4];
    if ((threadIdx.x & 63) == 0) part[threadIdx.x >> 6] = v;
    __syncthreads();
    if (threadIdx.x == 0)
        atomicAdd(&sums[2], (double)(part[0] + part[1] + part[2] + part[3]));
}

// final reduce: sum 4096 gather-partials + emit both scalars
__global__ __launch_bounds__(256) void k_final(const double* __restrict__ sums,
                                               const double* __restrict__ gpart,
                                               float* __restrict__ out) {
    __shared__ double part[4];
    const int t = threadIdx.x;
    double s = 0.0;
#pragma unroll
    for (int i = 0; i < NGB / 256; ++i) s += gpart[i * 256 + t];
    s = waveReduceSumD(s);
    if ((t & 63) == 0) part[t >> 6] = s;
    __syncthreads();
    if (t == 0) {
        const double diff2 = part[0] + part[1] + part[2] + part[3];
        const double loss = 1.25 * (diff2 / (double)((size_t)NZ * D));
        const double qq = 0.1 * (sums[2] / (double)NE) + 0.1 * sums[0];
        out[(size_t)NZ * D + NZ] = (float)loss;
        out[(size_t)NZ * D + NZ + 1] = (float)qq;
    }
}

extern "C" void kernel_launch(void* const* d_in, const int* in_sizes, int n_in,
                              void* d_out, int out_size, void* d_ws, size_t ws_size,
                              hipStream_t stream) {
    const float* z = (const float*)d_in[0];
    const float* emb = (const float*)d_in[1];
    float* out = (float*)d_out;
    char* ws = (char*)d_ws;

    double* sums = (double*)(ws + WS_SUMS);
    int* cnt8 = (int*)(ws + WS_CNT8);
    float* zsq = (float*)(ws + WS_ZSQ);
    float* esq = (float*)(ws + WS_ESQ);
    int* idxb = (int*)(ws + WS_IDX);
    float* ps1 = (float*)(ws + WS_PS1);
    float* ps2 = (float*)(ws + WS_PS2);
    int* pix = (int*)(ws + WS_PIX);
    unsigned* rmx = (unsigned*)(ws + WS_RMX);
    unsigned* rmn = (unsigned*)(ws + WS_RMN);
    unsigned long long* pack = (unsigned long long*)(ws + WS_PACK);
    double* gpart = (double*)(ws + WS_GPART);
    int* lists = (int*)(ws + WS_LISTS);
    f16x8* zhf = (f16x8*)(ws + WS_ZHF);
    f16x8* ehf = (f16x8*)(ws + WS_EHF);

    hipLaunchKernelGGL(k_init, dim3(1), dim3(1), 0, stream, sums, cnt8);
    hipLaunchKernelGGL(k_initmm, dim3(NZ / 256), dim3(256), 0, stream, rmx, rmn, pack);
    hipLaunchKernelGGL(k_rowsq, dim3(NZ / 256), dim3(256), 0, stream, z, zsq, (double*)nullptr);
    hipLaunchKernelGGL(k_rowsq, dim3(NE / 256), dim3(256), 0, stream, emb, esq, sums);
    hipLaunchKernelGGL(k_cvt_zf, dim3(NZ / 64), dim3(256), 0, stream, z, zhf);
    hipLaunchKernelGGL(k_cvt_ef, dim3(NE / 64), dim3(256), 0, stream, emb, esq, ehf);
    hipLaunchKernelGGL(k_argmin_f, dim3(NZ / BM, NSPLIT_A), dim3(256), 0, stream,
                       zhf, ehf, ps1, ps2, pix);
    hipLaunchKernelGGL(k_pairwise_f, dim3(NTRI), dim3(256), 0, stream,
                       ehf, esq, rmx, rmn);
    hipLaunchKernelGGL(k_merge, dim3(NZ / 256), dim3(256), 0, stream,
                       ps1, ps2, pix, idxb, out + (size_t)NZ * D, cnt8, lists);
    hipLaunchKernelGGL(k_fix_split, dim3(16, 64), dim3(256), 0, stream,
                       z, emb, zsq, esq, cnt8, lists, pack);
    hipLaunchKernelGGL(k_fixdecode, dim3(NZ / 256), dim3(256), 0, stream,
                       pack, idxb, out + (size_t)NZ * D);
    hipLaunchKernelGGL(k_gather, dim3(NGB), dim3(256), 0, stream,
                       z, emb, idxb, out, gpart);
    hipLaunchKernelGGL(k_mm_sum, dim3(NE / 256), dim3(256), 0, stream,
                       rmx, rmn, sums);
    hipLaunchKernelGGL(k_final, dim3(1), dim3(256), 0, stream, sums, gpart, out);
}